// Round 11
// baseline (1028.575 us; speedup 1.0000x reference)
//
#include <hip/hip_runtime.h>
#include <stdint.h>

#define NEG_INF_F (-1e30f)

typedef _Float16 half8 __attribute__((ext_vector_type(8)));
typedef float f32x4 __attribute__((ext_vector_type(4)));
typedef float f32x16 __attribute__((ext_vector_type(16)));
typedef uint32_t u32x4 __attribute__((ext_vector_type(4)));

__device__ __forceinline__ uint32_t ordf(float f) {
    uint32_t u = __float_as_uint(f);
    return u ^ ((u >> 31) ? 0xFFFFFFFFu : 0x80000000u);
}

#define GLL16(g, l) __builtin_amdgcn_global_load_lds( \
    (const __attribute__((address_space(1))) void*)(g), \
    (__attribute__((address_space(3))) void*)(l), 16, 0, 0)

// Apad: [split][b][yy 0..65][xx 0..67][icb 16][rot 4][8 fp16]  (pixel = 1024 B)
// Bw:   [split][kk 9][icb 16][oc 512][rot 4][8 fp16]; rot = (chunk + oc) & 3.
#define APLANE 36765696ull
#define BPLANE 4718592ull

// ---------------------------------------------------------------------------
// Conv weight prep: OIHW f32 -> fp16 hi plane + (lo*2048) plane, rotated slots.
// ---------------------------------------------------------------------------
__global__ __launch_bounds__(256) void prep_w(const float* __restrict__ w,
                                              char* __restrict__ bw)
{
    int t = blockIdx.x * 256 + threadIdx.x;     // 0 .. 589823
    int split = t / 294912;
    int r  = t % 294912;
    int kk = r >> 15;
    int r2 = r & 32767;
    int icb = r2 >> 11;
    int r3  = r2 & 2047;
    int oc  = r3 >> 2;
    int rot = r3 & 3;
    int g   = (rot - oc) & 3;
    int ic0 = icb * 32 + g * 8;

    half8 hv;
    #pragma unroll
    for (int e = 0; e < 8; ++e) {
        float wf = w[(size_t)(oc * 512 + ic0 + e) * 9 + kk];
        if (split == 0) {
            hv[e] = (_Float16)wf;
        } else {
            _Float16 hi = (_Float16)wf;
            hv[e] = (_Float16)((wf - (float)hi) * 2048.0f);
        }
    }
    *(half8*)(bw + (size_t)split * BPLANE +
              ((size_t)(kk * 16 + icb) * 2048 + r3) * 16) = hv;
}

// ---------------------------------------------------------------------------
// Input prep: NCHW f32 -> padded channels-last fp16 hi/lo planes.
// ---------------------------------------------------------------------------
__global__ __launch_bounds__(256) void prep_a(const float* __restrict__ in,
                                              char* __restrict__ apad)
{
    const int y = blockIdx.x;
    const int b = blockIdx.y;
    const int t = threadIdx.x;
    __shared__ float s_tile[64][65];

    for (int c = 0; c < 8; ++c) {
        __syncthreads();
        #pragma unroll
        for (int rep = 0; rep < 16; ++rep) {
            int ic_l = rep * 4 + (t >> 6);
            int x    = t & 63;
            s_tile[ic_l][x] =
                in[(((size_t)(b * 512 + c * 64 + ic_l) * 64 + y) << 6) + x];
        }
        __syncthreads();
        #pragma unroll
        for (int q = 0; q < 4; ++q) {
            int s     = q * 256 + t;           // 0..1023
            int split = s >> 9;
            int rem   = s & 511;
            int x     = rem >> 3;
            int icb_l = (rem >> 2) & 1;
            int rot   = rem & 3;
            int xx    = x + 1;
            int g     = (rot - xx) & 3;
            int ic_l0 = icb_l * 32 + g * 8;
            half8 hv;
            #pragma unroll
            for (int e = 0; e < 8; ++e) {
                float v = s_tile[ic_l0 + e][x];
                if (split == 0) {
                    hv[e] = (_Float16)v;
                } else {
                    _Float16 hi = (_Float16)v;
                    hv[e] = (_Float16)((v - (float)hi) * 2048.0f);
                }
            }
            *(half8*)(apad + (size_t)split * APLANE +
                      ((size_t)((b * 66 + y + 1) * 68 + xx) << 10) +
                      ((c * 2 + icb_l) << 6) + (rot << 4)) = hv;
        }
    }
}

// ---------------------------------------------------------------------------
// MFMA conv: implicit GEMM, fp16 x3 split precision.
// Round-8 staging/barrier structure; inner compute on 32x32x16 MFMA
// (24 instr/kk-step vs 48, ~18% fewer matrix-pipe cycles, same LDS traffic,
// same 128-reg accumulator budget).
// ---------------------------------------------------------------------------
__global__ __launch_bounds__(256, 2) void conv_mfma(
    const char* __restrict__ apad, const char* __restrict__ bw,
    const float* __restrict__ bias, float* __restrict__ out)
{
    __shared__ _Float16 sA[2][8704];
    __shared__ _Float16 sB[2][4096];

    const int tid = threadIdx.x;
    const int l   = tid & 63;
    const int wid = tid >> 6;
    const int m   = wid & 1;           // y-row within tile
    const int n   = wid >> 1;          // oc half
    const int l31 = l & 31;
    const int h   = l >> 5;            // k-half within 16-k window
    const int oc0 = blockIdx.x * 128;
    const int y0  = blockIdx.y * 2;
    const int b   = blockIdx.z;

    f32x16 accm[2][2], accc[2][2];
    #pragma unroll
    for (int i = 0; i < 2; ++i)
        #pragma unroll
        for (int j = 0; j < 2; ++j) {
            #pragma unroll
            for (int e = 0; e < 16; ++e) { accm[i][j][e] = 0.f; accc[i][j][e] = 0.f; }
        }

    auto stageA = [&](int icb) {
        for (int c = wid; c < 17; c += 4) {
            int s  = c * 64 + l;
            int px = s >> 2;
            int r  = px / 68;
            int xx = px - r * 68;
            const char* src = apad +
                ((size_t)((b * 66 + y0 + r) * 68 + xx) << 10) +
                (icb << 6) + ((s & 3) << 4);
            GLL16(src,          &sA[0][c * 512]);
            GLL16(src + APLANE, &sA[1][c * 512]);
        }
    };

    u32x4 breg[4];
    auto loadB = [&](int kk, int icb) {
        const char* bb = bw + ((size_t)(kk * 16 + icb) * 2048 + oc0 * 4) * 16;
        breg[0] = *(const u32x4*)(bb + (size_t)tid * 16);
        breg[1] = *(const u32x4*)(bb + (size_t)(tid + 256) * 16);
        breg[2] = *(const u32x4*)(bb + BPLANE + (size_t)tid * 16);
        breg[3] = *(const u32x4*)(bb + BPLANE + (size_t)(tid + 256) * 16);
    };
    auto writeB = [&]() {
        *(u32x4*)&sB[0][(size_t)tid * 8]         = breg[0];
        *(u32x4*)&sB[0][(size_t)(tid + 256) * 8] = breg[1];
        *(u32x4*)&sB[1][(size_t)tid * 8]         = breg[2];
        *(u32x4*)&sB[1][(size_t)(tid + 256) * 8] = breg[3];
    };

    // B fragment slots loop-invariant: lane holds k-chunk (2w+h) of oc l31.
    int bslot[2][2];
    #pragma unroll
    for (int j2 = 0; j2 < 2; ++j2)
        #pragma unroll
        for (int w = 0; w < 2; ++w) {
            int ocl = n * 64 + 32 * j2 + l31;
            int c   = 2 * w + h;
            bslot[j2][w] = ((ocl << 2) | ((c + ocl) & 3)) * 8;
        }

    stageA(0);
    loadB(0, 0);
    asm volatile("s_waitcnt vmcnt(0)" ::: "memory");
    writeB();
    __syncthreads();

    int kk = 0, icb = 0;
    for (int it = 0; it < 144; ++it) {
        int nkk = kk + 1, nicb = icb;
        if (nkk == 9) { nkk = 0; ++nicb; }
        const bool have_next = (it < 143);
        if (have_next) loadB(nkk, nicb);

        const int ky = kk / 3;
        const int kx = kk - 3 * ky;
        half8 bh[2][2], bl[2][2];
        #pragma unroll
        for (int j2 = 0; j2 < 2; ++j2)
            #pragma unroll
            for (int w = 0; w < 2; ++w) {
                bh[j2][w] = *(const half8*)&sB[0][bslot[j2][w]];
                bl[j2][w] = *(const half8*)&sB[1][bslot[j2][w]];
            }
        const int r = m + ky;
        #pragma unroll
        for (int i2 = 0; i2 < 2; ++i2) {
            int xx = 32 * i2 + l31 + kx;
            int px = r * 68 + xx;
            half8 ah[2], al[2];
            #pragma unroll
            for (int w = 0; w < 2; ++w) {
                int c    = 2 * w + h;
                int slot = ((px << 2) | ((c + px) & 3)) * 8;
                ah[w] = *(const half8*)&sA[0][slot];
                al[w] = *(const half8*)&sA[1][slot];
            }
            #pragma unroll
            for (int j2 = 0; j2 < 2; ++j2)
                #pragma unroll
                for (int w = 0; w < 2; ++w) {
                    accm[i2][j2] = __builtin_amdgcn_mfma_f32_32x32x16_f16(ah[w], bh[j2][w], accm[i2][j2], 0, 0, 0);
                    accc[i2][j2] = __builtin_amdgcn_mfma_f32_32x32x16_f16(ah[w], bl[j2][w], accc[i2][j2], 0, 0, 0);
                    accc[i2][j2] = __builtin_amdgcn_mfma_f32_32x32x16_f16(al[w], bh[j2][w], accc[i2][j2], 0, 0, 0);
                }
        }
        __syncthreads();
        if (have_next) {
            writeB();
            if (nkk == 0) {
                stageA(nicb);
                asm volatile("s_waitcnt vmcnt(0)" ::: "memory");
            }
        }
        __syncthreads();
        kk = nkk; icb = nicb;
    }

    // Epilogue. C/D 32x32 layout: col(oc)=lane&31, row(px)=(reg&3)+8*(reg>>2)+4*h.
    const float inv2048 = 4.8828125e-4f;
    #pragma unroll
    for (int i2 = 0; i2 < 2; ++i2) {
        #pragma unroll
        for (int j2 = 0; j2 < 2; ++j2) {
            int oc = oc0 + n * 64 + 32 * j2 + l31;
            float bv = bias[oc];
            #pragma unroll
            for (int q = 0; q < 4; ++q) {
                int x = 32 * i2 + 4 * h + 8 * q;
                f32x4 o;
                #pragma unroll
                for (int j = 0; j < 4; ++j) {
                    float v = accm[i2][j2][4 * q + j]
                            + accc[i2][j2][4 * q + j] * inv2048 + bv;
                    o[j] = v > 0.f ? v : 0.f;
                }
                *(f32x4*)(out + (((size_t)(b * 512 + oc) << 12) +
                                 ((y0 + m) << 6) + x)) = o;
            }
        }
    }
}

// ---------------------------------------------------------------------------
// Head-weight prep: pack cls_w(18x512)+bbox_w(36x512), pad to 64 oc, into
// MFMA B-fragment layout: [plane2][ks16][g4][oc64][8 halfs]. + bias64.
// ---------------------------------------------------------------------------
__global__ __launch_bounds__(256) void prep_hw(
    const float* __restrict__ cls_w, const float* __restrict__ bbox_w,
    const float* __restrict__ cls_b, const float* __restrict__ bbox_b,
    char* __restrict__ bhw)
{
    int t = blockIdx.x * 256 + threadIdx.x;   // 0..8191
    int plane = t >> 12;
    int r  = t & 4095;
    int ks = r >> 8;
    int g  = (r >> 6) & 3;
    int oc = r & 63;
    int ic0 = ks * 32 + g * 8;

    half8 hv;
    #pragma unroll
    for (int e = 0; e < 8; ++e) {
        int ic = ic0 + e;
        float wf = 0.f;
        if (oc < 18)      wf = cls_w[oc * 512 + ic];
        else if (oc < 54) wf = bbox_w[(oc - 18) * 512 + ic];
        if (plane == 0) {
            hv[e] = (_Float16)wf;
        } else {
            _Float16 hi = (_Float16)wf;
            hv[e] = (_Float16)((wf - (float)hi) * 2048.0f);
        }
    }
    *(half8*)(bhw + (size_t)plane * 65536 +
              (size_t)(((ks * 4 + g) * 64 + oc)) * 16) = hv;

    if (blockIdx.x == 0 && threadIdx.x < 64) {
        int o = threadIdx.x;
        float bv = 0.f;
        if (o < 18)      bv = cls_b[o];
        else if (o < 54) bv = bbox_b[o - 18];
        *(float*)(bhw + 131072 + o * 4) = bv;
    }
}

// ---------------------------------------------------------------------------
// Heads MFMA: M=px, N=64(oc padded), K=512, fp16x3. No LDS, no barriers.
// ---------------------------------------------------------------------------
__global__ __launch_bounds__(256) void heads_mfma(
    const float* __restrict__ h, const char* __restrict__ bhw,
    float* __restrict__ hs)
{
    const int tid = threadIdx.x;
    const int l   = tid & 63;
    const int w   = tid >> 6;
    const int g   = l >> 4;
    const int l15 = l & 15;
    const int b   = blockIdx.y;
    const int px0 = blockIdx.x * 256 + w * 64;

    f32x4 accm[4][4], accc[4][4];
    #pragma unroll
    for (int i = 0; i < 4; ++i)
        #pragma unroll
        for (int j = 0; j < 4; ++j) {
            accm[i][j] = (f32x4){0.f, 0.f, 0.f, 0.f};
            accc[i][j] = (f32x4){0.f, 0.f, 0.f, 0.f};
        }

    const float* hb = h + (((size_t)(b * 512 + g * 8)) << 12) + px0 + l15;
    const float* bias64 = (const float*)(bhw + 131072);

    #pragma unroll 2
    for (int ks = 0; ks < 16; ++ks) {
        half8 bh[4], bl[4];
        #pragma unroll
        for (int jf = 0; jf < 4; ++jf) {
            size_t slot = (size_t)(((ks * 4 + g) * 64 + 16 * jf + l15)) * 16;
            bh[jf] = *(const half8*)(bhw + slot);
            bl[jf] = *(const half8*)(bhw + 65536 + slot);
        }
        #pragma unroll
        for (int i = 0; i < 4; ++i) {
            float af[8];
            #pragma unroll
            for (int e = 0; e < 8; ++e)
                af[e] = hb[(((size_t)(ks * 32 + e)) << 12) + i * 16];
            half8 ah, al;
            #pragma unroll
            for (int e = 0; e < 8; ++e) {
                _Float16 hi = (_Float16)af[e];
                ah[e] = hi;
                al[e] = (_Float16)((af[e] - (float)hi) * 2048.0f);
            }
            #pragma unroll
            for (int jf = 0; jf < 4; ++jf) {
                accm[i][jf] = __builtin_amdgcn_mfma_f32_16x16x32_f16(ah, bh[jf], accm[i][jf], 0, 0, 0);
                accc[i][jf] = __builtin_amdgcn_mfma_f32_16x16x32_f16(ah, bl[jf], accc[i][jf], 0, 0, 0);
                accc[i][jf] = __builtin_amdgcn_mfma_f32_16x16x32_f16(al, bh[jf], accc[i][jf], 0, 0, 0);
            }
        }
    }

    const float inv2048 = 4.8828125e-4f;
    float bv[4];
    #pragma unroll
    for (int jf = 0; jf < 4; ++jf) bv[jf] = bias64[16 * jf + l15];

    #pragma unroll
    for (int i = 0; i < 4; ++i) {
        #pragma unroll
        for (int jf = 0; jf < 4; ++jf) {
            int oc = 16 * jf + l15;
            #pragma unroll
            for (int j = 0; j < 4; ++j) {
                int px = px0 + i * 16 + g * 4 + j;
                float v = accm[i][jf][j] + accc[i][jf][j] * inv2048 + bv[jf];
                hs[(((size_t)(b * 4096 + px)) << 6) + oc] = v;
            }
        }
    }
}

// ---------------------------------------------------------------------------
// Decode: softmax + box decode + min-size mask from hs[b][px][64].
// ---------------------------------------------------------------------------
__global__ __launch_bounds__(256) void heads_decode(
    const float* __restrict__ hs, const float* __restrict__ im_info,
    float* __restrict__ scores, float* __restrict__ boxes)
{
    const int gid = blockIdx.x * 256 + threadIdx.x;   // 0..32767
    const int b = gid >> 12;
    const int s = gid & 4095;

    float acc[56];
    const f32x4* hp = (const f32x4*)(hs + ((size_t)gid << 6));
    #pragma unroll
    for (int q = 0; q < 14; ++q) {
        f32x4 v = hp[q];
        acc[4 * q + 0] = v[0]; acc[4 * q + 1] = v[1];
        acc[4 * q + 2] = v[2]; acc[4 * q + 3] = v[3];
    }

    const float info0 = im_info[b * 3 + 0];
    const float info1 = im_info[b * 3 + 1];
    const float info2 = im_info[b * 3 + 2];
    const float maxx = info1 - 1.0f, maxy = info0 - 1.0f;
    const float min_size = 16.0f * info2;
    const int y = s >> 6, x = s & 63;
    const float cxa = 16.f * (float)x + 8.f;
    const float cya = 16.f * (float)y + 8.f;
    const float WA[9] = {184.f, 368.f, 736.f, 128.f, 256.f, 512.f,  88.f, 176.f, 352.f};
    const float HA[9] = { 96.f, 192.f, 384.f, 128.f, 256.f, 512.f, 176.f, 352.f, 704.f};

    const int base = b * 36864 + s * 9;
    #pragma unroll
    for (int a = 0; a < 9; ++a) {
        float c0v = acc[a], c1v = acc[9 + a];
        float mm = fmaxf(c0v, c1v);
        float e0 = expf(c0v - mm), e1 = expf(c1v - mm);
        float fg = e1 / (e0 + e1);
        float dx = acc[18 + 4 * a + 0];
        float dy = acc[18 + 4 * a + 1];
        float dw = acc[18 + 4 * a + 2];
        float dh = acc[18 + 4 * a + 3];
        float cx = dx * WA[a] + cxa;
        float cy = dy * HA[a] + cya;
        float pw = expf(dw) * WA[a];
        float ph = expf(dh) * HA[a];
        float x1 = fminf(fmaxf(cx - 0.5f * pw, 0.f), maxx);
        float y1 = fminf(fmaxf(cy - 0.5f * ph, 0.f), maxy);
        float x2 = fminf(fmaxf(cx + 0.5f * pw, 0.f), maxx);
        float y2 = fminf(fmaxf(cy + 0.5f * ph, 0.f), maxy);
        bool keep = ((x2 - x1 + 1.f) >= min_size) && ((y2 - y1 + 1.f) >= min_size);
        scores[base + a] = keep ? fg : NEG_INF_F;
        float* bp = boxes + (size_t)(base + a) * 4;
        bp[0] = x1; bp[1] = y1; bp[2] = x2; bp[3] = y2;
    }
}

// ---------------------------------------------------------------------------
// Fallback f32 conv + fused heads (used only if ws too small for MFMA path).
// ---------------------------------------------------------------------------
__global__ __launch_bounds__(256) void conv3_relu(
    const float* __restrict__ in, const float* __restrict__ w,
    const float* __restrict__ bias, float* __restrict__ out)
{
    const int oc0 = blockIdx.x * 32;
    const int y0  = blockIdx.y * 4;
    const int b   = blockIdx.z;
    const int tid = threadIdx.x;
    const int xg  = tid & 31;
    const int og  = tid >> 5;

    __shared__ float s_in[8][6][68];
    __shared__ float s_w[32][8][9];

    float acc[4][4][2];
    #pragma unroll
    for (int o = 0; o < 4; ++o)
        #pragma unroll
        for (int yy = 0; yy < 4; ++yy) { acc[o][yy][0] = 0.f; acc[o][yy][1] = 0.f; }

    for (int ic0 = 0; ic0 < 512; ic0 += 8) {
        for (int e = tid; e < 8 * 6 * 66; e += 256) {
            int ic = e / 396; int r = e - ic * 396;
            int yy = r / 66;  int xx = r - yy * 66;
            int gy = y0 + yy - 1;
            int gx = xx - 1;
            float v = 0.f;
            if (gy >= 0 && gy < 64 && gx >= 0 && gx < 64)
                v = in[(((b * 512 + ic0 + ic) * 64 + gy) << 6) + gx];
            s_in[ic][yy][xx] = v;
        }
        {
            int oc = tid >> 3, ic = tid & 7;
            const float* wp = w + ((size_t)(oc0 + oc) * 512 + ic0 + ic) * 9;
            #pragma unroll
            for (int k = 0; k < 9; ++k) s_w[oc][ic][k] = wp[k];
        }
        __syncthreads();
        for (int ic = 0; ic < 8; ++ic) {
            #pragma unroll
            for (int ky = 0; ky < 3; ++ky) {
                #pragma unroll
                for (int kx = 0; kx < 3; ++kx) {
                    const int k = ky * 3 + kx;
                    float w0 = s_w[og][ic][k];
                    float w1 = s_w[og + 8][ic][k];
                    float w2 = s_w[og + 16][ic][k];
                    float w3 = s_w[og + 24][ic][k];
                    #pragma unroll
                    for (int yy = 0; yy < 4; ++yy) {
                        float i0 = s_in[ic][yy + ky][xg + kx];
                        float i1 = s_in[ic][yy + ky][xg + 32 + kx];
                        acc[0][yy][0] = fmaf(w0, i0, acc[0][yy][0]);
                        acc[0][yy][1] = fmaf(w0, i1, acc[0][yy][1]);
                        acc[1][yy][0] = fmaf(w1, i0, acc[1][yy][0]);
                        acc[1][yy][1] = fmaf(w1, i1, acc[1][yy][1]);
                        acc[2][yy][0] = fmaf(w2, i0, acc[2][yy][0]);
                        acc[2][yy][1] = fmaf(w2, i1, acc[2][yy][1]);
                        acc[3][yy][0] = fmaf(w3, i0, acc[3][yy][0]);
                        acc[3][yy][1] = fmaf(w3, i1, acc[3][yy][1]);
                    }
                }
            }
        }
        __syncthreads();
    }

    #pragma unroll
    for (int o = 0; o < 4; ++o) {
        int oc = oc0 + og + 8 * o;
        float bv = bias[oc];
        #pragma unroll
        for (int yy = 0; yy < 4; ++yy) {
            int y = y0 + yy;
            float* op = out + (((b * 512 + oc) * 64 + y) << 6);
            float v0 = acc[o][yy][0] + bv; v0 = v0 > 0.f ? v0 : 0.f;
            float v1 = acc[o][yy][1] + bv; v1 = v1 > 0.f ? v1 : 0.f;
            op[xg] = v0; op[xg + 32] = v1;
        }
    }
}

__global__ __launch_bounds__(256) void heads(
    const float* __restrict__ h, const float* __restrict__ cls_w,
    const float* __restrict__ cls_b, const float* __restrict__ bbox_w,
    const float* __restrict__ bbox_b, const float* __restrict__ im_info,
    float* __restrict__ scores, float* __restrict__ boxes)
{
    const int tid = threadIdx.x;
    const int b = blockIdx.x >> 4;
    const int s = ((blockIdx.x & 15) << 8) + tid;

    __shared__ float s_w[54][64];

    float acc[54];
    #pragma unroll
    for (int o = 0; o < 54; ++o) acc[o] = 0.f;

    for (int c0 = 0; c0 < 512; c0 += 64) {
        __syncthreads();
        for (int e = tid; e < 54 * 64; e += 256) {
            int oc = e >> 6, i = e & 63;
            float v = (oc < 18) ? cls_w[oc * 512 + c0 + i]
                                : bbox_w[(oc - 18) * 512 + c0 + i];
            s_w[oc][i] = v;
        }
        __syncthreads();
        for (int i = 0; i < 64; ++i) {
            float hv = h[((b * 512 + c0 + i) << 12) + s];
            #pragma unroll
            for (int o = 0; o < 54; ++o) acc[o] = fmaf(hv, s_w[o][i], acc[o]);
        }
    }
    #pragma unroll
    for (int o = 0; o < 18; ++o) acc[o] += cls_b[o];
    #pragma unroll
    for (int o = 0; o < 36; ++o) acc[18 + o] += bbox_b[o];

    const float info0 = im_info[b * 3 + 0];
    const float info1 = im_info[b * 3 + 1];
    const float info2 = im_info[b * 3 + 2];
    const float maxx = info1 - 1.0f, maxy = info0 - 1.0f;
    const float min_size = 16.0f * info2;
    const int y = s >> 6, x = s & 63;
    const float cxa = 16.f * (float)x + 8.f;
    const float cya = 16.f * (float)y + 8.f;
    const float WA[9] = {184.f, 368.f, 736.f, 128.f, 256.f, 512.f,  88.f, 176.f, 352.f};
    const float HA[9] = { 96.f, 192.f, 384.f, 128.f, 256.f, 512.f, 176.f, 352.f, 704.f};

    const int base = b * 36864 + s * 9;
    #pragma unroll
    for (int a = 0; a < 9; ++a) {
        float c0v = acc[a], c1v = acc[9 + a];
        float mm = fmaxf(c0v, c1v);
        float e0 = expf(c0v - mm), e1 = expf(c1v - mm);
        float fg = e1 / (e0 + e1);
        float dx = acc[18 + 4 * a + 0];
        float dy = acc[18 + 4 * a + 1];
        float dw = acc[18 + 4 * a + 2];
        float dh = acc[18 + 4 * a + 3];
        float cx = dx * WA[a] + cxa;
        float cy = dy * HA[a] + cya;
        float pw = expf(dw) * WA[a];
        float ph = expf(dh) * HA[a];
        float x1 = fminf(fmaxf(cx - 0.5f * pw, 0.f), maxx);
        float y1 = fminf(fmaxf(cy - 0.5f * ph, 0.f), maxy);
        float x2 = fminf(fmaxf(cx + 0.5f * pw, 0.f), maxx);
        float y2 = fminf(fmaxf(cy + 0.5f * ph, 0.f), maxy);
        bool keep = ((x2 - x1 + 1.f) >= min_size) && ((y2 - y1 + 1.f) >= min_size);
        scores[base + a] = keep ? fg : NEG_INF_F;
        float* bp = boxes + (size_t)(base + a) * 4;
        bp[0] = x1; bp[1] = y1; bp[2] = x2; bp[3] = y2;
    }
}

// ---------------------------------------------------------------------------
// Exact top-2000 via 16-bit histogram select on key-high = ~ordf(score).
// ---------------------------------------------------------------------------
__global__ void hist_k(const float* __restrict__ scores, uint32_t* __restrict__ hist)
{
    int gidx = blockIdx.x * 256 + threadIdx.x;
    int b = gidx / 36864, i = gidx - b * 36864;
    uint32_t kh = ~ordf(scores[b * 36864 + i]);
    atomicAdd(&hist[((size_t)b << 16) + (kh >> 16)], 1u);
}

__global__ __launch_bounds__(1024) void scan_k(const uint32_t* __restrict__ hist,
                                               uint32_t* __restrict__ cnt)
{
    const int b = blockIdx.x;
    const int t = threadIdx.x;
    __shared__ uint32_t part[1024];
    const uint32_t* hb = hist + ((size_t)b << 16);

    uint32_t own = 0;
    #pragma unroll 4
    for (int k = 0; k < 64; ++k) own += hb[t * 64 + k];
    part[t] = own;
    __syncthreads();
    for (int off = 1; off < 1024; off <<= 1) {
        uint32_t v = (t >= off) ? part[t - off] : 0u;
        __syncthreads();
        part[t] += v;
        __syncthreads();
    }
    uint32_t incl = part[t];
    uint32_t excl = incl - own;
    if (excl < 2000u && incl >= 2000u) {
        uint32_t c = excl;
        for (int k = 0; k < 64; ++k) {
            uint32_t hh = hb[t * 64 + k];
            if (c + hh >= 2000u) { cnt[16 + b] = t * 64 + k; cnt[24 + b] = c; break; }
            c += hh;
        }
    }
}

__global__ void compact_k(const float* __restrict__ scores,
                          uint32_t* __restrict__ cnt,
                          uint64_t* __restrict__ cand)
{
    int gidx = blockIdx.x * 256 + threadIdx.x;
    int b = gidx / 36864, i = gidx - b * 36864;
    float sc = scores[b * 36864 + i];
    uint32_t kh = ~ordf(sc);
    uint32_t bin = kh >> 16;
    uint32_t T = cnt[16 + b];
    uint64_t key = ((uint64_t)kh << 32) | (uint32_t)i;
    if (bin < T) {
        uint32_t p = atomicAdd(&cnt[b * 2], 1u);
        cand[((size_t)b << 12) + p] = key;
    } else if (bin == T) {
        uint32_t p = atomicAdd(&cnt[b * 2 + 1], 1u);
        if (p < 2048u) cand[((size_t)b << 12) + 4095 - p] = key;
    }
}

__global__ __launch_bounds__(1024) void sort4096_k(uint64_t* __restrict__ cand)
{
    const int b = blockIdx.x;
    const int tid = threadIdx.x;
    __shared__ uint64_t s[4096];
    for (int i = tid; i < 4096; i += 1024) s[i] = cand[((size_t)b << 12) + i];
    __syncthreads();
    for (int k = 2; k <= 4096; k <<= 1) {
        for (int j = k >> 1; j > 0; j >>= 1) {
            for (int t2 = tid; t2 < 2048; t2 += 1024) {
                int i = ((t2 & ~(j - 1)) << 1) | (t2 & (j - 1));
                int ixj = i + j;
                bool up = ((i & k) == 0);
                uint64_t a = s[i], c = s[ixj];
                if ((a > c) == up) { s[i] = c; s[ixj] = a; }
            }
            __syncthreads();
        }
    }
    for (int i = tid; i < 4096; i += 1024) cand[((size_t)b << 12) + i] = s[i];
}

__global__ void gather_top(const uint64_t* __restrict__ cand,
                           const float* __restrict__ scores,
                           const float* __restrict__ boxes,
                           float* __restrict__ ts, float* __restrict__ tb)
{
    int gidx = blockIdx.x * 256 + threadIdx.x;
    if (gidx >= 8 * 2000) return;
    int b = gidx / 2000, r = gidx - b * 2000;
    uint64_t k = cand[((size_t)b << 12) + r];
    int idx = (int)(uint32_t)k;
    ts[b * 2048 + r] = scores[b * 36864 + idx];
    const float* sp = boxes + ((size_t)b * 36864 + idx) * 4;
    float* dp = tb + ((size_t)b * 2048 + r) * 4;
    dp[0] = sp[0]; dp[1] = sp[1]; dp[2] = sp[2]; dp[3] = sp[3];
}

// ---------------------------------------------------------------------------
// NMS: IoU bitmask build + serial greedy scan (1 wave per batch).
// ---------------------------------------------------------------------------
__global__ __launch_bounds__(64) void nms_mask(const float* __restrict__ tb,
                                               uint64_t* __restrict__ mask)
{
    const int b  = blockIdx.z;
    const int rb = blockIdx.y;
    const int cb = blockIdx.x;
    const int t  = threadIdx.x;
    __shared__ float cbox[64][4];
    const int col0 = cb * 64;
    {
        int c = col0 + t;
        if (c < 2000) {
            const float* p = tb + ((size_t)b * 2048 + c) * 4;
            cbox[t][0] = p[0]; cbox[t][1] = p[1]; cbox[t][2] = p[2]; cbox[t][3] = p[3];
        } else {
            cbox[t][0] = 0.f; cbox[t][1] = 0.f; cbox[t][2] = -1.f; cbox[t][3] = -1.f;
        }
    }
    __syncthreads();
    int row = rb * 64 + t;
    if (row >= 2000) return;
    const float* p = tb + ((size_t)b * 2048 + row) * 4;
    float x1 = p[0], y1 = p[1], x2 = p[2], y2 = p[3];
    float area = (x2 - x1 + 1.f) * (y2 - y1 + 1.f);
    uint64_t bits = 0;
    int ncol = 2000 - col0; if (ncol > 64) ncol = 64;
    for (int j = 0; j < ncol; ++j) {
        float xx1 = fmaxf(x1, cbox[j][0]);
        float yy1 = fmaxf(y1, cbox[j][1]);
        float xx2 = fminf(x2, cbox[j][2]);
        float yy2 = fminf(y2, cbox[j][3]);
        float iw = fmaxf(xx2 - xx1 + 1.f, 0.f);
        float ih = fmaxf(yy2 - yy1 + 1.f, 0.f);
        float inter = iw * ih;
        float areaj = (cbox[j][2] - cbox[j][0] + 1.f) * (cbox[j][3] - cbox[j][1] + 1.f);
        float iou = inter / (area + areaj - inter);
        if (iou > 0.7f) bits |= (1ull << j);
    }
    mask[((size_t)b * 2048 + row) * 32 + cb] = bits;
}

// Serial greedy scan: deep register prefetch + scalar readlane chain.
__global__ __launch_bounds__(64) void nms_seq(const uint64_t* __restrict__ mask,
                                              const float* __restrict__ ts,
                                              uint64_t* __restrict__ fkeys)
{
    const int b = blockIdx.x;
    const int lane = threadIdx.x;
    __shared__ uint64_t kw[32];        // keep bits, one u64 per 64 rows
    const uint64_t* mrow = mask + (size_t)b * 2048 * 32;
    const bool ml = (lane < 32);
    uint64_t remv = 0;
    uint32_t cur_lo = 0, cur_hi = 0;   // scalar copy of remv word (i>>6)
    uint64_t kcur = 0;                 // scalar keep accumulator for word

    uint64_t bufA[16], bufB[16];

#define LOADG(buf, gidx) do { int base_ = (gidx) * 16;                        \
    _Pragma("unroll")                                                         \
    for (int k_ = 0; k_ < 16; ++k_) {                                         \
        int r_ = base_ + k_;                                                  \
        buf[k_] = (ml && r_ < 2000) ? mrow[(size_t)r_ * 32 + lane] : 0ull;    \
    } } while (0)

#define PROCG(buf, gidx) do { int base_ = (gidx) * 16;                        \
    _Pragma("unroll")                                                         \
    for (int k_ = 0; k_ < 16; ++k_) {                                         \
        int i_ = base_ + k_;                                                  \
        int w_ = i_ >> 6;                                                     \
        int bit_ = i_ & 63;                                                   \
        if (bit_ == 0) {                                                      \
            cur_lo = __builtin_amdgcn_readlane((uint32_t)remv, w_);           \
            cur_hi = __builtin_amdgcn_readlane((uint32_t)(remv >> 32), w_);   \
            kcur = 0;                                                         \
        }                                                                     \
        uint32_t sw_ = (bit_ < 32) ? cur_lo : cur_hi;                         \
        if (!((sw_ >> (bit_ & 31)) & 1u)) {                                   \
            kcur |= (1ull << bit_);                                           \
            if (ml) remv |= buf[k_];                                          \
            cur_lo |= __builtin_amdgcn_readlane((uint32_t)buf[k_], w_);       \
            cur_hi |= __builtin_amdgcn_readlane((uint32_t)(buf[k_] >> 32), w_);\
        }                                                                     \
        if (bit_ == 63 || i_ == 1999) { if (lane == 0) kw[w_] = kcur; }       \
    } } while (0)

    LOADG(bufA, 0);
    LOADG(bufB, 1);
    for (int gq = 0; gq < 125; gq += 2) {          // 125 groups of 16 = 2000
        PROCG(bufA, gq);
        LOADG(bufA, gq + 2);
        if (gq + 1 < 125) {
            PROCG(bufB, gq + 1);
            LOADG(bufB, gq + 3);
        }
    }
#undef LOADG
#undef PROCG

    __syncthreads();
    for (int i = lane; i < 2048; i += 64) {
        uint64_t k;
        if (i < 2000) {
            bool kp = (kw[i >> 6] >> (i & 63)) & 1ull;
            float sc = kp ? ts[b * 2048 + i] : NEG_INF_F;
            k = ((uint64_t)(~ordf(sc)) << 32) | (uint32_t)i;
        } else {
            k = ~0ull;
        }
        fkeys[b * 2048 + i] = k;
    }
}

__global__ __launch_bounds__(1024) void final_out(const uint64_t* __restrict__ fkeys,
                                                  const float* __restrict__ tb,
                                                  float* __restrict__ out)
{
    const int b = blockIdx.x;
    const int tid = threadIdx.x;
    __shared__ uint64_t s[2048];
    for (int i = tid; i < 2048; i += 1024) s[i] = fkeys[b * 2048 + i];
    __syncthreads();
    for (int k = 2; k <= 2048; k <<= 1) {
        for (int j = k >> 1; j > 0; j >>= 1) {
            for (int t = tid; t < 2048; t += 1024) {
                int ixj = t ^ j;
                if (ixj > t) {
                    bool up = ((t & k) == 0);
                    uint64_t a = s[t], c = s[ixj];
                    if ((a > c) == up) { s[t] = c; s[ixj] = a; }
                }
            }
            __syncthreads();
        }
    }
    for (int r = tid; r < 300; r += 1024) {
        int idx = (int)(uint32_t)s[r];
        const float* bp = tb + ((size_t)b * 2048 + idx) * 4;
        float* op = out + (size_t)(b * 300 + r) * 5;
        op[0] = (float)b;
        op[1] = bp[0]; op[2] = bp[1]; op[3] = bp[2]; op[4] = bp[3];
    }
}

// ---------------------------------------------------------------------------
extern "C" void kernel_launch(void* const* d_in, const int* in_sizes, int n_in,
                              void* d_out, int out_size, void* d_ws, size_t ws_size,
                              hipStream_t stream)
{
    const float* im_data = (const float*)d_in[0];
    const float* im_info = (const float*)d_in[1];
    const float* conv_w  = (const float*)d_in[2];
    const float* conv_b  = (const float*)d_in[3];
    const float* cls_w   = (const float*)d_in[4];
    const float* cls_b   = (const float*)d_in[5];
    const float* bbox_w  = (const float*)d_in[6];
    const float* bbox_b  = (const float*)d_in[7];
    float* out = (float*)d_out;

    char* ws = (char*)d_ws;
    float*    h      = (float*)(ws);                      // 67,108,864
    float*    scores = (float*)(ws + 67108864ull);        // 1,179,648
    float*    boxes  = (float*)(ws + 68288512ull);        // 4,718,592
    uint32_t* hist   = (uint32_t*)(ws + 73007104ull);     // 2,097,152
    uint32_t* cnt    = (uint32_t*)(ws + 75104256ull);     // 1,024
    uint64_t* cand   = (uint64_t*)(ws + 75105280ull);     // 262,144
    float*    ts     = (float*)(ws + 75367424ull);        // 65,536
    float*    tb     = (float*)(ws + 75432960ull);        // 262,144
    uint64_t* mask   = (uint64_t*)(ws + 75695104ull);     // 4,194,304
    uint64_t* fkeys  = (uint64_t*)(ws + 79889408ull);     // 131,072 -> 80,020,480
    float*    hs     = (float*)(ws + 80020480ull);        // 8,388,608 (dead-apad zone)
    char*     bhw    = ws + 88409088ull;                  // 131,328   (dead-apad zone)

    char* apad = ws + 67108864ull;                        // 73,531,392 (conv phase only)
    char* bwp  = ws + 140640256ull;                       // 9,437,184
    const size_t NEED_FULL = 150077440ull;

    if (ws_size >= NEED_FULL) {
        hipMemsetAsync(apad, 0, 73531392ull, stream);
        prep_w<<<dim3(2304), 256, 0, stream>>>(conv_w, bwp);
        prep_a<<<dim3(64, 8), 256, 0, stream>>>(im_data, apad);
        conv_mfma<<<dim3(4, 32, 8), 256, 0, stream>>>(apad, bwp, conv_b, h);
        // apad dead from here; bhw/hs live in its footprint.
        prep_hw<<<dim3(32), 256, 0, stream>>>(cls_w, bbox_w, cls_b, bbox_b, bhw);
        heads_mfma<<<dim3(16, 8), 256, 0, stream>>>(h, bhw, hs);
        heads_decode<<<dim3(128), 256, 0, stream>>>(hs, im_info, scores, boxes);
    } else {
        conv3_relu<<<dim3(16, 16, 8), 256, 0, stream>>>(im_data, conv_w, conv_b, h);
        heads<<<dim3(128), 256, 0, stream>>>(h, cls_w, cls_b, bbox_w, bbox_b, im_info,
                                             scores, boxes);
    }

    hipMemsetAsync(hist, 0, 2097152ull + 1024ull, stream);
    hipMemsetAsync(cand, 0xFF, 262144ull, stream);
    hist_k<<<dim3(1152), 256, 0, stream>>>(scores, hist);
    scan_k<<<dim3(8), 1024, 0, stream>>>(hist, cnt);
    compact_k<<<dim3(1152), 256, 0, stream>>>(scores, cnt, cand);
    sort4096_k<<<dim3(8), 1024, 0, stream>>>(cand);
    gather_top<<<dim3(63), 256, 0, stream>>>(cand, scores, boxes, ts, tb);
    nms_mask<<<dim3(32, 32, 8), 64, 0, stream>>>(tb, mask);
    nms_seq<<<dim3(8), 64, 0, stream>>>(mask, ts, fkeys);
    final_out<<<dim3(8), 1024, 0, stream>>>(fkeys, tb, out);
}

// Round 12
// 938.800 us; speedup vs baseline: 1.0956x; 1.0956x over previous
//
#include <hip/hip_runtime.h>
#include <stdint.h>

#define NEG_INF_F (-1e30f)

typedef _Float16 half8 __attribute__((ext_vector_type(8)));
typedef float f32x4 __attribute__((ext_vector_type(4)));
typedef uint32_t u32x4 __attribute__((ext_vector_type(4)));

__device__ __forceinline__ uint32_t ordf(float f) {
    uint32_t u = __float_as_uint(f);
    return u ^ ((u >> 31) ? 0xFFFFFFFFu : 0x80000000u);
}

#define GLL16(g, l) __builtin_amdgcn_global_load_lds( \
    (const __attribute__((address_space(1))) void*)(g), \
    (__attribute__((address_space(3))) void*)(l), 16, 0, 0)

// Apad: [split][b][yy 0..65][xx 0..67][icb 16][rot 4][8 fp16]  (pixel = 1024 B)
// Bw:   [split][kk 9][icb 16][oc 512][rot 4][8 fp16]; rot = (g + oc) & 3.
#define APLANE 36765696ull
#define BPLANE 4718592ull

// ---------------------------------------------------------------------------
// Halo zero: zero ONLY the apad border pixels prep_a never writes
// (yy=0,65 all xx; yy=1..64, xx in {0,65,66,67}) -- 6.4 MB vs 73.5 MB memset.
// ---------------------------------------------------------------------------
__global__ __launch_bounds__(256) void halo_zero(char* __restrict__ apad)
{
    int t = blockIdx.x * 256 + threadIdx.x;     // 0 .. 401407
    int chunk = t & 63;
    int r  = t >> 6;                            // 0 .. 6271
    int p  = r % 392;
    int bs = r / 392;                           // b*2 + split
    int split = bs & 1;
    int b     = bs >> 1;
    int yy, xx;
    if (p < 68)       { yy = 0;  xx = p; }
    else if (p < 136) { yy = 65; xx = p - 68; }
    else {
        int q = p - 136;
        yy = 1 + (q >> 2);
        int s2 = q & 3;
        xx = (s2 == 0) ? 0 : 64 + s2;
    }
    *(f32x4*)(apad + (size_t)split * APLANE +
              ((size_t)((b * 66 + yy) * 68 + xx) << 10) + chunk * 16) =
        (f32x4){0.f, 0.f, 0.f, 0.f};
}

// ---------------------------------------------------------------------------
// Conv weight prep: OIHW f32 -> fp16 hi plane + (lo*2048) plane, rotated slots.
// ---------------------------------------------------------------------------
__global__ __launch_bounds__(256) void prep_w(const float* __restrict__ w,
                                              char* __restrict__ bw)
{
    int t = blockIdx.x * 256 + threadIdx.x;     // 0 .. 589823
    int split = t / 294912;
    int r  = t % 294912;
    int kk = r >> 15;
    int r2 = r & 32767;
    int icb = r2 >> 11;
    int r3  = r2 & 2047;
    int oc  = r3 >> 2;
    int rot = r3 & 3;
    int g   = (rot - oc) & 3;
    int ic0 = icb * 32 + g * 8;

    half8 hv;
    #pragma unroll
    for (int e = 0; e < 8; ++e) {
        float wf = w[(size_t)(oc * 512 + ic0 + e) * 9 + kk];
        if (split == 0) {
            hv[e] = (_Float16)wf;
        } else {
            _Float16 hi = (_Float16)wf;
            hv[e] = (_Float16)((wf - (float)hi) * 2048.0f);
        }
    }
    *(half8*)(bw + (size_t)split * BPLANE +
              ((size_t)(kk * 16 + icb) * 2048 + r3) * 16) = hv;
}

// ---------------------------------------------------------------------------
// Input prep: NCHW f32 -> padded channels-last fp16 hi/lo planes.
// ---------------------------------------------------------------------------
__global__ __launch_bounds__(256) void prep_a(const float* __restrict__ in,
                                              char* __restrict__ apad)
{
    const int y = blockIdx.x;
    const int b = blockIdx.y;
    const int t = threadIdx.x;
    __shared__ float s_tile[64][65];

    for (int c = 0; c < 8; ++c) {
        __syncthreads();
        #pragma unroll
        for (int rep = 0; rep < 16; ++rep) {
            int ic_l = rep * 4 + (t >> 6);
            int x    = t & 63;
            s_tile[ic_l][x] =
                in[(((size_t)(b * 512 + c * 64 + ic_l) * 64 + y) << 6) + x];
        }
        __syncthreads();
        #pragma unroll
        for (int q = 0; q < 4; ++q) {
            int s     = q * 256 + t;           // 0..1023
            int split = s >> 9;
            int rem   = s & 511;
            int x     = rem >> 3;
            int icb_l = (rem >> 2) & 1;
            int rot   = rem & 3;
            int xx    = x + 1;
            int g     = (rot - xx) & 3;
            int ic_l0 = icb_l * 32 + g * 8;
            half8 hv;
            #pragma unroll
            for (int e = 0; e < 8; ++e) {
                float v = s_tile[ic_l0 + e][x];
                if (split == 0) {
                    hv[e] = (_Float16)v;
                } else {
                    _Float16 hi = (_Float16)v;
                    hv[e] = (_Float16)((v - (float)hi) * 2048.0f);
                }
            }
            *(half8*)(apad + (size_t)split * APLANE +
                      ((size_t)((b * 66 + y + 1) * 68 + xx) << 10) +
                      ((c * 2 + icb_l) << 6) + (rot << 4)) = hv;
        }
    }
}

// ---------------------------------------------------------------------------
// MFMA conv: implicit GEMM, fp16 x3 split precision.
// Round-8 proven structure: 128 px (2 y-rows) x 128 oc, 4 waves (2x2),
// sB single-buffer staged via registers, 2 barriers per kk-step.
// ---------------------------------------------------------------------------
__global__ __launch_bounds__(256, 2) void conv_mfma(
    const char* __restrict__ apad, const char* __restrict__ bw,
    const float* __restrict__ bias, float* __restrict__ out)
{
    __shared__ _Float16 sA[2][8704];
    __shared__ _Float16 sB[2][4096];

    const int tid = threadIdx.x;
    const int l   = tid & 63;
    const int wid = tid >> 6;
    const int m   = wid & 1;
    const int n   = wid >> 1;
    const int g   = l >> 4;
    const int l15 = l & 15;
    const int oc0 = blockIdx.x * 128;
    const int y0  = blockIdx.y * 2;
    const int b   = blockIdx.z;

    f32x4 accm[4][4], accc[4][4];
    #pragma unroll
    for (int i = 0; i < 4; ++i)
        #pragma unroll
        for (int j = 0; j < 4; ++j) {
            accm[i][j] = (f32x4){0.f, 0.f, 0.f, 0.f};
            accc[i][j] = (f32x4){0.f, 0.f, 0.f, 0.f};
        }

    auto stageA = [&](int icb) {
        for (int c = wid; c < 17; c += 4) {
            int s  = c * 64 + l;
            int px = s >> 2;
            int r  = px / 68;
            int xx = px - r * 68;
            const char* src = apad +
                ((size_t)((b * 66 + y0 + r) * 68 + xx) << 10) +
                (icb << 6) + ((s & 3) << 4);
            GLL16(src,          &sA[0][c * 512]);
            GLL16(src + APLANE, &sA[1][c * 512]);
        }
    };

    u32x4 breg[4];
    auto loadB = [&](int kk, int icb) {
        const char* bb = bw + ((size_t)(kk * 16 + icb) * 2048 + oc0 * 4) * 16;
        breg[0] = *(const u32x4*)(bb + (size_t)tid * 16);
        breg[1] = *(const u32x4*)(bb + (size_t)(tid + 256) * 16);
        breg[2] = *(const u32x4*)(bb + BPLANE + (size_t)tid * 16);
        breg[3] = *(const u32x4*)(bb + BPLANE + (size_t)(tid + 256) * 16);
    };
    auto writeB = [&]() {
        *(u32x4*)&sB[0][(size_t)tid * 8]         = breg[0];
        *(u32x4*)&sB[0][(size_t)(tid + 256) * 8] = breg[1];
        *(u32x4*)&sB[1][(size_t)tid * 8]         = breg[2];
        *(u32x4*)&sB[1][(size_t)(tid + 256) * 8] = breg[3];
    };

    stageA(0);
    loadB(0, 0);
    asm volatile("s_waitcnt vmcnt(0)" ::: "memory");
    writeB();
    __syncthreads();

    int kk = 0, icb = 0;
    for (int it = 0; it < 144; ++it) {
        int nkk = kk + 1, nicb = icb;
        if (nkk == 9) { nkk = 0; ++nicb; }
        const bool have_next = (it < 143);
        if (have_next) loadB(nkk, nicb);

        const int ky = kk / 3;
        const int kx = kk - 3 * ky;
        half8 bh[4], bl[4];
        #pragma unroll
        for (int jf = 0; jf < 4; ++jf) {
            int ocl  = n * 64 + 16 * jf + l15;
            int slot = (ocl << 2) | ((g + ocl) & 3);
            bh[jf] = *(const half8*)&sB[0][slot * 8];
            bl[jf] = *(const half8*)&sB[1][slot * 8];
        }
        const int r = m + ky;
        #pragma unroll
        for (int i = 0; i < 4; ++i) {
            int xx   = 16 * i + l15 + kx;
            int px   = r * 68 + xx;
            int slot = (px << 2) | ((g + px) & 3);
            half8 ah = *(const half8*)&sA[0][slot * 8];
            half8 al = *(const half8*)&sA[1][slot * 8];
            #pragma unroll
            for (int jf = 0; jf < 4; ++jf) {
                accm[i][jf] = __builtin_amdgcn_mfma_f32_16x16x32_f16(ah, bh[jf], accm[i][jf], 0, 0, 0);
                accc[i][jf] = __builtin_amdgcn_mfma_f32_16x16x32_f16(ah, bl[jf], accc[i][jf], 0, 0, 0);
                accc[i][jf] = __builtin_amdgcn_mfma_f32_16x16x32_f16(al, bh[jf], accc[i][jf], 0, 0, 0);
            }
        }
        __syncthreads();
        if (have_next) {
            writeB();
            if (nkk == 0) {
                stageA(nicb);
                asm volatile("s_waitcnt vmcnt(0)" ::: "memory");
            }
        }
        __syncthreads();
        kk = nkk; icb = nicb;
    }

    const float inv2048 = 4.8828125e-4f;
    #pragma unroll
    for (int i = 0; i < 4; ++i) {
        #pragma unroll
        for (int jf = 0; jf < 4; ++jf) {
            int oc = oc0 + n * 64 + 16 * jf + l15;
            int x  = 16 * i + (l >> 4) * 4;
            float bv = bias[oc];
            f32x4 vm = accm[i][jf], vc = accc[i][jf];
            f32x4 o;
            #pragma unroll
            for (int j = 0; j < 4; ++j) {
                float v = vm[j] + vc[j] * inv2048 + bv;
                o[j] = v > 0.f ? v : 0.f;
            }
            *(f32x4*)(out + (((size_t)(b * 512 + oc) << 12) +
                             ((y0 + m) << 6) + x)) = o;
        }
    }
}

// ---------------------------------------------------------------------------
// Head-weight prep: pack cls_w(18x512)+bbox_w(36x512), pad to 64 oc, into
// MFMA B-fragment layout: [plane2][ks16][g4][oc64][8 halfs]. + bias64.
// ---------------------------------------------------------------------------
__global__ __launch_bounds__(256) void prep_hw(
    const float* __restrict__ cls_w, const float* __restrict__ bbox_w,
    const float* __restrict__ cls_b, const float* __restrict__ bbox_b,
    char* __restrict__ bhw)
{
    int t = blockIdx.x * 256 + threadIdx.x;   // 0..8191
    int plane = t >> 12;
    int r  = t & 4095;
    int ks = r >> 8;
    int g  = (r >> 6) & 3;
    int oc = r & 63;
    int ic0 = ks * 32 + g * 8;

    half8 hv;
    #pragma unroll
    for (int e = 0; e < 8; ++e) {
        int ic = ic0 + e;
        float wf = 0.f;
        if (oc < 18)      wf = cls_w[oc * 512 + ic];
        else if (oc < 54) wf = bbox_w[(oc - 18) * 512 + ic];
        if (plane == 0) {
            hv[e] = (_Float16)wf;
        } else {
            _Float16 hi = (_Float16)wf;
            hv[e] = (_Float16)((wf - (float)hi) * 2048.0f);
        }
    }
    *(half8*)(bhw + (size_t)plane * 65536 +
              (size_t)(((ks * 4 + g) * 64 + oc)) * 16) = hv;

    if (blockIdx.x == 0 && threadIdx.x < 64) {
        int o = threadIdx.x;
        float bv = 0.f;
        if (o < 18)      bv = cls_b[o];
        else if (o < 54) bv = bbox_b[o - 18];
        *(float*)(bhw + 131072 + o * 4) = bv;
    }
}

// ---------------------------------------------------------------------------
// Heads MFMA: M=px, N=64(oc padded), K=512, fp16x3. No LDS, no barriers.
// ---------------------------------------------------------------------------
__global__ __launch_bounds__(256) void heads_mfma(
    const float* __restrict__ h, const char* __restrict__ bhw,
    float* __restrict__ hs)
{
    const int tid = threadIdx.x;
    const int l   = tid & 63;
    const int w   = tid >> 6;
    const int g   = l >> 4;
    const int l15 = l & 15;
    const int b   = blockIdx.y;
    const int px0 = blockIdx.x * 256 + w * 64;

    f32x4 accm[4][4], accc[4][4];
    #pragma unroll
    for (int i = 0; i < 4; ++i)
        #pragma unroll
        for (int j = 0; j < 4; ++j) {
            accm[i][j] = (f32x4){0.f, 0.f, 0.f, 0.f};
            accc[i][j] = (f32x4){0.f, 0.f, 0.f, 0.f};
        }

    const float* hb = h + (((size_t)(b * 512 + g * 8)) << 12) + px0 + l15;
    const float* bias64 = (const float*)(bhw + 131072);

    #pragma unroll 2
    for (int ks = 0; ks < 16; ++ks) {
        half8 bh[4], bl[4];
        #pragma unroll
        for (int jf = 0; jf < 4; ++jf) {
            size_t slot = (size_t)(((ks * 4 + g) * 64 + 16 * jf + l15)) * 16;
            bh[jf] = *(const half8*)(bhw + slot);
            bl[jf] = *(const half8*)(bhw + 65536 + slot);
        }
        #pragma unroll
        for (int i = 0; i < 4; ++i) {
            float af[8];
            #pragma unroll
            for (int e = 0; e < 8; ++e)
                af[e] = hb[(((size_t)(ks * 32 + e)) << 12) + i * 16];
            half8 ah, al;
            #pragma unroll
            for (int e = 0; e < 8; ++e) {
                _Float16 hi = (_Float16)af[e];
                ah[e] = hi;
                al[e] = (_Float16)((af[e] - (float)hi) * 2048.0f);
            }
            #pragma unroll
            for (int jf = 0; jf < 4; ++jf) {
                accm[i][jf] = __builtin_amdgcn_mfma_f32_16x16x32_f16(ah, bh[jf], accm[i][jf], 0, 0, 0);
                accc[i][jf] = __builtin_amdgcn_mfma_f32_16x16x32_f16(ah, bl[jf], accc[i][jf], 0, 0, 0);
                accc[i][jf] = __builtin_amdgcn_mfma_f32_16x16x32_f16(al, bh[jf], accc[i][jf], 0, 0, 0);
            }
        }
    }

    const float inv2048 = 4.8828125e-4f;
    float bv[4];
    #pragma unroll
    for (int jf = 0; jf < 4; ++jf) bv[jf] = bias64[16 * jf + l15];

    #pragma unroll
    for (int i = 0; i < 4; ++i) {
        #pragma unroll
        for (int jf = 0; jf < 4; ++jf) {
            int oc = 16 * jf + l15;
            #pragma unroll
            for (int j = 0; j < 4; ++j) {
                int px = px0 + i * 16 + g * 4 + j;
                float v = accm[i][jf][j] + accc[i][jf][j] * inv2048 + bv[jf];
                hs[(((size_t)(b * 4096 + px)) << 6) + oc] = v;
            }
        }
    }
}

// ---------------------------------------------------------------------------
// Decode: softmax + box decode + min-size mask from hs[b][px][64].
// ---------------------------------------------------------------------------
__global__ __launch_bounds__(256) void heads_decode(
    const float* __restrict__ hs, const float* __restrict__ im_info,
    float* __restrict__ scores, float* __restrict__ boxes)
{
    const int gid = blockIdx.x * 256 + threadIdx.x;   // 0..32767
    const int b = gid >> 12;
    const int s = gid & 4095;

    float acc[56];
    const f32x4* hp = (const f32x4*)(hs + ((size_t)gid << 6));
    #pragma unroll
    for (int q = 0; q < 14; ++q) {
        f32x4 v = hp[q];
        acc[4 * q + 0] = v[0]; acc[4 * q + 1] = v[1];
        acc[4 * q + 2] = v[2]; acc[4 * q + 3] = v[3];
    }

    const float info0 = im_info[b * 3 + 0];
    const float info1 = im_info[b * 3 + 1];
    const float info2 = im_info[b * 3 + 2];
    const float maxx = info1 - 1.0f, maxy = info0 - 1.0f;
    const float min_size = 16.0f * info2;
    const int y = s >> 6, x = s & 63;
    const float cxa = 16.f * (float)x + 8.f;
    const float cya = 16.f * (float)y + 8.f;
    const float WA[9] = {184.f, 368.f, 736.f, 128.f, 256.f, 512.f,  88.f, 176.f, 352.f};
    const float HA[9] = { 96.f, 192.f, 384.f, 128.f, 256.f, 512.f, 176.f, 352.f, 704.f};

    const int base = b * 36864 + s * 9;
    #pragma unroll
    for (int a = 0; a < 9; ++a) {
        float c0v = acc[a], c1v = acc[9 + a];
        float mm = fmaxf(c0v, c1v);
        float e0 = expf(c0v - mm), e1 = expf(c1v - mm);
        float fg = e1 / (e0 + e1);
        float dx = acc[18 + 4 * a + 0];
        float dy = acc[18 + 4 * a + 1];
        float dw = acc[18 + 4 * a + 2];
        float dh = acc[18 + 4 * a + 3];
        float cx = dx * WA[a] + cxa;
        float cy = dy * HA[a] + cya;
        float pw = expf(dw) * WA[a];
        float ph = expf(dh) * HA[a];
        float x1 = fminf(fmaxf(cx - 0.5f * pw, 0.f), maxx);
        float y1 = fminf(fmaxf(cy - 0.5f * ph, 0.f), maxy);
        float x2 = fminf(fmaxf(cx + 0.5f * pw, 0.f), maxx);
        float y2 = fminf(fmaxf(cy + 0.5f * ph, 0.f), maxy);
        bool keep = ((x2 - x1 + 1.f) >= min_size) && ((y2 - y1 + 1.f) >= min_size);
        scores[base + a] = keep ? fg : NEG_INF_F;
        float* bp = boxes + (size_t)(base + a) * 4;
        bp[0] = x1; bp[1] = y1; bp[2] = x2; bp[3] = y2;
    }
}

// ---------------------------------------------------------------------------
// Fallback f32 conv + fused heads (used only if ws too small for MFMA path).
// ---------------------------------------------------------------------------
__global__ __launch_bounds__(256) void conv3_relu(
    const float* __restrict__ in, const float* __restrict__ w,
    const float* __restrict__ bias, float* __restrict__ out)
{
    const int oc0 = blockIdx.x * 32;
    const int y0  = blockIdx.y * 4;
    const int b   = blockIdx.z;
    const int tid = threadIdx.x;
    const int xg  = tid & 31;
    const int og  = tid >> 5;

    __shared__ float s_in[8][6][68];
    __shared__ float s_w[32][8][9];

    float acc[4][4][2];
    #pragma unroll
    for (int o = 0; o < 4; ++o)
        #pragma unroll
        for (int yy = 0; yy < 4; ++yy) { acc[o][yy][0] = 0.f; acc[o][yy][1] = 0.f; }

    for (int ic0 = 0; ic0 < 512; ic0 += 8) {
        for (int e = tid; e < 8 * 6 * 66; e += 256) {
            int ic = e / 396; int r = e - ic * 396;
            int yy = r / 66;  int xx = r - yy * 66;
            int gy = y0 + yy - 1;
            int gx = xx - 1;
            float v = 0.f;
            if (gy >= 0 && gy < 64 && gx >= 0 && gx < 64)
                v = in[(((b * 512 + ic0 + ic) * 64 + gy) << 6) + gx];
            s_in[ic][yy][xx] = v;
        }
        {
            int oc = tid >> 3, ic = tid & 7;
            const float* wp = w + ((size_t)(oc0 + oc) * 512 + ic0 + ic) * 9;
            #pragma unroll
            for (int k = 0; k < 9; ++k) s_w[oc][ic][k] = wp[k];
        }
        __syncthreads();
        for (int ic = 0; ic < 8; ++ic) {
            #pragma unroll
            for (int ky = 0; ky < 3; ++ky) {
                #pragma unroll
                for (int kx = 0; kx < 3; ++kx) {
                    const int k = ky * 3 + kx;
                    float w0 = s_w[og][ic][k];
                    float w1 = s_w[og + 8][ic][k];
                    float w2 = s_w[og + 16][ic][k];
                    float w3 = s_w[og + 24][ic][k];
                    #pragma unroll
                    for (int yy = 0; yy < 4; ++yy) {
                        float i0 = s_in[ic][yy + ky][xg + kx];
                        float i1 = s_in[ic][yy + ky][xg + 32 + kx];
                        acc[0][yy][0] = fmaf(w0, i0, acc[0][yy][0]);
                        acc[0][yy][1] = fmaf(w0, i1, acc[0][yy][1]);
                        acc[1][yy][0] = fmaf(w1, i0, acc[1][yy][0]);
                        acc[1][yy][1] = fmaf(w1, i1, acc[1][yy][1]);
                        acc[2][yy][0] = fmaf(w2, i0, acc[2][yy][0]);
                        acc[2][yy][1] = fmaf(w2, i1, acc[2][yy][1]);
                        acc[3][yy][0] = fmaf(w3, i0, acc[3][yy][0]);
                        acc[3][yy][1] = fmaf(w3, i1, acc[3][yy][1]);
                    }
                }
            }
        }
        __syncthreads();
    }

    #pragma unroll
    for (int o = 0; o < 4; ++o) {
        int oc = oc0 + og + 8 * o;
        float bv = bias[oc];
        #pragma unroll
        for (int yy = 0; yy < 4; ++yy) {
            int y = y0 + yy;
            float* op = out + (((b * 512 + oc) * 64 + y) << 6);
            float v0 = acc[o][yy][0] + bv; v0 = v0 > 0.f ? v0 : 0.f;
            float v1 = acc[o][yy][1] + bv; v1 = v1 > 0.f ? v1 : 0.f;
            op[xg] = v0; op[xg + 32] = v1;
        }
    }
}

__global__ __launch_bounds__(256) void heads(
    const float* __restrict__ h, const float* __restrict__ cls_w,
    const float* __restrict__ cls_b, const float* __restrict__ bbox_w,
    const float* __restrict__ bbox_b, const float* __restrict__ im_info,
    float* __restrict__ scores, float* __restrict__ boxes)
{
    const int tid = threadIdx.x;
    const int b = blockIdx.x >> 4;
    const int s = ((blockIdx.x & 15) << 8) + tid;

    __shared__ float s_w[54][64];

    float acc[54];
    #pragma unroll
    for (int o = 0; o < 54; ++o) acc[o] = 0.f;

    for (int c0 = 0; c0 < 512; c0 += 64) {
        __syncthreads();
        for (int e = tid; e < 54 * 64; e += 256) {
            int oc = e >> 6, i = e & 63;
            float v = (oc < 18) ? cls_w[oc * 512 + c0 + i]
                                : bbox_w[(oc - 18) * 512 + c0 + i];
            s_w[oc][i] = v;
        }
        __syncthreads();
        for (int i = 0; i < 64; ++i) {
            float hv = h[((b * 512 + c0 + i) << 12) + s];
            #pragma unroll
            for (int o = 0; o < 54; ++o) acc[o] = fmaf(hv, s_w[o][i], acc[o]);
        }
    }
    #pragma unroll
    for (int o = 0; o < 18; ++o) acc[o] += cls_b[o];
    #pragma unroll
    for (int o = 0; o < 36; ++o) acc[18 + o] += bbox_b[o];

    const float info0 = im_info[b * 3 + 0];
    const float info1 = im_info[b * 3 + 1];
    const float info2 = im_info[b * 3 + 2];
    const float maxx = info1 - 1.0f, maxy = info0 - 1.0f;
    const float min_size = 16.0f * info2;
    const int y = s >> 6, x = s & 63;
    const float cxa = 16.f * (float)x + 8.f;
    const float cya = 16.f * (float)y + 8.f;
    const float WA[9] = {184.f, 368.f, 736.f, 128.f, 256.f, 512.f,  88.f, 176.f, 352.f};
    const float HA[9] = { 96.f, 192.f, 384.f, 128.f, 256.f, 512.f, 176.f, 352.f, 704.f};

    const int base = b * 36864 + s * 9;
    #pragma unroll
    for (int a = 0; a < 9; ++a) {
        float c0v = acc[a], c1v = acc[9 + a];
        float mm = fmaxf(c0v, c1v);
        float e0 = expf(c0v - mm), e1 = expf(c1v - mm);
        float fg = e1 / (e0 + e1);
        float dx = acc[18 + 4 * a + 0];
        float dy = acc[18 + 4 * a + 1];
        float dw = acc[18 + 4 * a + 2];
        float dh = acc[18 + 4 * a + 3];
        float cx = dx * WA[a] + cxa;
        float cy = dy * HA[a] + cya;
        float pw = expf(dw) * WA[a];
        float ph = expf(dh) * HA[a];
        float x1 = fminf(fmaxf(cx - 0.5f * pw, 0.f), maxx);
        float y1 = fminf(fmaxf(cy - 0.5f * ph, 0.f), maxy);
        float x2 = fminf(fmaxf(cx + 0.5f * pw, 0.f), maxx);
        float y2 = fminf(fmaxf(cy + 0.5f * ph, 0.f), maxy);
        bool keep = ((x2 - x1 + 1.f) >= min_size) && ((y2 - y1 + 1.f) >= min_size);
        scores[base + a] = keep ? fg : NEG_INF_F;
        float* bp = boxes + (size_t)(base + a) * 4;
        bp[0] = x1; bp[1] = y1; bp[2] = x2; bp[3] = y2;
    }
}

// ---------------------------------------------------------------------------
// Exact top-2000 via 16-bit histogram select on key-high = ~ordf(score).
// ---------------------------------------------------------------------------
__global__ void hist_k(const float* __restrict__ scores, uint32_t* __restrict__ hist)
{
    int gidx = blockIdx.x * 256 + threadIdx.x;
    int b = gidx / 36864, i = gidx - b * 36864;
    uint32_t kh = ~ordf(scores[b * 36864 + i]);
    atomicAdd(&hist[((size_t)b << 16) + (kh >> 16)], 1u);
}

__global__ __launch_bounds__(1024) void scan_k(const uint32_t* __restrict__ hist,
                                               uint32_t* __restrict__ cnt)
{
    const int b = blockIdx.x;
    const int t = threadIdx.x;
    __shared__ uint32_t part[1024];
    const uint32_t* hb = hist + ((size_t)b << 16);

    uint32_t own = 0;
    #pragma unroll 4
    for (int k = 0; k < 64; ++k) own += hb[t * 64 + k];
    part[t] = own;
    __syncthreads();
    for (int off = 1; off < 1024; off <<= 1) {
        uint32_t v = (t >= off) ? part[t - off] : 0u;
        __syncthreads();
        part[t] += v;
        __syncthreads();
    }
    uint32_t incl = part[t];
    uint32_t excl = incl - own;
    if (excl < 2000u && incl >= 2000u) {
        uint32_t c = excl;
        for (int k = 0; k < 64; ++k) {
            uint32_t hh = hb[t * 64 + k];
            if (c + hh >= 2000u) { cnt[16 + b] = t * 64 + k; cnt[24 + b] = c; break; }
            c += hh;
        }
    }
}

__global__ void compact_k(const float* __restrict__ scores,
                          uint32_t* __restrict__ cnt,
                          uint64_t* __restrict__ cand)
{
    int gidx = blockIdx.x * 256 + threadIdx.x;
    int b = gidx / 36864, i = gidx - b * 36864;
    float sc = scores[b * 36864 + i];
    uint32_t kh = ~ordf(sc);
    uint32_t bin = kh >> 16;
    uint32_t T = cnt[16 + b];
    uint64_t key = ((uint64_t)kh << 32) | (uint32_t)i;
    if (bin < T) {
        uint32_t p = atomicAdd(&cnt[b * 2], 1u);
        cand[((size_t)b << 12) + p] = key;
    } else if (bin == T) {
        uint32_t p = atomicAdd(&cnt[b * 2 + 1], 1u);
        if (p < 2048u) cand[((size_t)b << 12) + 4095 - p] = key;
    }
}

__global__ __launch_bounds__(1024) void sort4096_k(uint64_t* __restrict__ cand)
{
    const int b = blockIdx.x;
    const int tid = threadIdx.x;
    __shared__ uint64_t s[4096];
    for (int i = tid; i < 4096; i += 1024) s[i] = cand[((size_t)b << 12) + i];
    __syncthreads();
    for (int k = 2; k <= 4096; k <<= 1) {
        for (int j = k >> 1; j > 0; j >>= 1) {
            for (int t2 = tid; t2 < 2048; t2 += 1024) {
                int i = ((t2 & ~(j - 1)) << 1) | (t2 & (j - 1));
                int ixj = i + j;
                bool up = ((i & k) == 0);
                uint64_t a = s[i], c = s[ixj];
                if ((a > c) == up) { s[i] = c; s[ixj] = a; }
            }
            __syncthreads();
        }
    }
    for (int i = tid; i < 4096; i += 1024) cand[((size_t)b << 12) + i] = s[i];
}

__global__ void gather_top(const uint64_t* __restrict__ cand,
                           const float* __restrict__ scores,
                           const float* __restrict__ boxes,
                           float* __restrict__ ts, float* __restrict__ tb)
{
    int gidx = blockIdx.x * 256 + threadIdx.x;
    if (gidx >= 8 * 2000) return;
    int b = gidx / 2000, r = gidx - b * 2000;
    uint64_t k = cand[((size_t)b << 12) + r];
    int idx = (int)(uint32_t)k;
    ts[b * 2048 + r] = scores[b * 36864 + idx];
    const float* sp = boxes + ((size_t)b * 36864 + idx) * 4;
    float* dp = tb + ((size_t)b * 2048 + r) * 4;
    dp[0] = sp[0]; dp[1] = sp[1]; dp[2] = sp[2]; dp[3] = sp[3];
}

// ---------------------------------------------------------------------------
// NMS: IoU bitmask build (unchanged).
// ---------------------------------------------------------------------------
__global__ __launch_bounds__(64) void nms_mask(const float* __restrict__ tb,
                                               uint64_t* __restrict__ mask)
{
    const int b  = blockIdx.z;
    const int rb = blockIdx.y;
    const int cb = blockIdx.x;
    const int t  = threadIdx.x;
    __shared__ float cbox[64][4];
    const int col0 = cb * 64;
    {
        int c = col0 + t;
        if (c < 2000) {
            const float* p = tb + ((size_t)b * 2048 + c) * 4;
            cbox[t][0] = p[0]; cbox[t][1] = p[1]; cbox[t][2] = p[2]; cbox[t][3] = p[3];
        } else {
            cbox[t][0] = 0.f; cbox[t][1] = 0.f; cbox[t][2] = -1.f; cbox[t][3] = -1.f;
        }
    }
    __syncthreads();
    int row = rb * 64 + t;
    if (row >= 2000) return;
    const float* p = tb + ((size_t)b * 2048 + row) * 4;
    float x1 = p[0], y1 = p[1], x2 = p[2], y2 = p[3];
    float area = (x2 - x1 + 1.f) * (y2 - y1 + 1.f);
    uint64_t bits = 0;
    int ncol = 2000 - col0; if (ncol > 64) ncol = 64;
    for (int j = 0; j < ncol; ++j) {
        float xx1 = fmaxf(x1, cbox[j][0]);
        float yy1 = fmaxf(y1, cbox[j][1]);
        float xx2 = fminf(x2, cbox[j][2]);
        float yy2 = fminf(y2, cbox[j][3]);
        float iw = fmaxf(xx2 - xx1 + 1.f, 0.f);
        float ih = fmaxf(yy2 - yy1 + 1.f, 0.f);
        float inter = iw * ih;
        float areaj = (cbox[j][2] - cbox[j][0] + 1.f) * (cbox[j][3] - cbox[j][1] + 1.f);
        float iou = inter / (area + areaj - inter);
        if (iou > 0.7f) bits |= (1ull << j);
    }
    mask[((size_t)b * 2048 + row) * 32 + cb] = bits;
}

// ---------------------------------------------------------------------------
// Fused NMS scan + final sort + roi emit. Wave 0 (tid<64) runs the proven
// readlane greedy scan into LDS kw[]; after one full-block barrier the whole
// 1024-thread block builds post-NMS keys in LDS, bitonic-sorts 2048, and
// writes the 300 rois. (No fkeys global round-trip, one launch fewer.)
// ---------------------------------------------------------------------------
__global__ __launch_bounds__(1024) void nms_final(
    const uint64_t* __restrict__ mask, const float* __restrict__ ts,
    const float* __restrict__ tb, float* __restrict__ out)
{
    const int b = blockIdx.x;
    const int tid = threadIdx.x;
    __shared__ uint64_t kw[32];        // keep bits, one u64 per 64 rows
    __shared__ uint64_t s[2048];

    if (tid < 64) {
        const int lane = tid;
        const uint64_t* mrow = mask + (size_t)b * 2048 * 32;
        const bool ml = (lane < 32);
        uint64_t remv = 0;
        uint32_t cur_lo = 0, cur_hi = 0;
        uint64_t kcur = 0;

        uint64_t bufA[16], bufB[16];

#define LOADG(buf, gidx) do { int base_ = (gidx) * 16;                        \
    _Pragma("unroll")                                                         \
    for (int k_ = 0; k_ < 16; ++k_) {                                         \
        int r_ = base_ + k_;                                                  \
        buf[k_] = (ml && r_ < 2000) ? mrow[(size_t)r_ * 32 + lane] : 0ull;    \
    } } while (0)

#define PROCG(buf, gidx) do { int base_ = (gidx) * 16;                        \
    _Pragma("unroll")                                                         \
    for (int k_ = 0; k_ < 16; ++k_) {                                         \
        int i_ = base_ + k_;                                                  \
        int w_ = i_ >> 6;                                                     \
        int bit_ = i_ & 63;                                                   \
        if (bit_ == 0) {                                                      \
            cur_lo = __builtin_amdgcn_readlane((uint32_t)remv, w_);           \
            cur_hi = __builtin_amdgcn_readlane((uint32_t)(remv >> 32), w_);   \
            kcur = 0;                                                         \
        }                                                                     \
        uint32_t sw_ = (bit_ < 32) ? cur_lo : cur_hi;                         \
        if (!((sw_ >> (bit_ & 31)) & 1u)) {                                   \
            kcur |= (1ull << bit_);                                           \
            if (ml) remv |= buf[k_];                                          \
            cur_lo |= __builtin_amdgcn_readlane((uint32_t)buf[k_], w_);       \
            cur_hi |= __builtin_amdgcn_readlane((uint32_t)(buf[k_] >> 32), w_);\
        }                                                                     \
        if (bit_ == 63 || i_ == 1999) { if (lane == 0) kw[w_] = kcur; }       \
    } } while (0)

        LOADG(bufA, 0);
        LOADG(bufB, 1);
        for (int gq = 0; gq < 125; gq += 2) {      // 125 groups of 16 = 2000
            PROCG(bufA, gq);
            LOADG(bufA, gq + 2);
            if (gq + 1 < 125) {
                PROCG(bufB, gq + 1);
                LOADG(bufB, gq + 3);
            }
        }
#undef LOADG
#undef PROCG
    }
    __syncthreads();                               // kw visible to all waves

    for (int i = tid; i < 2048; i += 1024) {
        uint64_t k;
        if (i < 2000) {
            bool kp = (kw[i >> 6] >> (i & 63)) & 1ull;
            float sc = kp ? ts[b * 2048 + i] : NEG_INF_F;
            k = ((uint64_t)(~ordf(sc)) << 32) | (uint32_t)i;
        } else {
            k = ~0ull;
        }
        s[i] = k;
    }
    __syncthreads();

    for (int k = 2; k <= 2048; k <<= 1) {
        for (int j = k >> 1; j > 0; j >>= 1) {
            for (int t = tid; t < 2048; t += 1024) {
                int ixj = t ^ j;
                if (ixj > t) {
                    bool up = ((t & k) == 0);
                    uint64_t a = s[t], c = s[ixj];
                    if ((a > c) == up) { s[t] = c; s[ixj] = a; }
                }
            }
            __syncthreads();
        }
    }
    for (int r = tid; r < 300; r += 1024) {
        int idx = (int)(uint32_t)s[r];
        const float* bp = tb + ((size_t)b * 2048 + idx) * 4;
        float* op = out + (size_t)(b * 300 + r) * 5;
        op[0] = (float)b;
        op[1] = bp[0]; op[2] = bp[1]; op[3] = bp[2]; op[4] = bp[3];
    }
}

// ---------------------------------------------------------------------------
extern "C" void kernel_launch(void* const* d_in, const int* in_sizes, int n_in,
                              void* d_out, int out_size, void* d_ws, size_t ws_size,
                              hipStream_t stream)
{
    const float* im_data = (const float*)d_in[0];
    const float* im_info = (const float*)d_in[1];
    const float* conv_w  = (const float*)d_in[2];
    const float* conv_b  = (const float*)d_in[3];
    const float* cls_w   = (const float*)d_in[4];
    const float* cls_b   = (const float*)d_in[5];
    const float* bbox_w  = (const float*)d_in[6];
    const float* bbox_b  = (const float*)d_in[7];
    float* out = (float*)d_out;

    char* ws = (char*)d_ws;
    float*    h      = (float*)(ws);                      // 67,108,864
    float*    scores = (float*)(ws + 67108864ull);        // 1,179,648
    float*    boxes  = (float*)(ws + 68288512ull);        // 4,718,592
    uint32_t* hist   = (uint32_t*)(ws + 73007104ull);     // 2,097,152
    uint32_t* cnt    = (uint32_t*)(ws + 75104256ull);     // 1,024
    uint64_t* cand   = (uint64_t*)(ws + 75105280ull);     // 262,144
    float*    ts     = (float*)(ws + 75367424ull);        // 65,536
    float*    tb     = (float*)(ws + 75432960ull);        // 262,144
    uint64_t* mask   = (uint64_t*)(ws + 75695104ull);     // 4,194,304
    float*    hs     = (float*)(ws + 80020480ull);        // 8,388,608 (dead-apad zone)
    char*     bhw    = ws + 88409088ull;                  // 131,328   (dead-apad zone)

    char* apad = ws + 67108864ull;                        // 73,531,392 (conv phase only)
    char* bwp  = ws + 140640256ull;                       // 9,437,184
    const size_t NEED_FULL = 150077440ull;

    if (ws_size >= NEED_FULL) {
        halo_zero<<<dim3(1568), 256, 0, stream>>>(apad);
        prep_w<<<dim3(2304), 256, 0, stream>>>(conv_w, bwp);
        prep_a<<<dim3(64, 8), 256, 0, stream>>>(im_data, apad);
        conv_mfma<<<dim3(4, 32, 8), 256, 0, stream>>>(apad, bwp, conv_b, h);
        // apad dead from here; bhw/hs live in its footprint.
        prep_hw<<<dim3(32), 256, 0, stream>>>(cls_w, bbox_w, cls_b, bbox_b, bhw);
        heads_mfma<<<dim3(16, 8), 256, 0, stream>>>(h, bhw, hs);
        heads_decode<<<dim3(128), 256, 0, stream>>>(hs, im_info, scores, boxes);
    } else {
        conv3_relu<<<dim3(16, 16, 8), 256, 0, stream>>>(im_data, conv_w, conv_b, h);
        heads<<<dim3(128), 256, 0, stream>>>(h, cls_w, cls_b, bbox_w, bbox_b, im_info,
                                             scores, boxes);
    }

    hipMemsetAsync(hist, 0, 2097152ull + 1024ull, stream);
    hipMemsetAsync(cand, 0xFF, 262144ull, stream);
    hist_k<<<dim3(1152), 256, 0, stream>>>(scores, hist);
    scan_k<<<dim3(8), 1024, 0, stream>>>(hist, cnt);
    compact_k<<<dim3(1152), 256, 0, stream>>>(scores, cnt, cand);
    sort4096_k<<<dim3(8), 1024, 0, stream>>>(cand);
    gather_top<<<dim3(63), 256, 0, stream>>>(cand, scores, boxes, ts, tb);
    nms_mask<<<dim3(32, 32, 8), 64, 0, stream>>>(tb, mask);
    nms_final<<<dim3(8), 1024, 0, stream>>>(mask, ts, tb, out);
}

// Round 14
// 925.555 us; speedup vs baseline: 1.1113x; 1.0143x over previous
//
#include <hip/hip_runtime.h>
#include <stdint.h>

#define NEG_INF_F (-1e30f)

typedef _Float16 half8 __attribute__((ext_vector_type(8)));
typedef float f32x4 __attribute__((ext_vector_type(4)));
typedef uint32_t u32x4 __attribute__((ext_vector_type(4)));

__device__ __forceinline__ uint32_t ordf(float f) {
    uint32_t u = __float_as_uint(f);
    return u ^ ((u >> 31) ? 0xFFFFFFFFu : 0x80000000u);
}

#define GLL16(g, l) __builtin_amdgcn_global_load_lds( \
    (const __attribute__((address_space(1))) void*)(g), \
    (__attribute__((address_space(3))) void*)(l), 16, 0, 0)

// Apad: [split][b][yy 0..65][xx 0..67][icb 16][rot 4][8 fp16]  (pixel = 1024 B)
// Bw:   [split][kk 9][icb 16][oc 512][rot 4][8 fp16]; rot = (g + oc) & 3.
#define APLANE 36765696ull
#define BPLANE 4718592ull

// ---------------------------------------------------------------------------
// Halo zero: zero ONLY the apad border pixels prep_a never writes.
// ---------------------------------------------------------------------------
__global__ __launch_bounds__(256) void halo_zero(char* __restrict__ apad)
{
    int t = blockIdx.x * 256 + threadIdx.x;     // 0 .. 401407
    int chunk = t & 63;
    int r  = t >> 6;                            // 0 .. 6271
    int p  = r % 392;
    int bs = r / 392;                           // b*2 + split
    int split = bs & 1;
    int b     = bs >> 1;
    int yy, xx;
    if (p < 68)       { yy = 0;  xx = p; }
    else if (p < 136) { yy = 65; xx = p - 68; }
    else {
        int q = p - 136;
        yy = 1 + (q >> 2);
        int s2 = q & 3;
        xx = (s2 == 0) ? 0 : 64 + s2;
    }
    *(f32x4*)(apad + (size_t)split * APLANE +
              ((size_t)((b * 66 + yy) * 68 + xx) << 10) + chunk * 16) =
        (f32x4){0.f, 0.f, 0.f, 0.f};
}

// ---------------------------------------------------------------------------
// Conv weight prep: OIHW f32 -> fp16 hi plane + (lo*2048) plane, rotated slots.
// ---------------------------------------------------------------------------
__global__ __launch_bounds__(256) void prep_w(const float* __restrict__ w,
                                              char* __restrict__ bw)
{
    int t = blockIdx.x * 256 + threadIdx.x;     // 0 .. 589823
    int split = t / 294912;
    int r  = t % 294912;
    int kk = r >> 15;
    int r2 = r & 32767;
    int icb = r2 >> 11;
    int r3  = r2 & 2047;
    int oc  = r3 >> 2;
    int rot = r3 & 3;
    int g   = (rot - oc) & 3;
    int ic0 = icb * 32 + g * 8;

    half8 hv;
    #pragma unroll
    for (int e = 0; e < 8; ++e) {
        float wf = w[(size_t)(oc * 512 + ic0 + e) * 9 + kk];
        if (split == 0) {
            hv[e] = (_Float16)wf;
        } else {
            _Float16 hi = (_Float16)wf;
            hv[e] = (_Float16)((wf - (float)hi) * 2048.0f);
        }
    }
    *(half8*)(bw + (size_t)split * BPLANE +
              ((size_t)(kk * 16 + icb) * 2048 + r3) * 16) = hv;
}

// ---------------------------------------------------------------------------
// Input prep: NCHW f32 -> padded channels-last fp16 hi/lo planes.
// ---------------------------------------------------------------------------
__global__ __launch_bounds__(256) void prep_a(const float* __restrict__ in,
                                              char* __restrict__ apad)
{
    const int y = blockIdx.x;
    const int b = blockIdx.y;
    const int t = threadIdx.x;
    __shared__ float s_tile[64][65];

    for (int c = 0; c < 8; ++c) {
        __syncthreads();
        #pragma unroll
        for (int rep = 0; rep < 16; ++rep) {
            int ic_l = rep * 4 + (t >> 6);
            int x    = t & 63;
            s_tile[ic_l][x] =
                in[(((size_t)(b * 512 + c * 64 + ic_l) * 64 + y) << 6) + x];
        }
        __syncthreads();
        #pragma unroll
        for (int q = 0; q < 4; ++q) {
            int s     = q * 256 + t;           // 0..1023
            int split = s >> 9;
            int rem   = s & 511;
            int x     = rem >> 3;
            int icb_l = (rem >> 2) & 1;
            int rot   = rem & 3;
            int xx    = x + 1;
            int g     = (rot - xx) & 3;
            int ic_l0 = icb_l * 32 + g * 8;
            half8 hv;
            #pragma unroll
            for (int e = 0; e < 8; ++e) {
                float v = s_tile[ic_l0 + e][x];
                if (split == 0) {
                    hv[e] = (_Float16)v;
                } else {
                    _Float16 hi = (_Float16)v;
                    hv[e] = (_Float16)((v - (float)hi) * 2048.0f);
                }
            }
            *(half8*)(apad + (size_t)split * APLANE +
                      ((size_t)((b * 66 + y + 1) * 68 + xx) << 10) +
                      ((c * 2 + icb_l) << 6) + (rot << 4)) = hv;
        }
    }
}

// ---------------------------------------------------------------------------
// MFMA conv: implicit GEMM, fp16 x3 split precision (round-8 structure).
// ---------------------------------------------------------------------------
__global__ __launch_bounds__(256, 2) void conv_mfma(
    const char* __restrict__ apad, const char* __restrict__ bw,
    const float* __restrict__ bias, float* __restrict__ out)
{
    __shared__ _Float16 sA[2][8704];
    __shared__ _Float16 sB[2][4096];

    const int tid = threadIdx.x;
    const int l   = tid & 63;
    const int wid = tid >> 6;
    const int m   = wid & 1;
    const int n   = wid >> 1;
    const int g   = l >> 4;
    const int l15 = l & 15;
    const int oc0 = blockIdx.x * 128;
    const int y0  = blockIdx.y * 2;
    const int b   = blockIdx.z;

    f32x4 accm[4][4], accc[4][4];
    #pragma unroll
    for (int i = 0; i < 4; ++i)
        #pragma unroll
        for (int j = 0; j < 4; ++j) {
            accm[i][j] = (f32x4){0.f, 0.f, 0.f, 0.f};
            accc[i][j] = (f32x4){0.f, 0.f, 0.f, 0.f};
        }

    auto stageA = [&](int icb) {
        for (int c = wid; c < 17; c += 4) {
            int s  = c * 64 + l;
            int px = s >> 2;
            int r  = px / 68;
            int xx = px - r * 68;
            const char* src = apad +
                ((size_t)((b * 66 + y0 + r) * 68 + xx) << 10) +
                (icb << 6) + ((s & 3) << 4);
            GLL16(src,          &sA[0][c * 512]);
            GLL16(src + APLANE, &sA[1][c * 512]);
        }
    };

    u32x4 breg[4];
    auto loadB = [&](int kk, int icb) {
        const char* bb = bw + ((size_t)(kk * 16 + icb) * 2048 + oc0 * 4) * 16;
        breg[0] = *(const u32x4*)(bb + (size_t)tid * 16);
        breg[1] = *(const u32x4*)(bb + (size_t)(tid + 256) * 16);
        breg[2] = *(const u32x4*)(bb + BPLANE + (size_t)tid * 16);
        breg[3] = *(const u32x4*)(bb + BPLANE + (size_t)(tid + 256) * 16);
    };
    auto writeB = [&]() {
        *(u32x4*)&sB[0][(size_t)tid * 8]         = breg[0];
        *(u32x4*)&sB[0][(size_t)(tid + 256) * 8] = breg[1];
        *(u32x4*)&sB[1][(size_t)tid * 8]         = breg[2];
        *(u32x4*)&sB[1][(size_t)(tid + 256) * 8] = breg[3];
    };

    stageA(0);
    loadB(0, 0);
    asm volatile("s_waitcnt vmcnt(0)" ::: "memory");
    writeB();
    __syncthreads();

    int kk = 0, icb = 0;
    for (int it = 0; it < 144; ++it) {
        int nkk = kk + 1, nicb = icb;
        if (nkk == 9) { nkk = 0; ++nicb; }
        const bool have_next = (it < 143);
        if (have_next) loadB(nkk, nicb);

        const int ky = kk / 3;
        const int kx = kk - 3 * ky;
        half8 bh[4], bl[4];
        #pragma unroll
        for (int jf = 0; jf < 4; ++jf) {
            int ocl  = n * 64 + 16 * jf + l15;
            int slot = (ocl << 2) | ((g + ocl) & 3);
            bh[jf] = *(const half8*)&sB[0][slot * 8];
            bl[jf] = *(const half8*)&sB[1][slot * 8];
        }
        const int r = m + ky;
        #pragma unroll
        for (int i = 0; i < 4; ++i) {
            int xx   = 16 * i + l15 + kx;
            int px   = r * 68 + xx;
            int slot = (px << 2) | ((g + px) & 3);
            half8 ah = *(const half8*)&sA[0][slot * 8];
            half8 al = *(const half8*)&sA[1][slot * 8];
            #pragma unroll
            for (int jf = 0; jf < 4; ++jf) {
                accm[i][jf] = __builtin_amdgcn_mfma_f32_16x16x32_f16(ah, bh[jf], accm[i][jf], 0, 0, 0);
                accc[i][jf] = __builtin_amdgcn_mfma_f32_16x16x32_f16(ah, bl[jf], accc[i][jf], 0, 0, 0);
                accc[i][jf] = __builtin_amdgcn_mfma_f32_16x16x32_f16(al, bh[jf], accc[i][jf], 0, 0, 0);
            }
        }
        __syncthreads();
        if (have_next) {
            writeB();
            if (nkk == 0) {
                stageA(nicb);
                asm volatile("s_waitcnt vmcnt(0)" ::: "memory");
            }
        }
        __syncthreads();
        kk = nkk; icb = nicb;
    }

    const float inv2048 = 4.8828125e-4f;
    #pragma unroll
    for (int i = 0; i < 4; ++i) {
        #pragma unroll
        for (int jf = 0; jf < 4; ++jf) {
            int oc = oc0 + n * 64 + 16 * jf + l15;
            int x  = 16 * i + (l >> 4) * 4;
            float bv = bias[oc];
            f32x4 vm = accm[i][jf], vc = accc[i][jf];
            f32x4 o;
            #pragma unroll
            for (int j = 0; j < 4; ++j) {
                float v = vm[j] + vc[j] * inv2048 + bv;
                o[j] = v > 0.f ? v : 0.f;
            }
            *(f32x4*)(out + (((size_t)(b * 512 + oc) << 12) +
                             ((y0 + m) << 6) + x)) = o;
        }
    }
}

// ---------------------------------------------------------------------------
// Head-weight prep: pack cls_w(18x512)+bbox_w(36x512), pad to 64 oc, into
// MFMA B-fragment layout: [plane2][ks16][g4][oc64][8 halfs]. + bias64.
// ---------------------------------------------------------------------------
__global__ __launch_bounds__(256) void prep_hw(
    const float* __restrict__ cls_w, const float* __restrict__ bbox_w,
    const float* __restrict__ cls_b, const float* __restrict__ bbox_b,
    char* __restrict__ bhw)
{
    int t = blockIdx.x * 256 + threadIdx.x;   // 0..8191
    int plane = t >> 12;
    int r  = t & 4095;
    int ks = r >> 8;
    int g  = (r >> 6) & 3;
    int oc = r & 63;
    int ic0 = ks * 32 + g * 8;

    half8 hv;
    #pragma unroll
    for (int e = 0; e < 8; ++e) {
        int ic = ic0 + e;
        float wf = 0.f;
        if (oc < 18)      wf = cls_w[oc * 512 + ic];
        else if (oc < 54) wf = bbox_w[(oc - 18) * 512 + ic];
        if (plane == 0) {
            hv[e] = (_Float16)wf;
        } else {
            _Float16 hi = (_Float16)wf;
            hv[e] = (_Float16)((wf - (float)hi) * 2048.0f);
        }
    }
    *(half8*)(bhw + (size_t)plane * 65536 +
              (size_t)(((ks * 4 + g) * 64 + oc)) * 16) = hv;

    if (blockIdx.x == 0 && threadIdx.x < 64) {
        int o = threadIdx.x;
        float bv = 0.f;
        if (o < 18)      bv = cls_b[o];
        else if (o < 54) bv = bbox_b[o - 18];
        *(float*)(bhw + 131072 + o * 4) = bv;
    }
}

// ---------------------------------------------------------------------------
// Heads MFMA: M=px, N=64(oc padded), K=512, fp16x3. No LDS, no barriers.
// ---------------------------------------------------------------------------
__global__ __launch_bounds__(256) void heads_mfma(
    const float* __restrict__ h, const char* __restrict__ bhw,
    float* __restrict__ hs)
{
    const int tid = threadIdx.x;
    const int l   = tid & 63;
    const int w   = tid >> 6;
    const int g   = l >> 4;
    const int l15 = l & 15;
    const int b   = blockIdx.y;
    const int px0 = blockIdx.x * 256 + w * 64;

    f32x4 accm[4][4], accc[4][4];
    #pragma unroll
    for (int i = 0; i < 4; ++i)
        #pragma unroll
        for (int j = 0; j < 4; ++j) {
            accm[i][j] = (f32x4){0.f, 0.f, 0.f, 0.f};
            accc[i][j] = (f32x4){0.f, 0.f, 0.f, 0.f};
        }

    const float* hb = h + (((size_t)(b * 512 + g * 8)) << 12) + px0 + l15;
    const float* bias64 = (const float*)(bhw + 131072);

    #pragma unroll 2
    for (int ks = 0; ks < 16; ++ks) {
        half8 bh[4], bl[4];
        #pragma unroll
        for (int jf = 0; jf < 4; ++jf) {
            size_t slot = (size_t)(((ks * 4 + g) * 64 + 16 * jf + l15)) * 16;
            bh[jf] = *(const half8*)(bhw + slot);
            bl[jf] = *(const half8*)(bhw + 65536 + slot);
        }
        #pragma unroll
        for (int i = 0; i < 4; ++i) {
            float af[8];
            #pragma unroll
            for (int e = 0; e < 8; ++e)
                af[e] = hb[(((size_t)(ks * 32 + e)) << 12) + i * 16];
            half8 ah, al;
            #pragma unroll
            for (int e = 0; e < 8; ++e) {
                _Float16 hi = (_Float16)af[e];
                ah[e] = hi;
                al[e] = (_Float16)((af[e] - (float)hi) * 2048.0f);
            }
            #pragma unroll
            for (int jf = 0; jf < 4; ++jf) {
                accm[i][jf] = __builtin_amdgcn_mfma_f32_16x16x32_f16(ah, bh[jf], accm[i][jf], 0, 0, 0);
                accc[i][jf] = __builtin_amdgcn_mfma_f32_16x16x32_f16(ah, bl[jf], accc[i][jf], 0, 0, 0);
                accc[i][jf] = __builtin_amdgcn_mfma_f32_16x16x32_f16(al, bh[jf], accc[i][jf], 0, 0, 0);
            }
        }
    }

    const float inv2048 = 4.8828125e-4f;
    float bv[4];
    #pragma unroll
    for (int jf = 0; jf < 4; ++jf) bv[jf] = bias64[16 * jf + l15];

    #pragma unroll
    for (int i = 0; i < 4; ++i) {
        #pragma unroll
        for (int jf = 0; jf < 4; ++jf) {
            int oc = 16 * jf + l15;
            #pragma unroll
            for (int j = 0; j < 4; ++j) {
                int px = px0 + i * 16 + g * 4 + j;
                float v = accm[i][jf][j] + accc[i][jf][j] * inv2048 + bv[jf];
                hs[(((size_t)(b * 4096 + px)) << 6) + oc] = v;
            }
        }
    }
}

// ---------------------------------------------------------------------------
// Decode: softmax + box decode + min-size mask from hs[b][px][64],
// PLUS fused 16-bit score histogram (hist must be zeroed beforehand).
// ---------------------------------------------------------------------------
__global__ __launch_bounds__(256) void heads_decode(
    const float* __restrict__ hs, const float* __restrict__ im_info,
    float* __restrict__ scores, float* __restrict__ boxes,
    uint32_t* __restrict__ hist)
{
    const int gid = blockIdx.x * 256 + threadIdx.x;   // 0..32767
    const int b = gid >> 12;
    const int s = gid & 4095;

    float acc[56];
    const f32x4* hp = (const f32x4*)(hs + ((size_t)gid << 6));
    #pragma unroll
    for (int q = 0; q < 14; ++q) {
        f32x4 v = hp[q];
        acc[4 * q + 0] = v[0]; acc[4 * q + 1] = v[1];
        acc[4 * q + 2] = v[2]; acc[4 * q + 3] = v[3];
    }

    const float info0 = im_info[b * 3 + 0];
    const float info1 = im_info[b * 3 + 1];
    const float info2 = im_info[b * 3 + 2];
    const float maxx = info1 - 1.0f, maxy = info0 - 1.0f;
    const float min_size = 16.0f * info2;
    const int y = s >> 6, x = s & 63;
    const float cxa = 16.f * (float)x + 8.f;
    const float cya = 16.f * (float)y + 8.f;
    const float WA[9] = {184.f, 368.f, 736.f, 128.f, 256.f, 512.f,  88.f, 176.f, 352.f};
    const float HA[9] = { 96.f, 192.f, 384.f, 128.f, 256.f, 512.f, 176.f, 352.f, 704.f};

    uint32_t* hb = hist + ((size_t)b << 16);
    const int base = b * 36864 + s * 9;
    #pragma unroll
    for (int a = 0; a < 9; ++a) {
        float c0v = acc[a], c1v = acc[9 + a];
        float mm = fmaxf(c0v, c1v);
        float e0 = expf(c0v - mm), e1 = expf(c1v - mm);
        float fg = e1 / (e0 + e1);
        float dx = acc[18 + 4 * a + 0];
        float dy = acc[18 + 4 * a + 1];
        float dw = acc[18 + 4 * a + 2];
        float dh = acc[18 + 4 * a + 3];
        float cx = dx * WA[a] + cxa;
        float cy = dy * HA[a] + cya;
        float pw = expf(dw) * WA[a];
        float ph = expf(dh) * HA[a];
        float x1 = fminf(fmaxf(cx - 0.5f * pw, 0.f), maxx);
        float y1 = fminf(fmaxf(cy - 0.5f * ph, 0.f), maxy);
        float x2 = fminf(fmaxf(cx + 0.5f * pw, 0.f), maxx);
        float y2 = fminf(fmaxf(cy + 0.5f * ph, 0.f), maxy);
        bool keep = ((x2 - x1 + 1.f) >= min_size) && ((y2 - y1 + 1.f) >= min_size);
        float sc = keep ? fg : NEG_INF_F;
        scores[base + a] = sc;
        atomicAdd(&hb[(~ordf(sc)) >> 16], 1u);
        float* bp = boxes + (size_t)(base + a) * 4;
        bp[0] = x1; bp[1] = y1; bp[2] = x2; bp[3] = y2;
    }
}

// ---------------------------------------------------------------------------
// Fallback f32 conv + fused heads (used only if ws too small for MFMA path).
// ---------------------------------------------------------------------------
__global__ __launch_bounds__(256) void conv3_relu(
    const float* __restrict__ in, const float* __restrict__ w,
    const float* __restrict__ bias, float* __restrict__ out)
{
    const int oc0 = blockIdx.x * 32;
    const int y0  = blockIdx.y * 4;
    const int b   = blockIdx.z;
    const int tid = threadIdx.x;
    const int xg  = tid & 31;
    const int og  = tid >> 5;

    __shared__ float s_in[8][6][68];
    __shared__ float s_w[32][8][9];

    float acc[4][4][2];
    #pragma unroll
    for (int o = 0; o < 4; ++o)
        #pragma unroll
        for (int yy = 0; yy < 4; ++yy) { acc[o][yy][0] = 0.f; acc[o][yy][1] = 0.f; }

    for (int ic0 = 0; ic0 < 512; ic0 += 8) {
        for (int e = tid; e < 8 * 6 * 66; e += 256) {
            int ic = e / 396; int r = e - ic * 396;
            int yy = r / 66;  int xx = r - yy * 66;
            int gy = y0 + yy - 1;
            int gx = xx - 1;
            float v = 0.f;
            if (gy >= 0 && gy < 64 && gx >= 0 && gx < 64)
                v = in[(((b * 512 + ic0 + ic) * 64 + gy) << 6) + gx];
            s_in[ic][yy][xx] = v;
        }
        {
            int oc = tid >> 3, ic = tid & 7;
            const float* wp = w + ((size_t)(oc0 + oc) * 512 + ic0 + ic) * 9;
            #pragma unroll
            for (int k = 0; k < 9; ++k) s_w[oc][ic][k] = wp[k];
        }
        __syncthreads();
        for (int ic = 0; ic < 8; ++ic) {
            #pragma unroll
            for (int ky = 0; ky < 3; ++ky) {
                #pragma unroll
                for (int kx = 0; kx < 3; ++kx) {
                    const int k = ky * 3 + kx;
                    float w0 = s_w[og][ic][k];
                    float w1 = s_w[og + 8][ic][k];
                    float w2 = s_w[og + 16][ic][k];
                    float w3 = s_w[og + 24][ic][k];
                    #pragma unroll
                    for (int yy = 0; yy < 4; ++yy) {
                        float i0 = s_in[ic][yy + ky][xg + kx];
                        float i1 = s_in[ic][yy + ky][xg + 32 + kx];
                        acc[0][yy][0] = fmaf(w0, i0, acc[0][yy][0]);
                        acc[0][yy][1] = fmaf(w0, i1, acc[0][yy][1]);
                        acc[1][yy][0] = fmaf(w1, i0, acc[1][yy][0]);
                        acc[1][yy][1] = fmaf(w1, i1, acc[1][yy][1]);
                        acc[2][yy][0] = fmaf(w2, i0, acc[2][yy][0]);
                        acc[2][yy][1] = fmaf(w2, i1, acc[2][yy][1]);
                        acc[3][yy][0] = fmaf(w3, i0, acc[3][yy][0]);
                        acc[3][yy][1] = fmaf(w3, i1, acc[3][yy][1]);
                    }
                }
            }
        }
        __syncthreads();
    }

    #pragma unroll
    for (int o = 0; o < 4; ++o) {
        int oc = oc0 + og + 8 * o;
        float bv = bias[oc];
        #pragma unroll
        for (int yy = 0; yy < 4; ++yy) {
            int y = y0 + yy;
            float* op = out + (((b * 512 + oc) * 64 + y) << 6);
            float v0 = acc[o][yy][0] + bv; v0 = v0 > 0.f ? v0 : 0.f;
            float v1 = acc[o][yy][1] + bv; v1 = v1 > 0.f ? v1 : 0.f;
            op[xg] = v0; op[xg + 32] = v1;
        }
    }
}

__global__ __launch_bounds__(256) void heads(
    const float* __restrict__ h, const float* __restrict__ cls_w,
    const float* __restrict__ cls_b, const float* __restrict__ bbox_w,
    const float* __restrict__ bbox_b, const float* __restrict__ im_info,
    float* __restrict__ scores, float* __restrict__ boxes,
    uint32_t* __restrict__ hist)
{
    const int tid = threadIdx.x;
    const int b = blockIdx.x >> 4;
    const int s = ((blockIdx.x & 15) << 8) + tid;

    __shared__ float s_w[54][64];

    float acc[54];
    #pragma unroll
    for (int o = 0; o < 54; ++o) acc[o] = 0.f;

    for (int c0 = 0; c0 < 512; c0 += 64) {
        __syncthreads();
        for (int e = tid; e < 54 * 64; e += 256) {
            int oc = e >> 6, i = e & 63;
            float v = (oc < 18) ? cls_w[oc * 512 + c0 + i]
                                : bbox_w[(oc - 18) * 512 + c0 + i];
            s_w[oc][i] = v;
        }
        __syncthreads();
        for (int i = 0; i < 64; ++i) {
            float hv = h[((b * 512 + c0 + i) << 12) + s];
            #pragma unroll
            for (int o = 0; o < 54; ++o) acc[o] = fmaf(hv, s_w[o][i], acc[o]);
        }
    }
    #pragma unroll
    for (int o = 0; o < 18; ++o) acc[o] += cls_b[o];
    #pragma unroll
    for (int o = 0; o < 36; ++o) acc[18 + o] += bbox_b[o];

    const float info0 = im_info[b * 3 + 0];
    const float info1 = im_info[b * 3 + 1];
    const float info2 = im_info[b * 3 + 2];
    const float maxx = info1 - 1.0f, maxy = info0 - 1.0f;
    const float min_size = 16.0f * info2;
    const int y = s >> 6, x = s & 63;
    const float cxa = 16.f * (float)x + 8.f;
    const float cya = 16.f * (float)y + 8.f;
    const float WA[9] = {184.f, 368.f, 736.f, 128.f, 256.f, 512.f,  88.f, 176.f, 352.f};
    const float HA[9] = { 96.f, 192.f, 384.f, 128.f, 256.f, 512.f, 176.f, 352.f, 704.f};

    uint32_t* hb = hist + ((size_t)b << 16);
    const int base = b * 36864 + s * 9;
    #pragma unroll
    for (int a = 0; a < 9; ++a) {
        float c0v = acc[a], c1v = acc[9 + a];
        float mm = fmaxf(c0v, c1v);
        float e0 = expf(c0v - mm), e1 = expf(c1v - mm);
        float fg = e1 / (e0 + e1);
        float dx = acc[18 + 4 * a + 0];
        float dy = acc[18 + 4 * a + 1];
        float dw = acc[18 + 4 * a + 2];
        float dh = acc[18 + 4 * a + 3];
        float cx = dx * WA[a] + cxa;
        float cy = dy * HA[a] + cya;
        float pw = expf(dw) * WA[a];
        float ph = expf(dh) * HA[a];
        float x1 = fminf(fmaxf(cx - 0.5f * pw, 0.f), maxx);
        float y1 = fminf(fmaxf(cy - 0.5f * ph, 0.f), maxy);
        float x2 = fminf(fmaxf(cx + 0.5f * pw, 0.f), maxx);
        float y2 = fminf(fmaxf(cy + 0.5f * ph, 0.f), maxy);
        bool keep = ((x2 - x1 + 1.f) >= min_size) && ((y2 - y1 + 1.f) >= min_size);
        float sc = keep ? fg : NEG_INF_F;
        scores[base + a] = sc;
        atomicAdd(&hb[(~ordf(sc)) >> 16], 1u);
        float* bp = boxes + (size_t)(base + a) * 4;
        bp[0] = x1; bp[1] = y1; bp[2] = x2; bp[3] = y2;
    }
}

// ---------------------------------------------------------------------------
// Top-2000 select: scan histogram, compact, sort candidates.
// ---------------------------------------------------------------------------
__global__ __launch_bounds__(1024) void scan_k(const uint32_t* __restrict__ hist,
                                               uint32_t* __restrict__ cnt)
{
    const int b = blockIdx.x;
    const int t = threadIdx.x;
    __shared__ uint32_t part[1024];
    const uint32_t* hb = hist + ((size_t)b << 16);

    uint32_t own = 0;
    #pragma unroll 4
    for (int k = 0; k < 64; ++k) own += hb[t * 64 + k];
    part[t] = own;
    __syncthreads();
    for (int off = 1; off < 1024; off <<= 1) {
        uint32_t v = (t >= off) ? part[t - off] : 0u;
        __syncthreads();
        part[t] += v;
        __syncthreads();
    }
    uint32_t incl = part[t];
    uint32_t excl = incl - own;
    if (excl < 2000u && incl >= 2000u) {
        uint32_t c = excl;
        for (int k = 0; k < 64; ++k) {
            uint32_t hh = hb[t * 64 + k];
            if (c + hh >= 2000u) { cnt[16 + b] = t * 64 + k; cnt[24 + b] = c; break; }
            c += hh;
        }
    }
}

__global__ void compact_k(const float* __restrict__ scores,
                          uint32_t* __restrict__ cnt,
                          uint64_t* __restrict__ cand)
{
    int gidx = blockIdx.x * 256 + threadIdx.x;
    int b = gidx / 36864, i = gidx - b * 36864;
    float sc = scores[b * 36864 + i];
    uint32_t kh = ~ordf(sc);
    uint32_t bin = kh >> 16;
    uint32_t T = cnt[16 + b];
    uint64_t key = ((uint64_t)kh << 32) | (uint32_t)i;
    if (bin < T) {
        uint32_t p = atomicAdd(&cnt[b * 2], 1u);
        cand[((size_t)b << 12) + p] = key;
    } else if (bin == T) {
        uint32_t p = atomicAdd(&cnt[b * 2 + 1], 1u);
        if (p < 2048u) cand[((size_t)b << 12) + 4095 - p] = key;
    }
}

__global__ __launch_bounds__(1024) void sort4096_k(uint64_t* __restrict__ cand)
{
    const int b = blockIdx.x;
    const int tid = threadIdx.x;
    __shared__ uint64_t s[4096];
    for (int i = tid; i < 4096; i += 1024) s[i] = cand[((size_t)b << 12) + i];
    __syncthreads();
    for (int k = 2; k <= 4096; k <<= 1) {
        for (int j = k >> 1; j > 0; j >>= 1) {
            for (int t2 = tid; t2 < 2048; t2 += 1024) {
                int i = ((t2 & ~(j - 1)) << 1) | (t2 & (j - 1));
                int ixj = i + j;
                bool up = ((i & k) == 0);
                uint64_t a = s[i], c = s[ixj];
                if ((a > c) == up) { s[i] = c; s[ixj] = a; }
            }
            __syncthreads();
        }
    }
    for (int i = tid; i < 4096; i += 1024) cand[((size_t)b << 12) + i] = s[i];
}

__global__ void gather_top(const uint64_t* __restrict__ cand,
                           const float* __restrict__ scores,
                           const float* __restrict__ boxes,
                           float* __restrict__ ts, float* __restrict__ tb)
{
    int gidx = blockIdx.x * 256 + threadIdx.x;
    if (gidx >= 8 * 2000) return;
    int b = gidx / 2000, r = gidx - b * 2000;
    uint64_t k = cand[((size_t)b << 12) + r];
    int idx = (int)(uint32_t)k;
    ts[b * 2048 + r] = scores[b * 36864 + idx];
    const float* sp = boxes + ((size_t)b * 36864 + idx) * 4;
    float* dp = tb + ((size_t)b * 2048 + r) * 4;
    dp[0] = sp[0]; dp[1] = sp[1]; dp[2] = sp[2]; dp[3] = sp[3];
}

// ---------------------------------------------------------------------------
// NMS: IoU bitmask build, UPPER TRIANGLE only (cb >= rb). Greedy suppression
// only consults bits of computed blocks (see nms_final scan ordering).
// ---------------------------------------------------------------------------
__global__ __launch_bounds__(64) void nms_mask(const float* __restrict__ tb,
                                               uint64_t* __restrict__ mask)
{
    const int b  = blockIdx.z;
    const int rb = blockIdx.y;
    const int cb = blockIdx.x;
    if (cb < rb) return;
    const int t  = threadIdx.x;
    __shared__ float cbox[64][4];
    const int col0 = cb * 64;
    {
        int c = col0 + t;
        if (c < 2000) {
            const float* p = tb + ((size_t)b * 2048 + c) * 4;
            cbox[t][0] = p[0]; cbox[t][1] = p[1]; cbox[t][2] = p[2]; cbox[t][3] = p[3];
        } else {
            cbox[t][0] = 0.f; cbox[t][1] = 0.f; cbox[t][2] = -1.f; cbox[t][3] = -1.f;
        }
    }
    __syncthreads();
    int row = rb * 64 + t;
    if (row >= 2000) return;
    const float* p = tb + ((size_t)b * 2048 + row) * 4;
    float x1 = p[0], y1 = p[1], x2 = p[2], y2 = p[3];
    float area = (x2 - x1 + 1.f) * (y2 - y1 + 1.f);
    uint64_t bits = 0;
    int ncol = 2000 - col0; if (ncol > 64) ncol = 64;
    for (int j = 0; j < ncol; ++j) {
        float xx1 = fmaxf(x1, cbox[j][0]);
        float yy1 = fmaxf(y1, cbox[j][1]);
        float xx2 = fminf(x2, cbox[j][2]);
        float yy2 = fminf(y2, cbox[j][3]);
        float iw = fmaxf(xx2 - xx1 + 1.f, 0.f);
        float ih = fmaxf(yy2 - yy1 + 1.f, 0.f);
        float inter = iw * ih;
        float areaj = (cbox[j][2] - cbox[j][0] + 1.f) * (cbox[j][3] - cbox[j][1] + 1.f);
        float iou = inter / (area + areaj - inter);
        if (iou > 0.7f) bits |= (1ull << j);
    }
    mask[((size_t)b * 2048 + row) * 32 + cb] = bits;
}

// ---------------------------------------------------------------------------
// Fused NMS scan + final sort + roi emit (round-12 proven).
// ---------------------------------------------------------------------------
__global__ __launch_bounds__(1024) void nms_final(
    const uint64_t* __restrict__ mask, const float* __restrict__ ts,
    const float* __restrict__ tb, float* __restrict__ out)
{
    const int b = blockIdx.x;
    const int tid = threadIdx.x;
    __shared__ uint64_t kw[32];        // keep bits, one u64 per 64 rows
    __shared__ uint64_t s[2048];

    if (tid < 64) {
        const int lane = tid;
        const uint64_t* mrow = mask + (size_t)b * 2048 * 32;
        const bool ml = (lane < 32);
        uint64_t remv = 0;
        uint32_t cur_lo = 0, cur_hi = 0;
        uint64_t kcur = 0;

        uint64_t bufA[16], bufB[16];

#define LOADG(buf, gidx) do { int base_ = (gidx) * 16;                        \
    _Pragma("unroll")                                                         \
    for (int k_ = 0; k_ < 16; ++k_) {                                         \
        int r_ = base_ + k_;                                                  \
        buf[k_] = (ml && r_ < 2000) ? mrow[(size_t)r_ * 32 + lane] : 0ull;    \
    } } while (0)

#define PROCG(buf, gidx) do { int base_ = (gidx) * 16;                        \
    _Pragma("unroll")                                                         \
    for (int k_ = 0; k_ < 16; ++k_) {                                         \
        int i_ = base_ + k_;                                                  \
        int w_ = i_ >> 6;                                                     \
        int bit_ = i_ & 63;                                                   \
        if (bit_ == 0) {                                                      \
            cur_lo = __builtin_amdgcn_readlane((uint32_t)remv, w_);           \
            cur_hi = __builtin_amdgcn_readlane((uint32_t)(remv >> 32), w_);   \
            kcur = 0;                                                         \
        }                                                                     \
        uint32_t sw_ = (bit_ < 32) ? cur_lo : cur_hi;                         \
        if (!((sw_ >> (bit_ & 31)) & 1u)) {                                   \
            kcur |= (1ull << bit_);                                           \
            if (ml) remv |= buf[k_];                                          \
            cur_lo |= __builtin_amdgcn_readlane((uint32_t)buf[k_], w_);       \
            cur_hi |= __builtin_amdgcn_readlane((uint32_t)(buf[k_] >> 32), w_);\
        }                                                                     \
        if (bit_ == 63 || i_ == 1999) { if (lane == 0) kw[w_] = kcur; }       \
    } } while (0)

        LOADG(bufA, 0);
        LOADG(bufB, 1);
        for (int gq = 0; gq < 125; gq += 2) {      // 125 groups of 16 = 2000
            PROCG(bufA, gq);
            LOADG(bufA, gq + 2);
            if (gq + 1 < 125) {
                PROCG(bufB, gq + 1);
                LOADG(bufB, gq + 3);
            }
        }
#undef LOADG
#undef PROCG
    }
    __syncthreads();                               // kw visible to all waves

    for (int i = tid; i < 2048; i += 1024) {
        uint64_t k;
        if (i < 2000) {
            bool kp = (kw[i >> 6] >> (i & 63)) & 1ull;
            float sc = kp ? ts[b * 2048 + i] : NEG_INF_F;
            k = ((uint64_t)(~ordf(sc)) << 32) | (uint32_t)i;
        } else {
            k = ~0ull;
        }
        s[i] = k;
    }
    __syncthreads();

    for (int k = 2; k <= 2048; k <<= 1) {
        for (int j = k >> 1; j > 0; j >>= 1) {
            for (int t = tid; t < 2048; t += 1024) {
                int ixj = t ^ j;
                if (ixj > t) {
                    bool up = ((t & k) == 0);
                    uint64_t a = s[t], c = s[ixj];
                    if ((a > c) == up) { s[t] = c; s[ixj] = a; }
                }
            }
            __syncthreads();
        }
    }
    for (int r = tid; r < 300; r += 1024) {
        int idx = (int)(uint32_t)s[r];
        const float* bp = tb + ((size_t)b * 2048 + idx) * 4;
        float* op = out + (size_t)(b * 300 + r) * 5;
        op[0] = (float)b;
        op[1] = bp[0]; op[2] = bp[1]; op[3] = bp[2]; op[4] = bp[3];
    }
}

// ---------------------------------------------------------------------------
extern "C" void kernel_launch(void* const* d_in, const int* in_sizes, int n_in,
                              void* d_out, int out_size, void* d_ws, size_t ws_size,
                              hipStream_t stream)
{
    const float* im_data = (const float*)d_in[0];
    const float* im_info = (const float*)d_in[1];
    const float* conv_w  = (const float*)d_in[2];
    const float* conv_b  = (const float*)d_in[3];
    const float* cls_w   = (const float*)d_in[4];
    const float* cls_b   = (const float*)d_in[5];
    const float* bbox_w  = (const float*)d_in[6];
    const float* bbox_b  = (const float*)d_in[7];
    float* out = (float*)d_out;

    char* ws = (char*)d_ws;
    float*    h      = (float*)(ws);                      // 67,108,864
    float*    scores = (float*)(ws + 67108864ull);        // 1,179,648
    float*    boxes  = (float*)(ws + 68288512ull);        // 4,718,592
    uint32_t* hist   = (uint32_t*)(ws + 73007104ull);     // 2,097,152
    uint32_t* cnt    = (uint32_t*)(ws + 75104256ull);     // 1,024
    uint64_t* cand   = (uint64_t*)(ws + 75105280ull);     // 262,144
    float*    ts     = (float*)(ws + 75367424ull);        // 65,536
    float*    tb     = (float*)(ws + 75432960ull);        // 262,144
    uint64_t* mask   = (uint64_t*)(ws + 75695104ull);     // 4,194,304
    float*    hs     = (float*)(ws + 80020480ull);        // 8,388,608 (dead-apad zone)
    char*     bhw    = ws + 88409088ull;                  // 131,328   (dead-apad zone)

    char* apad = ws + 67108864ull;                        // 73,531,392 (conv phase only)
    char* bwp  = ws + 140640256ull;                       // 9,437,184
    const size_t NEED_FULL = 150077440ull;

    if (ws_size >= NEED_FULL) {
        halo_zero<<<dim3(1568), 256, 0, stream>>>(apad);
        prep_w<<<dim3(2304), 256, 0, stream>>>(conv_w, bwp);
        prep_a<<<dim3(64, 8), 256, 0, stream>>>(im_data, apad);
        conv_mfma<<<dim3(4, 32, 8), 256, 0, stream>>>(apad, bwp, conv_b, h);
        // apad dead from here; hist/cand/hs/bhw live in its footprint --
        // their initialization MUST come after conv_mfma (r13 crash lesson).
        hipMemsetAsync(hist, 0, 2097152ull + 1024ull, stream);
        hipMemsetAsync(cand, 0xFF, 262144ull, stream);
        prep_hw<<<dim3(32), 256, 0, stream>>>(cls_w, bbox_w, cls_b, bbox_b, bhw);
        heads_mfma<<<dim3(16, 8), 256, 0, stream>>>(h, bhw, hs);
        heads_decode<<<dim3(128), 256, 0, stream>>>(hs, im_info, scores, boxes, hist);
    } else {
        hipMemsetAsync(hist, 0, 2097152ull + 1024ull, stream);
        hipMemsetAsync(cand, 0xFF, 262144ull, stream);
        conv3_relu<<<dim3(16, 16, 8), 256, 0, stream>>>(im_data, conv_w, conv_b, h);
        heads<<<dim3(128), 256, 0, stream>>>(h, cls_w, cls_b, bbox_w, bbox_b, im_info,
                                             scores, boxes, hist);
    }

    scan_k<<<dim3(8), 1024, 0, stream>>>(hist, cnt);
    compact_k<<<dim3(1152), 256, 0, stream>>>(scores, cnt, cand);
    sort4096_k<<<dim3(8), 1024, 0, stream>>>(cand);
    gather_top<<<dim3(63), 256, 0, stream>>>(cand, scores, boxes, ts, tb);
    nms_mask<<<dim3(32, 32, 8), 64, 0, stream>>>(tb, mask);
    nms_final<<<dim3(8), 1024, 0, stream>>>(mask, ts, tb, out);
}

// Round 16
// 921.129 us; speedup vs baseline: 1.1166x; 1.0048x over previous
//
#include <hip/hip_runtime.h>
#include <stdint.h>

#define NEG_INF_F (-1e30f)

typedef _Float16 half8 __attribute__((ext_vector_type(8)));
typedef float f32x4 __attribute__((ext_vector_type(4)));
typedef uint32_t u32x4 __attribute__((ext_vector_type(4)));

__device__ __forceinline__ uint32_t ordf(float f) {
    uint32_t u = __float_as_uint(f);
    return u ^ ((u >> 31) ? 0xFFFFFFFFu : 0x80000000u);
}

#define GLL16(g, l) __builtin_amdgcn_global_load_lds( \
    (const __attribute__((address_space(1))) void*)(g), \
    (__attribute__((address_space(3))) void*)(l), 16, 0, 0)

// Apad: [split][b][yy 0..65][xx 0..67][icb 16][rot 4][8 fp16]  (pixel = 1024 B)
// Bw:   [split][kk 9][icb 16][oc 512][rot 4][8 fp16]; rot = (g + oc) & 3.
#define APLANE 36765696ull
#define BPLANE 4718592ull

// ---------------------------------------------------------------------------
// prep_init: merged halo-zero (blocks 0..1567) + conv weight prep
// (blocks 1568..3871). Both independent; one dispatch instead of two.
// ---------------------------------------------------------------------------
__global__ __launch_bounds__(256) void prep_init(const float* __restrict__ w,
                                                 char* __restrict__ apad,
                                                 char* __restrict__ bw)
{
    if (blockIdx.x < 1568) {
        int t = blockIdx.x * 256 + threadIdx.x;     // 0 .. 401407
        int chunk = t & 63;
        int r  = t >> 6;                            // 0 .. 6271
        int p  = r % 392;
        int bs = r / 392;                           // b*2 + split
        int split = bs & 1;
        int b     = bs >> 1;
        int yy, xx;
        if (p < 68)       { yy = 0;  xx = p; }
        else if (p < 136) { yy = 65; xx = p - 68; }
        else {
            int q = p - 136;
            yy = 1 + (q >> 2);
            int s2 = q & 3;
            xx = (s2 == 0) ? 0 : 64 + s2;
        }
        *(f32x4*)(apad + (size_t)split * APLANE +
                  ((size_t)((b * 66 + yy) * 68 + xx) << 10) + chunk * 16) =
            (f32x4){0.f, 0.f, 0.f, 0.f};
    } else {
        int t = (blockIdx.x - 1568) * 256 + threadIdx.x;  // 0 .. 589823
        int split = t / 294912;
        int r  = t % 294912;
        int kk = r >> 15;
        int r2 = r & 32767;
        int icb = r2 >> 11;
        int r3  = r2 & 2047;
        int oc  = r3 >> 2;
        int rot = r3 & 3;
        int g   = (rot - oc) & 3;
        int ic0 = icb * 32 + g * 8;

        half8 hv;
        #pragma unroll
        for (int e = 0; e < 8; ++e) {
            float wf = w[(size_t)(oc * 512 + ic0 + e) * 9 + kk];
            if (split == 0) {
                hv[e] = (_Float16)wf;
            } else {
                _Float16 hi = (_Float16)wf;
                hv[e] = (_Float16)((wf - (float)hi) * 2048.0f);
            }
        }
        *(half8*)(bw + (size_t)split * BPLANE +
                  ((size_t)(kk * 16 + icb) * 2048 + r3) * 16) = hv;
    }
}

// ---------------------------------------------------------------------------
// Input prep: NCHW f32 -> padded channels-last fp16 hi/lo planes.
// ---------------------------------------------------------------------------
__global__ __launch_bounds__(256) void prep_a(const float* __restrict__ in,
                                              char* __restrict__ apad)
{
    const int y = blockIdx.x;
    const int b = blockIdx.y;
    const int t = threadIdx.x;
    __shared__ float s_tile[64][65];

    for (int c = 0; c < 8; ++c) {
        __syncthreads();
        #pragma unroll
        for (int rep = 0; rep < 16; ++rep) {
            int ic_l = rep * 4 + (t >> 6);
            int x    = t & 63;
            s_tile[ic_l][x] =
                in[(((size_t)(b * 512 + c * 64 + ic_l) * 64 + y) << 6) + x];
        }
        __syncthreads();
        #pragma unroll
        for (int q = 0; q < 4; ++q) {
            int s     = q * 256 + t;           // 0..1023
            int split = s >> 9;
            int rem   = s & 511;
            int x     = rem >> 3;
            int icb_l = (rem >> 2) & 1;
            int rot   = rem & 3;
            int xx    = x + 1;
            int g     = (rot - xx) & 3;
            int ic_l0 = icb_l * 32 + g * 8;
            half8 hv;
            #pragma unroll
            for (int e = 0; e < 8; ++e) {
                float v = s_tile[ic_l0 + e][x];
                if (split == 0) {
                    hv[e] = (_Float16)v;
                } else {
                    _Float16 hi = (_Float16)v;
                    hv[e] = (_Float16)((v - (float)hi) * 2048.0f);
                }
            }
            *(half8*)(apad + (size_t)split * APLANE +
                      ((size_t)((b * 66 + y + 1) * 68 + xx) << 10) +
                      ((c * 2 + icb_l) << 6) + (rot << 4)) = hv;
        }
    }
}

// ---------------------------------------------------------------------------
// MFMA conv: implicit GEMM, fp16 x3 split precision (round-8 structure).
// ---------------------------------------------------------------------------
__global__ __launch_bounds__(256, 2) void conv_mfma(
    const char* __restrict__ apad, const char* __restrict__ bw,
    const float* __restrict__ bias, float* __restrict__ out)
{
    __shared__ _Float16 sA[2][8704];
    __shared__ _Float16 sB[2][4096];

    const int tid = threadIdx.x;
    const int l   = tid & 63;
    const int wid = tid >> 6;
    const int m   = wid & 1;
    const int n   = wid >> 1;
    const int g   = l >> 4;
    const int l15 = l & 15;
    const int oc0 = blockIdx.x * 128;
    const int y0  = blockIdx.y * 2;
    const int b   = blockIdx.z;

    f32x4 accm[4][4], accc[4][4];
    #pragma unroll
    for (int i = 0; i < 4; ++i)
        #pragma unroll
        for (int j = 0; j < 4; ++j) {
            accm[i][j] = (f32x4){0.f, 0.f, 0.f, 0.f};
            accc[i][j] = (f32x4){0.f, 0.f, 0.f, 0.f};
        }

    auto stageA = [&](int icb) {
        for (int c = wid; c < 17; c += 4) {
            int s  = c * 64 + l;
            int px = s >> 2;
            int r  = px / 68;
            int xx = px - r * 68;
            const char* src = apad +
                ((size_t)((b * 66 + y0 + r) * 68 + xx) << 10) +
                (icb << 6) + ((s & 3) << 4);
            GLL16(src,          &sA[0][c * 512]);
            GLL16(src + APLANE, &sA[1][c * 512]);
        }
    };

    u32x4 breg[4];
    auto loadB = [&](int kk, int icb) {
        const char* bb = bw + ((size_t)(kk * 16 + icb) * 2048 + oc0 * 4) * 16;
        breg[0] = *(const u32x4*)(bb + (size_t)tid * 16);
        breg[1] = *(const u32x4*)(bb + (size_t)(tid + 256) * 16);
        breg[2] = *(const u32x4*)(bb + BPLANE + (size_t)tid * 16);
        breg[3] = *(const u32x4*)(bb + BPLANE + (size_t)(tid + 256) * 16);
    };
    auto writeB = [&]() {
        *(u32x4*)&sB[0][(size_t)tid * 8]         = breg[0];
        *(u32x4*)&sB[0][(size_t)(tid + 256) * 8] = breg[1];
        *(u32x4*)&sB[1][(size_t)tid * 8]         = breg[2];
        *(u32x4*)&sB[1][(size_t)(tid + 256) * 8] = breg[3];
    };

    stageA(0);
    loadB(0, 0);
    asm volatile("s_waitcnt vmcnt(0)" ::: "memory");
    writeB();
    __syncthreads();

    int kk = 0, icb = 0;
    for (int it = 0; it < 144; ++it) {
        int nkk = kk + 1, nicb = icb;
        if (nkk == 9) { nkk = 0; ++nicb; }
        const bool have_next = (it < 143);
        if (have_next) loadB(nkk, nicb);

        const int ky = kk / 3;
        const int kx = kk - 3 * ky;
        half8 bh[4], bl[4];
        #pragma unroll
        for (int jf = 0; jf < 4; ++jf) {
            int ocl  = n * 64 + 16 * jf + l15;
            int slot = (ocl << 2) | ((g + ocl) & 3);
            bh[jf] = *(const half8*)&sB[0][slot * 8];
            bl[jf] = *(const half8*)&sB[1][slot * 8];
        }
        const int r = m + ky;
        #pragma unroll
        for (int i = 0; i < 4; ++i) {
            int xx   = 16 * i + l15 + kx;
            int px   = r * 68 + xx;
            int slot = (px << 2) | ((g + px) & 3);
            half8 ah = *(const half8*)&sA[0][slot * 8];
            half8 al = *(const half8*)&sA[1][slot * 8];
            #pragma unroll
            for (int jf = 0; jf < 4; ++jf) {
                accm[i][jf] = __builtin_amdgcn_mfma_f32_16x16x32_f16(ah, bh[jf], accm[i][jf], 0, 0, 0);
                accc[i][jf] = __builtin_amdgcn_mfma_f32_16x16x32_f16(ah, bl[jf], accc[i][jf], 0, 0, 0);
                accc[i][jf] = __builtin_amdgcn_mfma_f32_16x16x32_f16(al, bh[jf], accc[i][jf], 0, 0, 0);
            }
        }
        __syncthreads();
        if (have_next) {
            writeB();
            if (nkk == 0) {
                stageA(nicb);
                asm volatile("s_waitcnt vmcnt(0)" ::: "memory");
            }
        }
        __syncthreads();
        kk = nkk; icb = nicb;
    }

    const float inv2048 = 4.8828125e-4f;
    #pragma unroll
    for (int i = 0; i < 4; ++i) {
        #pragma unroll
        for (int jf = 0; jf < 4; ++jf) {
            int oc = oc0 + n * 64 + 16 * jf + l15;
            int x  = 16 * i + (l >> 4) * 4;
            float bv = bias[oc];
            f32x4 vm = accm[i][jf], vc = accc[i][jf];
            f32x4 o;
            #pragma unroll
            for (int j = 0; j < 4; ++j) {
                float v = vm[j] + vc[j] * inv2048 + bv;
                o[j] = v > 0.f ? v : 0.f;
            }
            *(f32x4*)(out + (((size_t)(b * 512 + oc) << 12) +
                             ((y0 + m) << 6) + x)) = o;
        }
    }
}

// ---------------------------------------------------------------------------
// Head-weight prep + tail-buffer init (hist zero, cnt zero, cand poison).
// Runs AFTER conv_mfma: hist/cnt/cand live in dead-apad footprint (r13),
// and cnt MUST be zeroed here (r15 crash: uninitialized atomic counters).
// ---------------------------------------------------------------------------
__global__ __launch_bounds__(256) void prep_hw(
    const float* __restrict__ cls_w, const float* __restrict__ bbox_w,
    const float* __restrict__ cls_b, const float* __restrict__ bbox_b,
    char* __restrict__ bhw, uint32_t* __restrict__ hist,
    uint64_t* __restrict__ cand, uint32_t* __restrict__ cnt)
{
    int t = blockIdx.x * 256 + threadIdx.x;   // 0..8191
    int plane = t >> 12;
    int r  = t & 4095;
    int ks = r >> 8;
    int g  = (r >> 6) & 3;
    int oc = r & 63;
    int ic0 = ks * 32 + g * 8;

    half8 hv;
    #pragma unroll
    for (int e = 0; e < 8; ++e) {
        int ic = ic0 + e;
        float wf = 0.f;
        if (oc < 18)      wf = cls_w[oc * 512 + ic];
        else if (oc < 54) wf = bbox_w[(oc - 18) * 512 + ic];
        if (plane == 0) {
            hv[e] = (_Float16)wf;
        } else {
            _Float16 hi = (_Float16)wf;
            hv[e] = (_Float16)((wf - (float)hi) * 2048.0f);
        }
    }
    *(half8*)(bhw + (size_t)plane * 65536 +
              (size_t)(((ks * 4 + g) * 64 + oc)) * 16) = hv;

    if (blockIdx.x == 0) {
        if (threadIdx.x < 64) {
            int o = threadIdx.x;
            float bv = 0.f;
            if (o < 18)      bv = cls_b[o];
            else if (o < 54) bv = bbox_b[o - 18];
            *(float*)(bhw + 131072 + o * 4) = bv;
        }
        cnt[threadIdx.x] = 0u;               // all 256 u32 of cnt
    }

    // hist: 524288 u32 = 8192 threads x 64; cand: 32768 u64 = 8192 x 4.
    uint32_t* hz = hist + (size_t)t * 64;
    #pragma unroll
    for (int k = 0; k < 16; ++k)
        *(u32x4*)(hz + 4 * k) = (u32x4){0u, 0u, 0u, 0u};
    uint64_t* cz = cand + (size_t)t * 4;
    #pragma unroll
    for (int k = 0; k < 4; ++k) cz[k] = ~0ull;
}

// ---------------------------------------------------------------------------
// Heads MFMA: M=px, N=64(oc padded), K=512, fp16x3. No LDS, no barriers.
// ---------------------------------------------------------------------------
__global__ __launch_bounds__(256) void heads_mfma(
    const float* __restrict__ h, const char* __restrict__ bhw,
    float* __restrict__ hs)
{
    const int tid = threadIdx.x;
    const int l   = tid & 63;
    const int w   = tid >> 6;
    const int g   = l >> 4;
    const int l15 = l & 15;
    const int b   = blockIdx.y;
    const int px0 = blockIdx.x * 256 + w * 64;

    f32x4 accm[4][4], accc[4][4];
    #pragma unroll
    for (int i = 0; i < 4; ++i)
        #pragma unroll
        for (int j = 0; j < 4; ++j) {
            accm[i][j] = (f32x4){0.f, 0.f, 0.f, 0.f};
            accc[i][j] = (f32x4){0.f, 0.f, 0.f, 0.f};
        }

    const float* hb = h + (((size_t)(b * 512 + g * 8)) << 12) + px0 + l15;
    const float* bias64 = (const float*)(bhw + 131072);

    #pragma unroll 2
    for (int ks = 0; ks < 16; ++ks) {
        half8 bh[4], bl[4];
        #pragma unroll
        for (int jf = 0; jf < 4; ++jf) {
            size_t slot = (size_t)(((ks * 4 + g) * 64 + 16 * jf + l15)) * 16;
            bh[jf] = *(const half8*)(bhw + slot);
            bl[jf] = *(const half8*)(bhw + 65536 + slot);
        }
        #pragma unroll
        for (int i = 0; i < 4; ++i) {
            float af[8];
            #pragma unroll
            for (int e = 0; e < 8; ++e)
                af[e] = hb[(((size_t)(ks * 32 + e)) << 12) + i * 16];
            half8 ah, al;
            #pragma unroll
            for (int e = 0; e < 8; ++e) {
                _Float16 hi = (_Float16)af[e];
                ah[e] = hi;
                al[e] = (_Float16)((af[e] - (float)hi) * 2048.0f);
            }
            #pragma unroll
            for (int jf = 0; jf < 4; ++jf) {
                accm[i][jf] = __builtin_amdgcn_mfma_f32_16x16x32_f16(ah, bh[jf], accm[i][jf], 0, 0, 0);
                accc[i][jf] = __builtin_amdgcn_mfma_f32_16x16x32_f16(ah, bl[jf], accc[i][jf], 0, 0, 0);
                accc[i][jf] = __builtin_amdgcn_mfma_f32_16x16x32_f16(al, bh[jf], accc[i][jf], 0, 0, 0);
            }
        }
    }

    const float inv2048 = 4.8828125e-4f;
    float bv[4];
    #pragma unroll
    for (int jf = 0; jf < 4; ++jf) bv[jf] = bias64[16 * jf + l15];

    #pragma unroll
    for (int i = 0; i < 4; ++i) {
        #pragma unroll
        for (int jf = 0; jf < 4; ++jf) {
            int oc = 16 * jf + l15;
            #pragma unroll
            for (int j = 0; j < 4; ++j) {
                int px = px0 + i * 16 + g * 4 + j;
                float v = accm[i][jf][j] + accc[i][jf][j] * inv2048 + bv[jf];
                hs[(((size_t)(b * 4096 + px)) << 6) + oc] = v;
            }
        }
    }
}

// ---------------------------------------------------------------------------
// Decode: softmax + box decode + min-size mask from hs[b][px][64],
// PLUS fused 16-bit score histogram (hist zeroed by prep_hw).
// ---------------------------------------------------------------------------
__global__ __launch_bounds__(256) void heads_decode(
    const float* __restrict__ hs, const float* __restrict__ im_info,
    float* __restrict__ scores, float* __restrict__ boxes,
    uint32_t* __restrict__ hist)
{
    const int gid = blockIdx.x * 256 + threadIdx.x;   // 0..32767
    const int b = gid >> 12;
    const int s = gid & 4095;

    float acc[56];
    const f32x4* hp = (const f32x4*)(hs + ((size_t)gid << 6));
    #pragma unroll
    for (int q = 0; q < 14; ++q) {
        f32x4 v = hp[q];
        acc[4 * q + 0] = v[0]; acc[4 * q + 1] = v[1];
        acc[4 * q + 2] = v[2]; acc[4 * q + 3] = v[3];
    }

    const float info0 = im_info[b * 3 + 0];
    const float info1 = im_info[b * 3 + 1];
    const float info2 = im_info[b * 3 + 2];
    const float maxx = info1 - 1.0f, maxy = info0 - 1.0f;
    const float min_size = 16.0f * info2;
    const int y = s >> 6, x = s & 63;
    const float cxa = 16.f * (float)x + 8.f;
    const float cya = 16.f * (float)y + 8.f;
    const float WA[9] = {184.f, 368.f, 736.f, 128.f, 256.f, 512.f,  88.f, 176.f, 352.f};
    const float HA[9] = { 96.f, 192.f, 384.f, 128.f, 256.f, 512.f, 176.f, 352.f, 704.f};

    uint32_t* hb = hist + ((size_t)b << 16);
    const int base = b * 36864 + s * 9;
    #pragma unroll
    for (int a = 0; a < 9; ++a) {
        float c0v = acc[a], c1v = acc[9 + a];
        float mm = fmaxf(c0v, c1v);
        float e0 = expf(c0v - mm), e1 = expf(c1v - mm);
        float fg = e1 / (e0 + e1);
        float dx = acc[18 + 4 * a + 0];
        float dy = acc[18 + 4 * a + 1];
        float dw = acc[18 + 4 * a + 2];
        float dh = acc[18 + 4 * a + 3];
        float cx = dx * WA[a] + cxa;
        float cy = dy * HA[a] + cya;
        float pw = expf(dw) * WA[a];
        float ph = expf(dh) * HA[a];
        float x1 = fminf(fmaxf(cx - 0.5f * pw, 0.f), maxx);
        float y1 = fminf(fmaxf(cy - 0.5f * ph, 0.f), maxy);
        float x2 = fminf(fmaxf(cx + 0.5f * pw, 0.f), maxx);
        float y2 = fminf(fmaxf(cy + 0.5f * ph, 0.f), maxy);
        bool keep = ((x2 - x1 + 1.f) >= min_size) && ((y2 - y1 + 1.f) >= min_size);
        float sc = keep ? fg : NEG_INF_F;
        scores[base + a] = sc;
        atomicAdd(&hb[(~ordf(sc)) >> 16], 1u);
        float* bp = boxes + (size_t)(base + a) * 4;
        bp[0] = x1; bp[1] = y1; bp[2] = x2; bp[3] = y2;
    }
}

// ---------------------------------------------------------------------------
// Fallback f32 conv + fused heads (used only if ws too small for MFMA path).
// ---------------------------------------------------------------------------
__global__ __launch_bounds__(256) void conv3_relu(
    const float* __restrict__ in, const float* __restrict__ w,
    const float* __restrict__ bias, float* __restrict__ out)
{
    const int oc0 = blockIdx.x * 32;
    const int y0  = blockIdx.y * 4;
    const int b   = blockIdx.z;
    const int tid = threadIdx.x;
    const int xg  = tid & 31;
    const int og  = tid >> 5;

    __shared__ float s_in[8][6][68];
    __shared__ float s_w[32][8][9];

    float acc[4][4][2];
    #pragma unroll
    for (int o = 0; o < 4; ++o)
        #pragma unroll
        for (int yy = 0; yy < 4; ++yy) { acc[o][yy][0] = 0.f; acc[o][yy][1] = 0.f; }

    for (int ic0 = 0; ic0 < 512; ic0 += 8) {
        for (int e = tid; e < 8 * 6 * 66; e += 256) {
            int ic = e / 396; int r = e - ic * 396;
            int yy = r / 66;  int xx = r - yy * 66;
            int gy = y0 + yy - 1;
            int gx = xx - 1;
            float v = 0.f;
            if (gy >= 0 && gy < 64 && gx >= 0 && gx < 64)
                v = in[(((b * 512 + ic0 + ic) * 64 + gy) << 6) + gx];
            s_in[ic][yy][xx] = v;
        }
        {
            int oc = tid >> 3, ic = tid & 7;
            const float* wp = w + ((size_t)(oc0 + oc) * 512 + ic0 + ic) * 9;
            #pragma unroll
            for (int k = 0; k < 9; ++k) s_w[oc][ic][k] = wp[k];
        }
        __syncthreads();
        for (int ic = 0; ic < 8; ++ic) {
            #pragma unroll
            for (int ky = 0; ky < 3; ++ky) {
                #pragma unroll
                for (int kx = 0; kx < 3; ++kx) {
                    const int k = ky * 3 + kx;
                    float w0 = s_w[og][ic][k];
                    float w1 = s_w[og + 8][ic][k];
                    float w2 = s_w[og + 16][ic][k];
                    float w3 = s_w[og + 24][ic][k];
                    #pragma unroll
                    for (int yy = 0; yy < 4; ++yy) {
                        float i0 = s_in[ic][yy + ky][xg + kx];
                        float i1 = s_in[ic][yy + ky][xg + 32 + kx];
                        acc[0][yy][0] = fmaf(w0, i0, acc[0][yy][0]);
                        acc[0][yy][1] = fmaf(w0, i1, acc[0][yy][1]);
                        acc[1][yy][0] = fmaf(w1, i0, acc[1][yy][0]);
                        acc[1][yy][1] = fmaf(w1, i1, acc[1][yy][1]);
                        acc[2][yy][0] = fmaf(w2, i0, acc[2][yy][0]);
                        acc[2][yy][1] = fmaf(w2, i1, acc[2][yy][1]);
                        acc[3][yy][0] = fmaf(w3, i0, acc[3][yy][0]);
                        acc[3][yy][1] = fmaf(w3, i1, acc[3][yy][1]);
                    }
                }
            }
        }
        __syncthreads();
    }

    #pragma unroll
    for (int o = 0; o < 4; ++o) {
        int oc = oc0 + og + 8 * o;
        float bv = bias[oc];
        #pragma unroll
        for (int yy = 0; yy < 4; ++yy) {
            int y = y0 + yy;
            float* op = out + (((b * 512 + oc) * 64 + y) << 6);
            float v0 = acc[o][yy][0] + bv; v0 = v0 > 0.f ? v0 : 0.f;
            float v1 = acc[o][yy][1] + bv; v1 = v1 > 0.f ? v1 : 0.f;
            op[xg] = v0; op[xg + 32] = v1;
        }
    }
}

__global__ __launch_bounds__(256) void heads(
    const float* __restrict__ h, const float* __restrict__ cls_w,
    const float* __restrict__ cls_b, const float* __restrict__ bbox_w,
    const float* __restrict__ bbox_b, const float* __restrict__ im_info,
    float* __restrict__ scores, float* __restrict__ boxes,
    uint32_t* __restrict__ hist)
{
    const int tid = threadIdx.x;
    const int b = blockIdx.x >> 4;
    const int s = ((blockIdx.x & 15) << 8) + tid;

    __shared__ float s_w[54][64];

    float acc[54];
    #pragma unroll
    for (int o = 0; o < 54; ++o) acc[o] = 0.f;

    for (int c0 = 0; c0 < 512; c0 += 64) {
        __syncthreads();
        for (int e = tid; e < 54 * 64; e += 256) {
            int oc = e >> 6, i = e & 63;
            float v = (oc < 18) ? cls_w[oc * 512 + c0 + i]
                                : bbox_w[(oc - 18) * 512 + c0 + i];
            s_w[oc][i] = v;
        }
        __syncthreads();
        for (int i = 0; i < 64; ++i) {
            float hv = h[((b * 512 + c0 + i) << 12) + s];
            #pragma unroll
            for (int o = 0; o < 54; ++o) acc[o] = fmaf(hv, s_w[o][i], acc[o]);
        }
    }
    #pragma unroll
    for (int o = 0; o < 18; ++o) acc[o] += cls_b[o];
    #pragma unroll
    for (int o = 0; o < 36; ++o) acc[18 + o] += bbox_b[o];

    const float info0 = im_info[b * 3 + 0];
    const float info1 = im_info[b * 3 + 1];
    const float info2 = im_info[b * 3 + 2];
    const float maxx = info1 - 1.0f, maxy = info0 - 1.0f;
    const float min_size = 16.0f * info2;
    const int y = s >> 6, x = s & 63;
    const float cxa = 16.f * (float)x + 8.f;
    const float cya = 16.f * (float)y + 8.f;
    const float WA[9] = {184.f, 368.f, 736.f, 128.f, 256.f, 512.f,  88.f, 176.f, 352.f};
    const float HA[9] = { 96.f, 192.f, 384.f, 128.f, 256.f, 512.f, 176.f, 352.f, 704.f};

    uint32_t* hb = hist + ((size_t)b << 16);
    const int base = b * 36864 + s * 9;
    #pragma unroll
    for (int a = 0; a < 9; ++a) {
        float c0v = acc[a], c1v = acc[9 + a];
        float mm = fmaxf(c0v, c1v);
        float e0 = expf(c0v - mm), e1 = expf(c1v - mm);
        float fg = e1 / (e0 + e1);
        float dx = acc[18 + 4 * a + 0];
        float dy = acc[18 + 4 * a + 1];
        float dw = acc[18 + 4 * a + 2];
        float dh = acc[18 + 4 * a + 3];
        float cx = dx * WA[a] + cxa;
        float cy = dy * HA[a] + cya;
        float pw = expf(dw) * WA[a];
        float ph = expf(dh) * HA[a];
        float x1 = fminf(fmaxf(cx - 0.5f * pw, 0.f), maxx);
        float y1 = fminf(fmaxf(cy - 0.5f * ph, 0.f), maxy);
        float x2 = fminf(fmaxf(cx + 0.5f * pw, 0.f), maxx);
        float y2 = fminf(fmaxf(cy + 0.5f * ph, 0.f), maxy);
        bool keep = ((x2 - x1 + 1.f) >= min_size) && ((y2 - y1 + 1.f) >= min_size);
        float sc = keep ? fg : NEG_INF_F;
        scores[base + a] = sc;
        atomicAdd(&hb[(~ordf(sc)) >> 16], 1u);
        float* bp = boxes + (size_t)(base + a) * 4;
        bp[0] = x1; bp[1] = y1; bp[2] = x2; bp[3] = y2;
    }
}

// ---------------------------------------------------------------------------
// Top-2000 select: scan histogram, compact, sort candidates.
// ---------------------------------------------------------------------------
__global__ __launch_bounds__(1024) void scan_k(const uint32_t* __restrict__ hist,
                                               uint32_t* __restrict__ cnt)
{
    const int b = blockIdx.x;
    const int t = threadIdx.x;
    __shared__ uint32_t part[1024];
    const uint32_t* hb = hist + ((size_t)b << 16);

    uint32_t own = 0;
    #pragma unroll 4
    for (int k = 0; k < 64; ++k) own += hb[t * 64 + k];
    part[t] = own;
    __syncthreads();
    for (int off = 1; off < 1024; off <<= 1) {
        uint32_t v = (t >= off) ? part[t - off] : 0u;
        __syncthreads();
        part[t] += v;
        __syncthreads();
    }
    uint32_t incl = part[t];
    uint32_t excl = incl - own;
    if (excl < 2000u && incl >= 2000u) {
        uint32_t c = excl;
        for (int k = 0; k < 64; ++k) {
            uint32_t hh = hb[t * 64 + k];
            if (c + hh >= 2000u) { cnt[16 + b] = t * 64 + k; cnt[24 + b] = c; break; }
            c += hh;
        }
    }
}

__global__ void compact_k(const float* __restrict__ scores,
                          uint32_t* __restrict__ cnt,
                          uint64_t* __restrict__ cand)
{
    int gidx = blockIdx.x * 256 + threadIdx.x;
    int b = gidx / 36864, i = gidx - b * 36864;
    float sc = scores[b * 36864 + i];
    uint32_t kh = ~ordf(sc);
    uint32_t bin = kh >> 16;
    uint32_t T = cnt[16 + b];
    uint64_t key = ((uint64_t)kh << 32) | (uint32_t)i;
    if (bin < T) {
        uint32_t p = atomicAdd(&cnt[b * 2], 1u);
        cand[((size_t)b << 12) + p] = key;
    } else if (bin == T) {
        uint32_t p = atomicAdd(&cnt[b * 2 + 1], 1u);
        if (p < 2048u) cand[((size_t)b << 12) + 4095 - p] = key;
    }
}

// Sort 4096 candidate keys per batch in LDS, then gather top-2000 ts/tb
// directly from the sorted LDS image (no cand writeback).
__global__ __launch_bounds__(1024) void sort_gather_k(
    const uint64_t* __restrict__ cand, const float* __restrict__ scores,
    const float* __restrict__ boxes, float* __restrict__ ts,
    float* __restrict__ tb)
{
    const int b = blockIdx.x;
    const int tid = threadIdx.x;
    __shared__ uint64_t s[4096];
    for (int i = tid; i < 4096; i += 1024) s[i] = cand[((size_t)b << 12) + i];
    __syncthreads();
    for (int k = 2; k <= 4096; k <<= 1) {
        for (int j = k >> 1; j > 0; j >>= 1) {
            for (int t2 = tid; t2 < 2048; t2 += 1024) {
                int i = ((t2 & ~(j - 1)) << 1) | (t2 & (j - 1));
                int ixj = i + j;
                bool up = ((i & k) == 0);
                uint64_t a = s[i], c = s[ixj];
                if ((a > c) == up) { s[i] = c; s[ixj] = a; }
            }
            __syncthreads();
        }
    }
    for (int r = tid; r < 2000; r += 1024) {
        uint64_t k = s[r];
        int idx = (int)(uint32_t)k;
        ts[b * 2048 + r] = scores[b * 36864 + idx];
        const float* sp = boxes + ((size_t)b * 36864 + idx) * 4;
        float* dp = tb + ((size_t)b * 2048 + r) * 4;
        dp[0] = sp[0]; dp[1] = sp[1]; dp[2] = sp[2]; dp[3] = sp[3];
    }
}

// ---------------------------------------------------------------------------
// NMS: IoU bitmask build, UPPER TRIANGLE only (cb >= rb).
// ---------------------------------------------------------------------------
__global__ __launch_bounds__(64) void nms_mask(const float* __restrict__ tb,
                                               uint64_t* __restrict__ mask)
{
    const int b  = blockIdx.z;
    const int rb = blockIdx.y;
    const int cb = blockIdx.x;
    if (cb < rb) return;
    const int t  = threadIdx.x;
    __shared__ float cbox[64][4];
    const int col0 = cb * 64;
    {
        int c = col0 + t;
        if (c < 2000) {
            const float* p = tb + ((size_t)b * 2048 + c) * 4;
            cbox[t][0] = p[0]; cbox[t][1] = p[1]; cbox[t][2] = p[2]; cbox[t][3] = p[3];
        } else {
            cbox[t][0] = 0.f; cbox[t][1] = 0.f; cbox[t][2] = -1.f; cbox[t][3] = -1.f;
        }
    }
    __syncthreads();
    int row = rb * 64 + t;
    if (row >= 2000) return;
    const float* p = tb + ((size_t)b * 2048 + row) * 4;
    float x1 = p[0], y1 = p[1], x2 = p[2], y2 = p[3];
    float area = (x2 - x1 + 1.f) * (y2 - y1 + 1.f);
    uint64_t bits = 0;
    int ncol = 2000 - col0; if (ncol > 64) ncol = 64;
    for (int j = 0; j < ncol; ++j) {
        float xx1 = fmaxf(x1, cbox[j][0]);
        float yy1 = fmaxf(y1, cbox[j][1]);
        float xx2 = fminf(x2, cbox[j][2]);
        float yy2 = fminf(y2, cbox[j][3]);
        float iw = fmaxf(xx2 - xx1 + 1.f, 0.f);
        float ih = fmaxf(yy2 - yy1 + 1.f, 0.f);
        float inter = iw * ih;
        float areaj = (cbox[j][2] - cbox[j][0] + 1.f) * (cbox[j][3] - cbox[j][1] + 1.f);
        float iou = inter / (area + areaj - inter);
        if (iou > 0.7f) bits |= (1ull << j);
    }
    mask[((size_t)b * 2048 + row) * 32 + cb] = bits;
}

// ---------------------------------------------------------------------------
// Fused NMS scan + final sort + roi emit (round-12 proven).
// ---------------------------------------------------------------------------
__global__ __launch_bounds__(1024) void nms_final(
    const uint64_t* __restrict__ mask, const float* __restrict__ ts,
    const float* __restrict__ tb, float* __restrict__ out)
{
    const int b = blockIdx.x;
    const int tid = threadIdx.x;
    __shared__ uint64_t kw[32];        // keep bits, one u64 per 64 rows
    __shared__ uint64_t s[2048];

    if (tid < 64) {
        const int lane = tid;
        const uint64_t* mrow = mask + (size_t)b * 2048 * 32;
        const bool ml = (lane < 32);
        uint64_t remv = 0;
        uint32_t cur_lo = 0, cur_hi = 0;
        uint64_t kcur = 0;

        uint64_t bufA[16], bufB[16];

#define LOADG(buf, gidx) do { int base_ = (gidx) * 16;                        \
    _Pragma("unroll")                                                         \
    for (int k_ = 0; k_ < 16; ++k_) {                                         \
        int r_ = base_ + k_;                                                  \
        buf[k_] = (ml && r_ < 2000) ? mrow[(size_t)r_ * 32 + lane] : 0ull;    \
    } } while (0)

#define PROCG(buf, gidx) do { int base_ = (gidx) * 16;                        \
    _Pragma("unroll")                                                         \
    for (int k_ = 0; k_ < 16; ++k_) {                                         \
        int i_ = base_ + k_;                                                  \
        int w_ = i_ >> 6;                                                     \
        int bit_ = i_ & 63;                                                   \
        if (bit_ == 0) {                                                      \
            cur_lo = __builtin_amdgcn_readlane((uint32_t)remv, w_);           \
            cur_hi = __builtin_amdgcn_readlane((uint32_t)(remv >> 32), w_);   \
            kcur = 0;                                                         \
        }                                                                     \
        uint32_t sw_ = (bit_ < 32) ? cur_lo : cur_hi;                         \
        if (!((sw_ >> (bit_ & 31)) & 1u)) {                                   \
            kcur |= (1ull << bit_);                                           \
            if (ml) remv |= buf[k_];                                          \
            cur_lo |= __builtin_amdgcn_readlane((uint32_t)buf[k_], w_);       \
            cur_hi |= __builtin_amdgcn_readlane((uint32_t)(buf[k_] >> 32), w_);\
        }                                                                     \
        if (bit_ == 63 || i_ == 1999) { if (lane == 0) kw[w_] = kcur; }       \
    } } while (0)

        LOADG(bufA, 0);
        LOADG(bufB, 1);
        for (int gq = 0; gq < 125; gq += 2) {      // 125 groups of 16 = 2000
            PROCG(bufA, gq);
            LOADG(bufA, gq + 2);
            if (gq + 1 < 125) {
                PROCG(bufB, gq + 1);
                LOADG(bufB, gq + 3);
            }
        }
#undef LOADG
#undef PROCG
    }
    __syncthreads();                               // kw visible to all waves

    for (int i = tid; i < 2048; i += 1024) {
        uint64_t k;
        if (i < 2000) {
            bool kp = (kw[i >> 6] >> (i & 63)) & 1ull;
            float sc = kp ? ts[b * 2048 + i] : NEG_INF_F;
            k = ((uint64_t)(~ordf(sc)) << 32) | (uint32_t)i;
        } else {
            k = ~0ull;
        }
        s[i] = k;
    }
    __syncthreads();

    for (int k = 2; k <= 2048; k <<= 1) {
        for (int j = k >> 1; j > 0; j >>= 1) {
            for (int t = tid; t < 2048; t += 1024) {
                int ixj = t ^ j;
                if (ixj > t) {
                    bool up = ((t & k) == 0);
                    uint64_t a = s[t], c = s[ixj];
                    if ((a > c) == up) { s[t] = c; s[ixj] = a; }
                }
            }
            __syncthreads();
        }
    }
    for (int r = tid; r < 300; r += 1024) {
        int idx = (int)(uint32_t)s[r];
        const float* bp = tb + ((size_t)b * 2048 + idx) * 4;
        float* op = out + (size_t)(b * 300 + r) * 5;
        op[0] = (float)b;
        op[1] = bp[0]; op[2] = bp[1]; op[3] = bp[2]; op[4] = bp[3];
    }
}

// ---------------------------------------------------------------------------
extern "C" void kernel_launch(void* const* d_in, const int* in_sizes, int n_in,
                              void* d_out, int out_size, void* d_ws, size_t ws_size,
                              hipStream_t stream)
{
    const float* im_data = (const float*)d_in[0];
    const float* im_info = (const float*)d_in[1];
    const float* conv_w  = (const float*)d_in[2];
    const float* conv_b  = (const float*)d_in[3];
    const float* cls_w   = (const float*)d_in[4];
    const float* cls_b   = (const float*)d_in[5];
    const float* bbox_w  = (const float*)d_in[6];
    const float* bbox_b  = (const float*)d_in[7];
    float* out = (float*)d_out;

    char* ws = (char*)d_ws;
    float*    h      = (float*)(ws);                      // 67,108,864
    float*    scores = (float*)(ws + 67108864ull);        // 1,179,648
    float*    boxes  = (float*)(ws + 68288512ull);        // 4,718,592
    uint32_t* hist   = (uint32_t*)(ws + 73007104ull);     // 2,097,152
    uint32_t* cnt    = (uint32_t*)(ws + 75104256ull);     // 1,024
    uint64_t* cand   = (uint64_t*)(ws + 75105280ull);     // 262,144
    float*    ts     = (float*)(ws + 75367424ull);        // 65,536
    float*    tb     = (float*)(ws + 75432960ull);        // 262,144
    uint64_t* mask   = (uint64_t*)(ws + 75695104ull);     // 4,194,304
    float*    hs     = (float*)(ws + 80020480ull);        // 8,388,608 (dead-apad zone)
    char*     bhw    = ws + 88409088ull;                  // 131,328   (dead-apad zone)

    char* apad = ws + 67108864ull;                        // 73,531,392 (conv phase only)
    char* bwp  = ws + 140640256ull;                       // 9,437,184
    const size_t NEED_FULL = 150077440ull;

    if (ws_size >= NEED_FULL) {
        prep_init<<<dim3(3872), 256, 0, stream>>>(conv_w, apad, bwp);
        prep_a<<<dim3(64, 8), 256, 0, stream>>>(im_data, apad);
        conv_mfma<<<dim3(4, 32, 8), 256, 0, stream>>>(apad, bwp, conv_b, h);
        // apad dead from here; hist/cnt/cand/hs/bhw live in its footprint --
        // ALL of their initialization must come after conv_mfma (r13/r15).
        prep_hw<<<dim3(32), 256, 0, stream>>>(cls_w, bbox_w, cls_b, bbox_b,
                                              bhw, hist, cand, cnt);
        heads_mfma<<<dim3(16, 8), 256, 0, stream>>>(h, bhw, hs);
        heads_decode<<<dim3(128), 256, 0, stream>>>(hs, im_info, scores, boxes, hist);
    } else {
        hipMemsetAsync(hist, 0, 2097152ull + 1024ull, stream);
        hipMemsetAsync(cand, 0xFF, 262144ull, stream);
        conv3_relu<<<dim3(16, 16, 8), 256, 0, stream>>>(im_data, conv_w, conv_b, h);
        heads<<<dim3(128), 256, 0, stream>>>(h, cls_w, cls_b, bbox_w, bbox_b, im_info,
                                             scores, boxes, hist);
    }

    scan_k<<<dim3(8), 1024, 0, stream>>>(hist, cnt);
    compact_k<<<dim3(1152), 256, 0, stream>>>(scores, cnt, cand);
    sort_gather_k<<<dim3(8), 1024, 0, stream>>>(cand, scores, boxes, ts, tb);
    nms_mask<<<dim3(32, 32, 8), 64, 0, stream>>>(tb, mask);
    nms_final<<<dim3(8), 1024, 0, stream>>>(mask, ts, tb, out);
}

// Round 17
// 746.763 us; speedup vs baseline: 1.3774x; 1.2335x over previous
//
#include <hip/hip_runtime.h>
#include <stdint.h>

#define NEG_INF_F (-1e30f)

typedef _Float16 half8 __attribute__((ext_vector_type(8)));
typedef float f32x4 __attribute__((ext_vector_type(4)));
typedef uint32_t u32x4 __attribute__((ext_vector_type(4)));

__device__ __forceinline__ uint32_t ordf(float f) {
    uint32_t u = __float_as_uint(f);
    return u ^ ((u >> 31) ? 0xFFFFFFFFu : 0x80000000u);
}

#define GLL16(g, l) __builtin_amdgcn_global_load_lds( \
    (const __attribute__((address_space(1))) void*)(g), \
    (__attribute__((address_space(3))) void*)(l), 16, 0, 0)

// Apad: [split][b][yy 0..65][xx 0..67][icb 16][rot 4][8 fp16]  (pixel = 1024 B)
// Bw:   [split][kk 9][icb 16][oc 512][rot 4][8 fp16]; rot = (g + oc) & 3.
#define APLANE 36765696ull
#define BPLANE 4718592ull

// ---------------------------------------------------------------------------
// prep_init: merged halo-zero (blocks 0..1567) + conv weight prep
// (blocks 1568..3871).
// ---------------------------------------------------------------------------
__global__ __launch_bounds__(256) void prep_init(const float* __restrict__ w,
                                                 char* __restrict__ apad,
                                                 char* __restrict__ bw)
{
    if (blockIdx.x < 1568) {
        int t = blockIdx.x * 256 + threadIdx.x;     // 0 .. 401407
        int chunk = t & 63;
        int r  = t >> 6;                            // 0 .. 6271
        int p  = r % 392;
        int bs = r / 392;                           // b*2 + split
        int split = bs & 1;
        int b     = bs >> 1;
        int yy, xx;
        if (p < 68)       { yy = 0;  xx = p; }
        else if (p < 136) { yy = 65; xx = p - 68; }
        else {
            int q = p - 136;
            yy = 1 + (q >> 2);
            int s2 = q & 3;
            xx = (s2 == 0) ? 0 : 64 + s2;
        }
        *(f32x4*)(apad + (size_t)split * APLANE +
                  ((size_t)((b * 66 + yy) * 68 + xx) << 10) + chunk * 16) =
            (f32x4){0.f, 0.f, 0.f, 0.f};
    } else {
        int t = (blockIdx.x - 1568) * 256 + threadIdx.x;  // 0 .. 589823
        int split = t / 294912;
        int r  = t % 294912;
        int kk = r >> 15;
        int r2 = r & 32767;
        int icb = r2 >> 11;
        int r3  = r2 & 2047;
        int oc  = r3 >> 2;
        int rot = r3 & 3;
        int g   = (rot - oc) & 3;
        int ic0 = icb * 32 + g * 8;

        half8 hv;
        #pragma unroll
        for (int e = 0; e < 8; ++e) {
            float wf = w[(size_t)(oc * 512 + ic0 + e) * 9 + kk];
            if (split == 0) {
                hv[e] = (_Float16)wf;
            } else {
                _Float16 hi = (_Float16)wf;
                hv[e] = (_Float16)((wf - (float)hi) * 2048.0f);
            }
        }
        *(half8*)(bw + (size_t)split * BPLANE +
                  ((size_t)(kk * 16 + icb) * 2048 + r3) * 16) = hv;
    }
}

// ---------------------------------------------------------------------------
// Input prep: NCHW f32 -> padded channels-last fp16 hi/lo planes.
// ---------------------------------------------------------------------------
__global__ __launch_bounds__(256) void prep_a(const float* __restrict__ in,
                                              char* __restrict__ apad)
{
    const int y = blockIdx.x;
    const int b = blockIdx.y;
    const int t = threadIdx.x;
    __shared__ float s_tile[64][65];

    for (int c = 0; c < 8; ++c) {
        __syncthreads();
        #pragma unroll
        for (int rep = 0; rep < 16; ++rep) {
            int ic_l = rep * 4 + (t >> 6);
            int x    = t & 63;
            s_tile[ic_l][x] =
                in[(((size_t)(b * 512 + c * 64 + ic_l) * 64 + y) << 6) + x];
        }
        __syncthreads();
        #pragma unroll
        for (int q = 0; q < 4; ++q) {
            int s     = q * 256 + t;           // 0..1023
            int split = s >> 9;
            int rem   = s & 511;
            int x     = rem >> 3;
            int icb_l = (rem >> 2) & 1;
            int rot   = rem & 3;
            int xx    = x + 1;
            int g     = (rot - xx) & 3;
            int ic_l0 = icb_l * 32 + g * 8;
            half8 hv;
            #pragma unroll
            for (int e = 0; e < 8; ++e) {
                float v = s_tile[ic_l0 + e][x];
                if (split == 0) {
                    hv[e] = (_Float16)v;
                } else {
                    _Float16 hi = (_Float16)v;
                    hv[e] = (_Float16)((v - (float)hi) * 2048.0f);
                }
            }
            *(half8*)(apad + (size_t)split * APLANE +
                      ((size_t)((b * 66 + y + 1) * 68 + xx) << 10) +
                      ((c * 2 + icb_l) << 6) + (rot << 4)) = hv;
        }
    }
}

// ---------------------------------------------------------------------------
// MFMA conv: implicit GEMM, fp16 x3 split precision (round-8 structure).
// ---------------------------------------------------------------------------
__global__ __launch_bounds__(256, 2) void conv_mfma(
    const char* __restrict__ apad, const char* __restrict__ bw,
    const float* __restrict__ bias, float* __restrict__ out)
{
    __shared__ _Float16 sA[2][8704];
    __shared__ _Float16 sB[2][4096];

    const int tid = threadIdx.x;
    const int l   = tid & 63;
    const int wid = tid >> 6;
    const int m   = wid & 1;
    const int n   = wid >> 1;
    const int g   = l >> 4;
    const int l15 = l & 15;
    const int oc0 = blockIdx.x * 128;
    const int y0  = blockIdx.y * 2;
    const int b   = blockIdx.z;

    f32x4 accm[4][4], accc[4][4];
    #pragma unroll
    for (int i = 0; i < 4; ++i)
        #pragma unroll
        for (int j = 0; j < 4; ++j) {
            accm[i][j] = (f32x4){0.f, 0.f, 0.f, 0.f};
            accc[i][j] = (f32x4){0.f, 0.f, 0.f, 0.f};
        }

    auto stageA = [&](int icb) {
        for (int c = wid; c < 17; c += 4) {
            int s  = c * 64 + l;
            int px = s >> 2;
            int r  = px / 68;
            int xx = px - r * 68;
            const char* src = apad +
                ((size_t)((b * 66 + y0 + r) * 68 + xx) << 10) +
                (icb << 6) + ((s & 3) << 4);
            GLL16(src,          &sA[0][c * 512]);
            GLL16(src + APLANE, &sA[1][c * 512]);
        }
    };

    u32x4 breg[4];
    auto loadB = [&](int kk, int icb) {
        const char* bb = bw + ((size_t)(kk * 16 + icb) * 2048 + oc0 * 4) * 16;
        breg[0] = *(const u32x4*)(bb + (size_t)tid * 16);
        breg[1] = *(const u32x4*)(bb + (size_t)(tid + 256) * 16);
        breg[2] = *(const u32x4*)(bb + BPLANE + (size_t)tid * 16);
        breg[3] = *(const u32x4*)(bb + BPLANE + (size_t)(tid + 256) * 16);
    };
    auto writeB = [&]() {
        *(u32x4*)&sB[0][(size_t)tid * 8]         = breg[0];
        *(u32x4*)&sB[0][(size_t)(tid + 256) * 8] = breg[1];
        *(u32x4*)&sB[1][(size_t)tid * 8]         = breg[2];
        *(u32x4*)&sB[1][(size_t)(tid + 256) * 8] = breg[3];
    };

    stageA(0);
    loadB(0, 0);
    asm volatile("s_waitcnt vmcnt(0)" ::: "memory");
    writeB();
    __syncthreads();

    int kk = 0, icb = 0;
    for (int it = 0; it < 144; ++it) {
        int nkk = kk + 1, nicb = icb;
        if (nkk == 9) { nkk = 0; ++nicb; }
        const bool have_next = (it < 143);
        if (have_next) loadB(nkk, nicb);

        const int ky = kk / 3;
        const int kx = kk - 3 * ky;
        half8 bh[4], bl[4];
        #pragma unroll
        for (int jf = 0; jf < 4; ++jf) {
            int ocl  = n * 64 + 16 * jf + l15;
            int slot = (ocl << 2) | ((g + ocl) & 3);
            bh[jf] = *(const half8*)&sB[0][slot * 8];
            bl[jf] = *(const half8*)&sB[1][slot * 8];
        }
        const int r = m + ky;
        #pragma unroll
        for (int i = 0; i < 4; ++i) {
            int xx   = 16 * i + l15 + kx;
            int px   = r * 68 + xx;
            int slot = (px << 2) | ((g + px) & 3);
            half8 ah = *(const half8*)&sA[0][slot * 8];
            half8 al = *(const half8*)&sA[1][slot * 8];
            #pragma unroll
            for (int jf = 0; jf < 4; ++jf) {
                accm[i][jf] = __builtin_amdgcn_mfma_f32_16x16x32_f16(ah, bh[jf], accm[i][jf], 0, 0, 0);
                accc[i][jf] = __builtin_amdgcn_mfma_f32_16x16x32_f16(ah, bl[jf], accc[i][jf], 0, 0, 0);
                accc[i][jf] = __builtin_amdgcn_mfma_f32_16x16x32_f16(al, bh[jf], accc[i][jf], 0, 0, 0);
            }
        }
        __syncthreads();
        if (have_next) {
            writeB();
            if (nkk == 0) {
                stageA(nicb);
                asm volatile("s_waitcnt vmcnt(0)" ::: "memory");
            }
        }
        __syncthreads();
        kk = nkk; icb = nicb;
    }

    const float inv2048 = 4.8828125e-4f;
    #pragma unroll
    for (int i = 0; i < 4; ++i) {
        #pragma unroll
        for (int jf = 0; jf < 4; ++jf) {
            int oc = oc0 + n * 64 + 16 * jf + l15;
            int x  = 16 * i + (l >> 4) * 4;
            float bv = bias[oc];
            f32x4 vm = accm[i][jf], vc = accc[i][jf];
            f32x4 o;
            #pragma unroll
            for (int j = 0; j < 4; ++j) {
                float v = vm[j] + vc[j] * inv2048 + bv;
                o[j] = v > 0.f ? v : 0.f;
            }
            *(f32x4*)(out + (((size_t)(b * 512 + oc) << 12) +
                             ((y0 + m) << 6) + x)) = o;
        }
    }
}

// ---------------------------------------------------------------------------
// Head-weight prep + hist zero. Runs AFTER conv_mfma: hist/hs/bhw live in
// the dead-apad footprint (r13/r15 lessons).
// ---------------------------------------------------------------------------
__global__ __launch_bounds__(256) void prep_hw(
    const float* __restrict__ cls_w, const float* __restrict__ bbox_w,
    const float* __restrict__ cls_b, const float* __restrict__ bbox_b,
    char* __restrict__ bhw, uint32_t* __restrict__ hist)
{
    int t = blockIdx.x * 256 + threadIdx.x;   // 0..8191
    int plane = t >> 12;
    int r  = t & 4095;
    int ks = r >> 8;
    int g  = (r >> 6) & 3;
    int oc = r & 63;
    int ic0 = ks * 32 + g * 8;

    half8 hv;
    #pragma unroll
    for (int e = 0; e < 8; ++e) {
        int ic = ic0 + e;
        float wf = 0.f;
        if (oc < 18)      wf = cls_w[oc * 512 + ic];
        else if (oc < 54) wf = bbox_w[(oc - 18) * 512 + ic];
        if (plane == 0) {
            hv[e] = (_Float16)wf;
        } else {
            _Float16 hi = (_Float16)wf;
            hv[e] = (_Float16)((wf - (float)hi) * 2048.0f);
        }
    }
    *(half8*)(bhw + (size_t)plane * 65536 +
              (size_t)(((ks * 4 + g) * 64 + oc)) * 16) = hv;

    if (blockIdx.x == 0 && threadIdx.x < 64) {
        int o = threadIdx.x;
        float bv = 0.f;
        if (o < 18)      bv = cls_b[o];
        else if (o < 54) bv = bbox_b[o - 18];
        *(float*)(bhw + 131072 + o * 4) = bv;
    }

    // hist: 524288 u32 = 8192 threads x 64.
    uint32_t* hz = hist + (size_t)t * 64;
    #pragma unroll
    for (int k = 0; k < 16; ++k)
        *(u32x4*)(hz + 4 * k) = (u32x4){0u, 0u, 0u, 0u};
}

// ---------------------------------------------------------------------------
// Heads MFMA: M=px, N=64(oc padded), K=512, fp16x3. No LDS, no barriers.
// ---------------------------------------------------------------------------
__global__ __launch_bounds__(256) void heads_mfma(
    const float* __restrict__ h, const char* __restrict__ bhw,
    float* __restrict__ hs)
{
    const int tid = threadIdx.x;
    const int l   = tid & 63;
    const int w   = tid >> 6;
    const int g   = l >> 4;
    const int l15 = l & 15;
    const int b   = blockIdx.y;
    const int px0 = blockIdx.x * 256 + w * 64;

    f32x4 accm[4][4], accc[4][4];
    #pragma unroll
    for (int i = 0; i < 4; ++i)
        #pragma unroll
        for (int j = 0; j < 4; ++j) {
            accm[i][j] = (f32x4){0.f, 0.f, 0.f, 0.f};
            accc[i][j] = (f32x4){0.f, 0.f, 0.f, 0.f};
        }

    const float* hb = h + (((size_t)(b * 512 + g * 8)) << 12) + px0 + l15;
    const float* bias64 = (const float*)(bhw + 131072);

    #pragma unroll 2
    for (int ks = 0; ks < 16; ++ks) {
        half8 bh[4], bl[4];
        #pragma unroll
        for (int jf = 0; jf < 4; ++jf) {
            size_t slot = (size_t)(((ks * 4 + g) * 64 + 16 * jf + l15)) * 16;
            bh[jf] = *(const half8*)(bhw + slot);
            bl[jf] = *(const half8*)(bhw + 65536 + slot);
        }
        #pragma unroll
        for (int i = 0; i < 4; ++i) {
            float af[8];
            #pragma unroll
            for (int e = 0; e < 8; ++e)
                af[e] = hb[(((size_t)(ks * 32 + e)) << 12) + i * 16];
            half8 ah, al;
            #pragma unroll
            for (int e = 0; e < 8; ++e) {
                _Float16 hi = (_Float16)af[e];
                ah[e] = hi;
                al[e] = (_Float16)((af[e] - (float)hi) * 2048.0f);
            }
            #pragma unroll
            for (int jf = 0; jf < 4; ++jf) {
                accm[i][jf] = __builtin_amdgcn_mfma_f32_16x16x32_f16(ah, bh[jf], accm[i][jf], 0, 0, 0);
                accc[i][jf] = __builtin_amdgcn_mfma_f32_16x16x32_f16(ah, bl[jf], accc[i][jf], 0, 0, 0);
                accc[i][jf] = __builtin_amdgcn_mfma_f32_16x16x32_f16(al, bh[jf], accc[i][jf], 0, 0, 0);
            }
        }
    }

    const float inv2048 = 4.8828125e-4f;
    float bv[4];
    #pragma unroll
    for (int jf = 0; jf < 4; ++jf) bv[jf] = bias64[16 * jf + l15];

    #pragma unroll
    for (int i = 0; i < 4; ++i) {
        #pragma unroll
        for (int jf = 0; jf < 4; ++jf) {
            int oc = 16 * jf + l15;
            #pragma unroll
            for (int j = 0; j < 4; ++j) {
                int px = px0 + i * 16 + g * 4 + j;
                float v = accm[i][jf][j] + accc[i][jf][j] * inv2048 + bv[jf];
                hs[(((size_t)(b * 4096 + px)) << 6) + oc] = v;
            }
        }
    }
}

// ---------------------------------------------------------------------------
// Decode: softmax + box decode + min-size mask from hs[b][px][64],
// PLUS fused 16-bit score histogram (hist zeroed by prep_hw).
// ---------------------------------------------------------------------------
__global__ __launch_bounds__(256) void heads_decode(
    const float* __restrict__ hs, const float* __restrict__ im_info,
    float* __restrict__ scores, float* __restrict__ boxes,
    uint32_t* __restrict__ hist)
{
    const int gid = blockIdx.x * 256 + threadIdx.x;   // 0..32767
    const int b = gid >> 12;
    const int s = gid & 4095;

    float acc[56];
    const f32x4* hp = (const f32x4*)(hs + ((size_t)gid << 6));
    #pragma unroll
    for (int q = 0; q < 14; ++q) {
        f32x4 v = hp[q];
        acc[4 * q + 0] = v[0]; acc[4 * q + 1] = v[1];
        acc[4 * q + 2] = v[2]; acc[4 * q + 3] = v[3];
    }

    const float info0 = im_info[b * 3 + 0];
    const float info1 = im_info[b * 3 + 1];
    const float info2 = im_info[b * 3 + 2];
    const float maxx = info1 - 1.0f, maxy = info0 - 1.0f;
    const float min_size = 16.0f * info2;
    const int y = s >> 6, x = s & 63;
    const float cxa = 16.f * (float)x + 8.f;
    const float cya = 16.f * (float)y + 8.f;
    const float WA[9] = {184.f, 368.f, 736.f, 128.f, 256.f, 512.f,  88.f, 176.f, 352.f};
    const float HA[9] = { 96.f, 192.f, 384.f, 128.f, 256.f, 512.f, 176.f, 352.f, 704.f};

    uint32_t* hb = hist + ((size_t)b << 16);
    const int base = b * 36864 + s * 9;
    #pragma unroll
    for (int a = 0; a < 9; ++a) {
        float c0v = acc[a], c1v = acc[9 + a];
        float mm = fmaxf(c0v, c1v);
        float e0 = expf(c0v - mm), e1 = expf(c1v - mm);
        float fg = e1 / (e0 + e1);
        float dx = acc[18 + 4 * a + 0];
        float dy = acc[18 + 4 * a + 1];
        float dw = acc[18 + 4 * a + 2];
        float dh = acc[18 + 4 * a + 3];
        float cx = dx * WA[a] + cxa;
        float cy = dy * HA[a] + cya;
        float pw = expf(dw) * WA[a];
        float ph = expf(dh) * HA[a];
        float x1 = fminf(fmaxf(cx - 0.5f * pw, 0.f), maxx);
        float y1 = fminf(fmaxf(cy - 0.5f * ph, 0.f), maxy);
        float x2 = fminf(fmaxf(cx + 0.5f * pw, 0.f), maxx);
        float y2 = fminf(fmaxf(cy + 0.5f * ph, 0.f), maxy);
        bool keep = ((x2 - x1 + 1.f) >= min_size) && ((y2 - y1 + 1.f) >= min_size);
        float sc = keep ? fg : NEG_INF_F;
        scores[base + a] = sc;
        atomicAdd(&hb[(~ordf(sc)) >> 16], 1u);
        float* bp = boxes + (size_t)(base + a) * 4;
        bp[0] = x1; bp[1] = y1; bp[2] = x2; bp[3] = y2;
    }
}

// ---------------------------------------------------------------------------
// Fallback f32 conv + fused heads (used only if ws too small for MFMA path).
// ---------------------------------------------------------------------------
__global__ __launch_bounds__(256) void conv3_relu(
    const float* __restrict__ in, const float* __restrict__ w,
    const float* __restrict__ bias, float* __restrict__ out)
{
    const int oc0 = blockIdx.x * 32;
    const int y0  = blockIdx.y * 4;
    const int b   = blockIdx.z;
    const int tid = threadIdx.x;
    const int xg  = tid & 31;
    const int og  = tid >> 5;

    __shared__ float s_in[8][6][68];
    __shared__ float s_w[32][8][9];

    float acc[4][4][2];
    #pragma unroll
    for (int o = 0; o < 4; ++o)
        #pragma unroll
        for (int yy = 0; yy < 4; ++yy) { acc[o][yy][0] = 0.f; acc[o][yy][1] = 0.f; }

    for (int ic0 = 0; ic0 < 512; ic0 += 8) {
        for (int e = tid; e < 8 * 6 * 66; e += 256) {
            int ic = e / 396; int r = e - ic * 396;
            int yy = r / 66;  int xx = r - yy * 66;
            int gy = y0 + yy - 1;
            int gx = xx - 1;
            float v = 0.f;
            if (gy >= 0 && gy < 64 && gx >= 0 && gx < 64)
                v = in[(((b * 512 + ic0 + ic) * 64 + gy) << 6) + gx];
            s_in[ic][yy][xx] = v;
        }
        {
            int oc = tid >> 3, ic = tid & 7;
            const float* wp = w + ((size_t)(oc0 + oc) * 512 + ic0 + ic) * 9;
            #pragma unroll
            for (int k = 0; k < 9; ++k) s_w[oc][ic][k] = wp[k];
        }
        __syncthreads();
        for (int ic = 0; ic < 8; ++ic) {
            #pragma unroll
            for (int ky = 0; ky < 3; ++ky) {
                #pragma unroll
                for (int kx = 0; kx < 3; ++kx) {
                    const int k = ky * 3 + kx;
                    float w0 = s_w[og][ic][k];
                    float w1 = s_w[og + 8][ic][k];
                    float w2 = s_w[og + 16][ic][k];
                    float w3 = s_w[og + 24][ic][k];
                    #pragma unroll
                    for (int yy = 0; yy < 4; ++yy) {
                        float i0 = s_in[ic][yy + ky][xg + kx];
                        float i1 = s_in[ic][yy + ky][xg + 32 + kx];
                        acc[0][yy][0] = fmaf(w0, i0, acc[0][yy][0]);
                        acc[0][yy][1] = fmaf(w0, i1, acc[0][yy][1]);
                        acc[1][yy][0] = fmaf(w1, i0, acc[1][yy][0]);
                        acc[1][yy][1] = fmaf(w1, i1, acc[1][yy][1]);
                        acc[2][yy][0] = fmaf(w2, i0, acc[2][yy][0]);
                        acc[2][yy][1] = fmaf(w2, i1, acc[2][yy][1]);
                        acc[3][yy][0] = fmaf(w3, i0, acc[3][yy][0]);
                        acc[3][yy][1] = fmaf(w3, i1, acc[3][yy][1]);
                    }
                }
            }
        }
        __syncthreads();
    }

    #pragma unroll
    for (int o = 0; o < 4; ++o) {
        int oc = oc0 + og + 8 * o;
        float bv = bias[oc];
        #pragma unroll
        for (int yy = 0; yy < 4; ++yy) {
            int y = y0 + yy;
            float* op = out + (((b * 512 + oc) * 64 + y) << 6);
            float v0 = acc[o][yy][0] + bv; v0 = v0 > 0.f ? v0 : 0.f;
            float v1 = acc[o][yy][1] + bv; v1 = v1 > 0.f ? v1 : 0.f;
            op[xg] = v0; op[xg + 32] = v1;
        }
    }
}

__global__ __launch_bounds__(256) void heads(
    const float* __restrict__ h, const float* __restrict__ cls_w,
    const float* __restrict__ cls_b, const float* __restrict__ bbox_w,
    const float* __restrict__ bbox_b, const float* __restrict__ im_info,
    float* __restrict__ scores, float* __restrict__ boxes,
    uint32_t* __restrict__ hist)
{
    const int tid = threadIdx.x;
    const int b = blockIdx.x >> 4;
    const int s = ((blockIdx.x & 15) << 8) + tid;

    __shared__ float s_w[54][64];

    float acc[54];
    #pragma unroll
    for (int o = 0; o < 54; ++o) acc[o] = 0.f;

    for (int c0 = 0; c0 < 512; c0 += 64) {
        __syncthreads();
        for (int e = tid; e < 54 * 64; e += 256) {
            int oc = e >> 6, i = e & 63;
            float v = (oc < 18) ? cls_w[oc * 512 + c0 + i]
                                : bbox_w[(oc - 18) * 512 + c0 + i];
            s_w[oc][i] = v;
        }
        __syncthreads();
        for (int i = 0; i < 64; ++i) {
            float hv = h[((b * 512 + c0 + i) << 12) + s];
            #pragma unroll
            for (int o = 0; o < 54; ++o) acc[o] = fmaf(hv, s_w[o][i], acc[o]);
        }
    }
    #pragma unroll
    for (int o = 0; o < 18; ++o) acc[o] += cls_b[o];
    #pragma unroll
    for (int o = 0; o < 36; ++o) acc[18 + o] += bbox_b[o];

    const float info0 = im_info[b * 3 + 0];
    const float info1 = im_info[b * 3 + 1];
    const float info2 = im_info[b * 3 + 2];
    const float maxx = info1 - 1.0f, maxy = info0 - 1.0f;
    const float min_size = 16.0f * info2;
    const int y = s >> 6, x = s & 63;
    const float cxa = 16.f * (float)x + 8.f;
    const float cya = 16.f * (float)y + 8.f;
    const float WA[9] = {184.f, 368.f, 736.f, 128.f, 256.f, 512.f,  88.f, 176.f, 352.f};
    const float HA[9] = { 96.f, 192.f, 384.f, 128.f, 256.f, 512.f, 176.f, 352.f, 704.f};

    uint32_t* hb = hist + ((size_t)b << 16);
    const int base = b * 36864 + s * 9;
    #pragma unroll
    for (int a = 0; a < 9; ++a) {
        float c0v = acc[a], c1v = acc[9 + a];
        float mm = fmaxf(c0v, c1v);
        float e0 = expf(c0v - mm), e1 = expf(c1v - mm);
        float fg = e1 / (e0 + e1);
        float dx = acc[18 + 4 * a + 0];
        float dy = acc[18 + 4 * a + 1];
        float dw = acc[18 + 4 * a + 2];
        float dh = acc[18 + 4 * a + 3];
        float cx = dx * WA[a] + cxa;
        float cy = dy * HA[a] + cya;
        float pw = expf(dw) * WA[a];
        float ph = expf(dh) * HA[a];
        float x1 = fminf(fmaxf(cx - 0.5f * pw, 0.f), maxx);
        float y1 = fminf(fmaxf(cy - 0.5f * ph, 0.f), maxy);
        float x2 = fminf(fmaxf(cx + 0.5f * pw, 0.f), maxx);
        float y2 = fminf(fmaxf(cy + 0.5f * ph, 0.f), maxy);
        bool keep = ((x2 - x1 + 1.f) >= min_size) && ((y2 - y1 + 1.f) >= min_size);
        float sc = keep ? fg : NEG_INF_F;
        scores[base + a] = sc;
        atomicAdd(&hb[(~ordf(sc)) >> 16], 1u);
        float* bp = boxes + (size_t)(base + a) * 4;
        bp[0] = x1; bp[1] = y1; bp[2] = x2; bp[3] = y2;
    }
}

// ---------------------------------------------------------------------------
// select_k: per-batch fused top-2000 select. One 1024-thread block per batch:
// (1) histogram threshold scan (scan_k verbatim, result in LDS), (2) compact
// candidates into LDS via LDS atomics (same semantics as global compact_k),
// (3) bitonic sort 4096 in LDS, (4) gather top-2000 ts/tb.
// ---------------------------------------------------------------------------
__global__ __launch_bounds__(1024) void select_k(
    const uint32_t* __restrict__ hist, const float* __restrict__ scores,
    const float* __restrict__ boxes, float* __restrict__ ts,
    float* __restrict__ tb)
{
    const int b = blockIdx.x;
    const int t = threadIdx.x;
    __shared__ uint64_t s[4096];       // candidate keys (32 KB)
    __shared__ uint32_t part[1024];
    __shared__ uint32_t thr;
    __shared__ uint32_t sel[2];        // [0]=definite count, [1]=boundary count

    const uint32_t* hb = hist + ((size_t)b << 16);

    // ---- threshold-bin scan + LDS init ----
    uint32_t own = 0;
    #pragma unroll 4
    for (int k = 0; k < 64; ++k) own += hb[t * 64 + k];
    part[t] = own;
    for (int i = t; i < 4096; i += 1024) s[i] = ~0ull;
    if (t < 2) sel[t] = 0u;
    __syncthreads();
    for (int off = 1; off < 1024; off <<= 1) {
        uint32_t v = (t >= off) ? part[t - off] : 0u;
        __syncthreads();
        part[t] += v;
        __syncthreads();
    }
    uint32_t incl = part[t];
    uint32_t excl = incl - own;
    if (excl < 2000u && incl >= 2000u) {
        uint32_t c = excl;
        for (int k = 0; k < 64; ++k) {
            uint32_t hh = hb[t * 64 + k];
            if (c + hh >= 2000u) { thr = t * 64 + k; break; }
            c += hh;
        }
    }
    __syncthreads();
    const uint32_t T = thr;

    // ---- compact into LDS (definite < 2000 go [0,2000); boundary capped
    //      2048 go [2048,4096) top-down; untouched slots stay ~0 = +inf) ----
    for (int i = t; i < 36864; i += 1024) {
        float sc = scores[b * 36864 + i];
        uint32_t kh = ~ordf(sc);
        uint32_t bin = kh >> 16;
        uint64_t key = ((uint64_t)kh << 32) | (uint32_t)i;
        if (bin < T) {
            uint32_t p = atomicAdd(&sel[0], 1u);
            s[p] = key;
        } else if (bin == T) {
            uint32_t p = atomicAdd(&sel[1], 1u);
            if (p < 2048u) s[4095 - p] = key;
        }
    }
    __syncthreads();

    // ---- bitonic sort 4096 ----
    for (int k = 2; k <= 4096; k <<= 1) {
        for (int j = k >> 1; j > 0; j >>= 1) {
            for (int t2 = t; t2 < 2048; t2 += 1024) {
                int i = ((t2 & ~(j - 1)) << 1) | (t2 & (j - 1));
                int ixj = i + j;
                bool up = ((i & k) == 0);
                uint64_t a = s[i], c = s[ixj];
                if ((a > c) == up) { s[i] = c; s[ixj] = a; }
            }
            __syncthreads();
        }
    }

    // ---- gather top-2000 ----
    for (int r = t; r < 2000; r += 1024) {
        uint64_t k = s[r];
        int idx = (int)(uint32_t)k;
        ts[b * 2048 + r] = scores[b * 36864 + idx];
        const float* sp = boxes + ((size_t)b * 36864 + idx) * 4;
        float* dp = tb + ((size_t)b * 2048 + r) * 4;
        dp[0] = sp[0]; dp[1] = sp[1]; dp[2] = sp[2]; dp[3] = sp[3];
    }
}

// ---------------------------------------------------------------------------
// NMS: IoU bitmask build, UPPER TRIANGLE only (cb >= rb).
// ---------------------------------------------------------------------------
__global__ __launch_bounds__(64) void nms_mask(const float* __restrict__ tb,
                                               uint64_t* __restrict__ mask)
{
    const int b  = blockIdx.z;
    const int rb = blockIdx.y;
    const int cb = blockIdx.x;
    if (cb < rb) return;
    const int t  = threadIdx.x;
    __shared__ float cbox[64][4];
    const int col0 = cb * 64;
    {
        int c = col0 + t;
        if (c < 2000) {
            const float* p = tb + ((size_t)b * 2048 + c) * 4;
            cbox[t][0] = p[0]; cbox[t][1] = p[1]; cbox[t][2] = p[2]; cbox[t][3] = p[3];
        } else {
            cbox[t][0] = 0.f; cbox[t][1] = 0.f; cbox[t][2] = -1.f; cbox[t][3] = -1.f;
        }
    }
    __syncthreads();
    int row = rb * 64 + t;
    if (row >= 2000) return;
    const float* p = tb + ((size_t)b * 2048 + row) * 4;
    float x1 = p[0], y1 = p[1], x2 = p[2], y2 = p[3];
    float area = (x2 - x1 + 1.f) * (y2 - y1 + 1.f);
    uint64_t bits = 0;
    int ncol = 2000 - col0; if (ncol > 64) ncol = 64;
    for (int j = 0; j < ncol; ++j) {
        float xx1 = fmaxf(x1, cbox[j][0]);
        float yy1 = fmaxf(y1, cbox[j][1]);
        float xx2 = fminf(x2, cbox[j][2]);
        float yy2 = fminf(y2, cbox[j][3]);
        float iw = fmaxf(xx2 - xx1 + 1.f, 0.f);
        float ih = fmaxf(yy2 - yy1 + 1.f, 0.f);
        float inter = iw * ih;
        float areaj = (cbox[j][2] - cbox[j][0] + 1.f) * (cbox[j][3] - cbox[j][1] + 1.f);
        float iou = inter / (area + areaj - inter);
        if (iou > 0.7f) bits |= (1ull << j);
    }
    mask[((size_t)b * 2048 + row) * 32 + cb] = bits;
}

// ---------------------------------------------------------------------------
// Fused NMS scan + final sort + roi emit (round-12 proven).
// ---------------------------------------------------------------------------
__global__ __launch_bounds__(1024) void nms_final(
    const uint64_t* __restrict__ mask, const float* __restrict__ ts,
    const float* __restrict__ tb, float* __restrict__ out)
{
    const int b = blockIdx.x;
    const int tid = threadIdx.x;
    __shared__ uint64_t kw[32];        // keep bits, one u64 per 64 rows
    __shared__ uint64_t s[2048];

    if (tid < 64) {
        const int lane = tid;
        const uint64_t* mrow = mask + (size_t)b * 2048 * 32;
        const bool ml = (lane < 32);
        uint64_t remv = 0;
        uint32_t cur_lo = 0, cur_hi = 0;
        uint64_t kcur = 0;

        uint64_t bufA[16], bufB[16];

#define LOADG(buf, gidx) do { int base_ = (gidx) * 16;                        \
    _Pragma("unroll")                                                         \
    for (int k_ = 0; k_ < 16; ++k_) {                                         \
        int r_ = base_ + k_;                                                  \
        buf[k_] = (ml && r_ < 2000) ? mrow[(size_t)r_ * 32 + lane] : 0ull;    \
    } } while (0)

#define PROCG(buf, gidx) do { int base_ = (gidx) * 16;                        \
    _Pragma("unroll")                                                         \
    for (int k_ = 0; k_ < 16; ++k_) {                                         \
        int i_ = base_ + k_;                                                  \
        int w_ = i_ >> 6;                                                     \
        int bit_ = i_ & 63;                                                   \
        if (bit_ == 0) {                                                      \
            cur_lo = __builtin_amdgcn_readlane((uint32_t)remv, w_);           \
            cur_hi = __builtin_amdgcn_readlane((uint32_t)(remv >> 32), w_);   \
            kcur = 0;                                                         \
        }                                                                     \
        uint32_t sw_ = (bit_ < 32) ? cur_lo : cur_hi;                         \
        if (!((sw_ >> (bit_ & 31)) & 1u)) {                                   \
            kcur |= (1ull << bit_);                                           \
            if (ml) remv |= buf[k_];                                          \
            cur_lo |= __builtin_amdgcn_readlane((uint32_t)buf[k_], w_);       \
            cur_hi |= __builtin_amdgcn_readlane((uint32_t)(buf[k_] >> 32), w_);\
        }                                                                     \
        if (bit_ == 63 || i_ == 1999) { if (lane == 0) kw[w_] = kcur; }       \
    } } while (0)

        LOADG(bufA, 0);
        LOADG(bufB, 1);
        for (int gq = 0; gq < 125; gq += 2) {      // 125 groups of 16 = 2000
            PROCG(bufA, gq);
            LOADG(bufA, gq + 2);
            if (gq + 1 < 125) {
                PROCG(bufB, gq + 1);
                LOADG(bufB, gq + 3);
            }
        }
#undef LOADG
#undef PROCG
    }
    __syncthreads();                               // kw visible to all waves

    for (int i = tid; i < 2048; i += 1024) {
        uint64_t k;
        if (i < 2000) {
            bool kp = (kw[i >> 6] >> (i & 63)) & 1ull;
            float sc = kp ? ts[b * 2048 + i] : NEG_INF_F;
            k = ((uint64_t)(~ordf(sc)) << 32) | (uint32_t)i;
        } else {
            k = ~0ull;
        }
        s[i] = k;
    }
    __syncthreads();

    for (int k = 2; k <= 2048; k <<= 1) {
        for (int j = k >> 1; j > 0; j >>= 1) {
            for (int t = tid; t < 2048; t += 1024) {
                int ixj = t ^ j;
                if (ixj > t) {
                    bool up = ((t & k) == 0);
                    uint64_t a = s[t], c = s[ixj];
                    if ((a > c) == up) { s[t] = c; s[ixj] = a; }
                }
            }
            __syncthreads();
        }
    }
    for (int r = tid; r < 300; r += 1024) {
        int idx = (int)(uint32_t)s[r];
        const float* bp = tb + ((size_t)b * 2048 + idx) * 4;
        float* op = out + (size_t)(b * 300 + r) * 5;
        op[0] = (float)b;
        op[1] = bp[0]; op[2] = bp[1]; op[3] = bp[2]; op[4] = bp[3];
    }
}

// ---------------------------------------------------------------------------
extern "C" void kernel_launch(void* const* d_in, const int* in_sizes, int n_in,
                              void* d_out, int out_size, void* d_ws, size_t ws_size,
                              hipStream_t stream)
{
    const float* im_data = (const float*)d_in[0];
    const float* im_info = (const float*)d_in[1];
    const float* conv_w  = (const float*)d_in[2];
    const float* conv_b  = (const float*)d_in[3];
    const float* cls_w   = (const float*)d_in[4];
    const float* cls_b   = (const float*)d_in[5];
    const float* bbox_w  = (const float*)d_in[6];
    const float* bbox_b  = (const float*)d_in[7];
    float* out = (float*)d_out;

    char* ws = (char*)d_ws;
    float*    h      = (float*)(ws);                      // 67,108,864
    float*    scores = (float*)(ws + 67108864ull);        // 1,179,648
    float*    boxes  = (float*)(ws + 68288512ull);        // 4,718,592
    uint32_t* hist   = (uint32_t*)(ws + 73007104ull);     // 2,097,152
    float*    ts     = (float*)(ws + 75367424ull);        // 65,536
    float*    tb     = (float*)(ws + 75432960ull);        // 262,144
    uint64_t* mask   = (uint64_t*)(ws + 75695104ull);     // 4,194,304
    float*    hs     = (float*)(ws + 80020480ull);        // 8,388,608 (dead-apad zone)
    char*     bhw    = ws + 88409088ull;                  // 131,328   (dead-apad zone)

    char* apad = ws + 67108864ull;                        // 73,531,392 (conv phase only)
    char* bwp  = ws + 140640256ull;                       // 9,437,184
    const size_t NEED_FULL = 150077440ull;

    if (ws_size >= NEED_FULL) {
        prep_init<<<dim3(3872), 256, 0, stream>>>(conv_w, apad, bwp);
        prep_a<<<dim3(64, 8), 256, 0, stream>>>(im_data, apad);
        conv_mfma<<<dim3(4, 32, 8), 256, 0, stream>>>(apad, bwp, conv_b, h);
        // apad dead from here; hist/hs/bhw live in its footprint --
        // ALL of their initialization must come after conv_mfma (r13/r15).
        prep_hw<<<dim3(32), 256, 0, stream>>>(cls_w, bbox_w, cls_b, bbox_b,
                                              bhw, hist);
        heads_mfma<<<dim3(16, 8), 256, 0, stream>>>(h, bhw, hs);
        heads_decode<<<dim3(128), 256, 0, stream>>>(hs, im_info, scores, boxes, hist);
    } else {
        hipMemsetAsync(hist, 0, 2097152ull, stream);
        conv3_relu<<<dim3(16, 16, 8), 256, 0, stream>>>(im_data, conv_w, conv_b, h);
        heads<<<dim3(128), 256, 0, stream>>>(h, cls_w, cls_b, bbox_w, bbox_b, im_info,
                                             scores, boxes, hist);
    }

    select_k<<<dim3(8), 1024, 0, stream>>>(hist, scores, boxes, ts, tb);
    nms_mask<<<dim3(32, 32, 8), 64, 0, stream>>>(tb, mask);
    nms_final<<<dim3(8), 1024, 0, stream>>>(mask, ts, tb, out);
}

// Round 18
// 739.864 us; speedup vs baseline: 1.3902x; 1.0093x over previous
//
#include <hip/hip_runtime.h>
#include <stdint.h>

#define NEG_INF_F (-1e30f)

typedef _Float16 half8 __attribute__((ext_vector_type(8)));
typedef float f32x4 __attribute__((ext_vector_type(4)));
typedef uint32_t u32x4 __attribute__((ext_vector_type(4)));

__device__ __forceinline__ uint32_t ordf(float f) {
    uint32_t u = __float_as_uint(f);
    return u ^ ((u >> 31) ? 0xFFFFFFFFu : 0x80000000u);
}

#define GLL16(g, l) __builtin_amdgcn_global_load_lds( \
    (const __attribute__((address_space(1))) void*)(g), \
    (__attribute__((address_space(3))) void*)(l), 16, 0, 0)

// Apad: [split][b][yy 0..65][xx 0..67][icb 16][rot 4][8 fp16]  (pixel = 1024 B)
// Bw:   [split][kk 9][icb 16][oc 512][rot 4][8 fp16]; rot = (g + oc) & 3.
#define APLANE 36765696ull
#define BPLANE 4718592ull

// ---------------------------------------------------------------------------
// prep_init: merged halo-zero (blocks 0..1567) + conv weight prep
// (blocks 1568..3871) + input prep (blocks 3872..4383). All independent;
// halo and prep_a write disjoint apad regions.
// ---------------------------------------------------------------------------
__global__ __launch_bounds__(256) void prep_init(const float* __restrict__ w,
                                                 const float* __restrict__ in,
                                                 char* __restrict__ apad,
                                                 char* __restrict__ bw)
{
    __shared__ float s_tile[64][65];

    if (blockIdx.x < 1568) {
        int t = blockIdx.x * 256 + threadIdx.x;     // 0 .. 401407
        int chunk = t & 63;
        int r  = t >> 6;                            // 0 .. 6271
        int p  = r % 392;
        int bs = r / 392;                           // b*2 + split
        int split = bs & 1;
        int b     = bs >> 1;
        int yy, xx;
        if (p < 68)       { yy = 0;  xx = p; }
        else if (p < 136) { yy = 65; xx = p - 68; }
        else {
            int q = p - 136;
            yy = 1 + (q >> 2);
            int s2 = q & 3;
            xx = (s2 == 0) ? 0 : 64 + s2;
        }
        *(f32x4*)(apad + (size_t)split * APLANE +
                  ((size_t)((b * 66 + yy) * 68 + xx) << 10) + chunk * 16) =
            (f32x4){0.f, 0.f, 0.f, 0.f};
    } else if (blockIdx.x < 3872) {
        int t = (blockIdx.x - 1568) * 256 + threadIdx.x;  // 0 .. 589823
        int split = t / 294912;
        int r  = t % 294912;
        int kk = r >> 15;
        int r2 = r & 32767;
        int icb = r2 >> 11;
        int r3  = r2 & 2047;
        int oc  = r3 >> 2;
        int rot = r3 & 3;
        int g   = (rot - oc) & 3;
        int ic0 = icb * 32 + g * 8;

        half8 hv;
        #pragma unroll
        for (int e = 0; e < 8; ++e) {
            float wf = w[(size_t)(oc * 512 + ic0 + e) * 9 + kk];
            if (split == 0) {
                hv[e] = (_Float16)wf;
            } else {
                _Float16 hi = (_Float16)wf;
                hv[e] = (_Float16)((wf - (float)hi) * 2048.0f);
            }
        }
        *(half8*)(bw + (size_t)split * BPLANE +
                  ((size_t)(kk * 16 + icb) * 2048 + r3) * 16) = hv;
    } else {
        const int idx = blockIdx.x - 3872;          // 0..511
        const int y = idx & 63;
        const int b = idx >> 6;
        const int t = threadIdx.x;

        for (int c = 0; c < 8; ++c) {
            __syncthreads();
            #pragma unroll
            for (int rep = 0; rep < 16; ++rep) {
                int ic_l = rep * 4 + (t >> 6);
                int x    = t & 63;
                s_tile[ic_l][x] =
                    in[(((size_t)(b * 512 + c * 64 + ic_l) * 64 + y) << 6) + x];
            }
            __syncthreads();
            #pragma unroll
            for (int q = 0; q < 4; ++q) {
                int s     = q * 256 + t;           // 0..1023
                int split = s >> 9;
                int rem   = s & 511;
                int x     = rem >> 3;
                int icb_l = (rem >> 2) & 1;
                int rot   = rem & 3;
                int xx    = x + 1;
                int g     = (rot - xx) & 3;
                int ic_l0 = icb_l * 32 + g * 8;
                half8 hv;
                #pragma unroll
                for (int e = 0; e < 8; ++e) {
                    float v = s_tile[ic_l0 + e][x];
                    if (split == 0) {
                        hv[e] = (_Float16)v;
                    } else {
                        _Float16 hi = (_Float16)v;
                        hv[e] = (_Float16)((v - (float)hi) * 2048.0f);
                    }
                }
                *(half8*)(apad + (size_t)split * APLANE +
                          ((size_t)((b * 66 + y + 1) * 68 + xx) << 10) +
                          ((c * 2 + icb_l) << 6) + (rot << 4)) = hv;
            }
        }
    }
}

// ---------------------------------------------------------------------------
// MFMA conv: implicit GEMM, fp16 x3 split precision (round-8 structure).
// ---------------------------------------------------------------------------
__global__ __launch_bounds__(256, 2) void conv_mfma(
    const char* __restrict__ apad, const char* __restrict__ bw,
    const float* __restrict__ bias, float* __restrict__ out)
{
    __shared__ _Float16 sA[2][8704];
    __shared__ _Float16 sB[2][4096];

    const int tid = threadIdx.x;
    const int l   = tid & 63;
    const int wid = tid >> 6;
    const int m   = wid & 1;
    const int n   = wid >> 1;
    const int g   = l >> 4;
    const int l15 = l & 15;
    const int oc0 = blockIdx.x * 128;
    const int y0  = blockIdx.y * 2;
    const int b   = blockIdx.z;

    f32x4 accm[4][4], accc[4][4];
    #pragma unroll
    for (int i = 0; i < 4; ++i)
        #pragma unroll
        for (int j = 0; j < 4; ++j) {
            accm[i][j] = (f32x4){0.f, 0.f, 0.f, 0.f};
            accc[i][j] = (f32x4){0.f, 0.f, 0.f, 0.f};
        }

    auto stageA = [&](int icb) {
        for (int c = wid; c < 17; c += 4) {
            int s  = c * 64 + l;
            int px = s >> 2;
            int r  = px / 68;
            int xx = px - r * 68;
            const char* src = apad +
                ((size_t)((b * 66 + y0 + r) * 68 + xx) << 10) +
                (icb << 6) + ((s & 3) << 4);
            GLL16(src,          &sA[0][c * 512]);
            GLL16(src + APLANE, &sA[1][c * 512]);
        }
    };

    u32x4 breg[4];
    auto loadB = [&](int kk, int icb) {
        const char* bb = bw + ((size_t)(kk * 16 + icb) * 2048 + oc0 * 4) * 16;
        breg[0] = *(const u32x4*)(bb + (size_t)tid * 16);
        breg[1] = *(const u32x4*)(bb + (size_t)(tid + 256) * 16);
        breg[2] = *(const u32x4*)(bb + BPLANE + (size_t)tid * 16);
        breg[3] = *(const u32x4*)(bb + BPLANE + (size_t)(tid + 256) * 16);
    };
    auto writeB = [&]() {
        *(u32x4*)&sB[0][(size_t)tid * 8]         = breg[0];
        *(u32x4*)&sB[0][(size_t)(tid + 256) * 8] = breg[1];
        *(u32x4*)&sB[1][(size_t)tid * 8]         = breg[2];
        *(u32x4*)&sB[1][(size_t)(tid + 256) * 8] = breg[3];
    };

    stageA(0);
    loadB(0, 0);
    asm volatile("s_waitcnt vmcnt(0)" ::: "memory");
    writeB();
    __syncthreads();

    int kk = 0, icb = 0;
    for (int it = 0; it < 144; ++it) {
        int nkk = kk + 1, nicb = icb;
        if (nkk == 9) { nkk = 0; ++nicb; }
        const bool have_next = (it < 143);
        if (have_next) loadB(nkk, nicb);

        const int ky = kk / 3;
        const int kx = kk - 3 * ky;
        half8 bh[4], bl[4];
        #pragma unroll
        for (int jf = 0; jf < 4; ++jf) {
            int ocl  = n * 64 + 16 * jf + l15;
            int slot = (ocl << 2) | ((g + ocl) & 3);
            bh[jf] = *(const half8*)&sB[0][slot * 8];
            bl[jf] = *(const half8*)&sB[1][slot * 8];
        }
        const int r = m + ky;
        #pragma unroll
        for (int i = 0; i < 4; ++i) {
            int xx   = 16 * i + l15 + kx;
            int px   = r * 68 + xx;
            int slot = (px << 2) | ((g + px) & 3);
            half8 ah = *(const half8*)&sA[0][slot * 8];
            half8 al = *(const half8*)&sA[1][slot * 8];
            #pragma unroll
            for (int jf = 0; jf < 4; ++jf) {
                accm[i][jf] = __builtin_amdgcn_mfma_f32_16x16x32_f16(ah, bh[jf], accm[i][jf], 0, 0, 0);
                accc[i][jf] = __builtin_amdgcn_mfma_f32_16x16x32_f16(ah, bl[jf], accc[i][jf], 0, 0, 0);
                accc[i][jf] = __builtin_amdgcn_mfma_f32_16x16x32_f16(al, bh[jf], accc[i][jf], 0, 0, 0);
            }
        }
        __syncthreads();
        if (have_next) {
            writeB();
            if (nkk == 0) {
                stageA(nicb);
                asm volatile("s_waitcnt vmcnt(0)" ::: "memory");
            }
        }
        __syncthreads();
        kk = nkk; icb = nicb;
    }

    const float inv2048 = 4.8828125e-4f;
    #pragma unroll
    for (int i = 0; i < 4; ++i) {
        #pragma unroll
        for (int jf = 0; jf < 4; ++jf) {
            int oc = oc0 + n * 64 + 16 * jf + l15;
            int x  = 16 * i + (l >> 4) * 4;
            float bv = bias[oc];
            f32x4 vm = accm[i][jf], vc = accc[i][jf];
            f32x4 o;
            #pragma unroll
            for (int j = 0; j < 4; ++j) {
                float v = vm[j] + vc[j] * inv2048 + bv;
                o[j] = v > 0.f ? v : 0.f;
            }
            *(f32x4*)(out + (((size_t)(b * 512 + oc) << 12) +
                             ((y0 + m) << 6) + x)) = o;
        }
    }
}

// ---------------------------------------------------------------------------
// Head-weight prep + hist zero. Runs AFTER conv_mfma (r13/r15 lessons).
// ---------------------------------------------------------------------------
__global__ __launch_bounds__(256) void prep_hw(
    const float* __restrict__ cls_w, const float* __restrict__ bbox_w,
    const float* __restrict__ cls_b, const float* __restrict__ bbox_b,
    char* __restrict__ bhw, uint32_t* __restrict__ hist)
{
    int t = blockIdx.x * 256 + threadIdx.x;   // 0..8191
    int plane = t >> 12;
    int r  = t & 4095;
    int ks = r >> 8;
    int g  = (r >> 6) & 3;
    int oc = r & 63;
    int ic0 = ks * 32 + g * 8;

    half8 hv;
    #pragma unroll
    for (int e = 0; e < 8; ++e) {
        int ic = ic0 + e;
        float wf = 0.f;
        if (oc < 18)      wf = cls_w[oc * 512 + ic];
        else if (oc < 54) wf = bbox_w[(oc - 18) * 512 + ic];
        if (plane == 0) {
            hv[e] = (_Float16)wf;
        } else {
            _Float16 hi = (_Float16)wf;
            hv[e] = (_Float16)((wf - (float)hi) * 2048.0f);
        }
    }
    *(half8*)(bhw + (size_t)plane * 65536 +
              (size_t)(((ks * 4 + g) * 64 + oc)) * 16) = hv;

    if (blockIdx.x == 0 && threadIdx.x < 64) {
        int o = threadIdx.x;
        float bv = 0.f;
        if (o < 18)      bv = cls_b[o];
        else if (o < 54) bv = bbox_b[o - 18];
        *(float*)(bhw + 131072 + o * 4) = bv;
    }

    // hist: 524288 u32 = 8192 threads x 64.
    uint32_t* hz = hist + (size_t)t * 64;
    #pragma unroll
    for (int k = 0; k < 16; ++k)
        *(u32x4*)(hz + 4 * k) = (u32x4){0u, 0u, 0u, 0u};
}

// ---------------------------------------------------------------------------
// Fused heads: 1x1-conv GEMM (fp16x3 MFMA) -> LDS tile -> softmax/box decode
// + histogram, one kernel. Each wave computes 64px x 64oc; decode reads its
// pixel's 54 channels from LDS (pad 65 -> conflict-free).
// ---------------------------------------------------------------------------
__global__ __launch_bounds__(256) void heads_fused(
    const float* __restrict__ h, const char* __restrict__ bhw,
    const float* __restrict__ im_info, float* __restrict__ scores,
    float* __restrict__ boxes, uint32_t* __restrict__ hist)
{
    __shared__ float sdec[4][64][65];

    const int tid = threadIdx.x;
    const int l   = tid & 63;
    const int w   = tid >> 6;
    const int g   = l >> 4;
    const int l15 = l & 15;
    const int b   = blockIdx.y;
    const int px0 = blockIdx.x * 256 + w * 64;

    f32x4 accm[4][4], accc[4][4];
    #pragma unroll
    for (int i = 0; i < 4; ++i)
        #pragma unroll
        for (int j = 0; j < 4; ++j) {
            accm[i][j] = (f32x4){0.f, 0.f, 0.f, 0.f};
            accc[i][j] = (f32x4){0.f, 0.f, 0.f, 0.f};
        }

    const float* hb = h + (((size_t)(b * 512 + g * 8)) << 12) + px0 + l15;
    const float* bias64 = (const float*)(bhw + 131072);

    #pragma unroll 2
    for (int ks = 0; ks < 16; ++ks) {
        half8 bh[4], bl[4];
        #pragma unroll
        for (int jf = 0; jf < 4; ++jf) {
            size_t slot = (size_t)(((ks * 4 + g) * 64 + 16 * jf + l15)) * 16;
            bh[jf] = *(const half8*)(bhw + slot);
            bl[jf] = *(const half8*)(bhw + 65536 + slot);
        }
        #pragma unroll
        for (int i = 0; i < 4; ++i) {
            float af[8];
            #pragma unroll
            for (int e = 0; e < 8; ++e)
                af[e] = hb[(((size_t)(ks * 32 + e)) << 12) + i * 16];
            half8 ah, al;
            #pragma unroll
            for (int e = 0; e < 8; ++e) {
                _Float16 hi = (_Float16)af[e];
                ah[e] = hi;
                al[e] = (_Float16)((af[e] - (float)hi) * 2048.0f);
            }
            #pragma unroll
            for (int jf = 0; jf < 4; ++jf) {
                accm[i][jf] = __builtin_amdgcn_mfma_f32_16x16x32_f16(ah, bh[jf], accm[i][jf], 0, 0, 0);
                accc[i][jf] = __builtin_amdgcn_mfma_f32_16x16x32_f16(ah, bl[jf], accc[i][jf], 0, 0, 0);
                accc[i][jf] = __builtin_amdgcn_mfma_f32_16x16x32_f16(al, bh[jf], accc[i][jf], 0, 0, 0);
            }
        }
    }

    const float inv2048 = 4.8828125e-4f;
    float bv[4];
    #pragma unroll
    for (int jf = 0; jf < 4; ++jf) bv[jf] = bias64[16 * jf + l15];

    #pragma unroll
    for (int i = 0; i < 4; ++i) {
        #pragma unroll
        for (int jf = 0; jf < 4; ++jf) {
            int oc = 16 * jf + l15;
            #pragma unroll
            for (int j = 0; j < 4; ++j) {
                int pl = i * 16 + g * 4 + j;
                sdec[w][pl][oc] =
                    accm[i][jf][j] + accc[i][jf][j] * inv2048 + bv[jf];
            }
        }
    }
    __syncthreads();

    // ---- decode: thread tid handles pixel blockIdx.x*256 + tid ----
    const int w2  = tid >> 6;
    const int pl2 = tid & 63;
    const int s = blockIdx.x * 256 + tid;

    float acc[54];
    #pragma unroll
    for (int o = 0; o < 54; ++o) acc[o] = sdec[w2][pl2][o];

    const float info0 = im_info[b * 3 + 0];
    const float info1 = im_info[b * 3 + 1];
    const float info2 = im_info[b * 3 + 2];
    const float maxx = info1 - 1.0f, maxy = info0 - 1.0f;
    const float min_size = 16.0f * info2;
    const int y = s >> 6, x = s & 63;
    const float cxa = 16.f * (float)x + 8.f;
    const float cya = 16.f * (float)y + 8.f;
    const float WA[9] = {184.f, 368.f, 736.f, 128.f, 256.f, 512.f,  88.f, 176.f, 352.f};
    const float HA[9] = { 96.f, 192.f, 384.f, 128.f, 256.f, 512.f, 176.f, 352.f, 704.f};

    uint32_t* hbm = hist + ((size_t)b << 16);
    const int base = b * 36864 + s * 9;
    #pragma unroll
    for (int a = 0; a < 9; ++a) {
        float c0v = acc[a], c1v = acc[9 + a];
        float mm = fmaxf(c0v, c1v);
        float e0 = expf(c0v - mm), e1 = expf(c1v - mm);
        float fg = e1 / (e0 + e1);
        float dx = acc[18 + 4 * a + 0];
        float dy = acc[18 + 4 * a + 1];
        float dw = acc[18 + 4 * a + 2];
        float dh = acc[18 + 4 * a + 3];
        float cx = dx * WA[a] + cxa;
        float cy = dy * HA[a] + cya;
        float pw = expf(dw) * WA[a];
        float ph = expf(dh) * HA[a];
        float x1 = fminf(fmaxf(cx - 0.5f * pw, 0.f), maxx);
        float y1 = fminf(fmaxf(cy - 0.5f * ph, 0.f), maxy);
        float x2 = fminf(fmaxf(cx + 0.5f * pw, 0.f), maxx);
        float y2 = fminf(fmaxf(cy + 0.5f * ph, 0.f), maxy);
        bool keep = ((x2 - x1 + 1.f) >= min_size) && ((y2 - y1 + 1.f) >= min_size);
        float sc = keep ? fg : NEG_INF_F;
        scores[base + a] = sc;
        atomicAdd(&hbm[(~ordf(sc)) >> 16], 1u);
        float* bp = boxes + (size_t)(base + a) * 4;
        bp[0] = x1; bp[1] = y1; bp[2] = x2; bp[3] = y2;
    }
}

// ---------------------------------------------------------------------------
// Fallback f32 conv + fused heads (used only if ws too small for MFMA path).
// ---------------------------------------------------------------------------
__global__ __launch_bounds__(256) void conv3_relu(
    const float* __restrict__ in, const float* __restrict__ w,
    const float* __restrict__ bias, float* __restrict__ out)
{
    const int oc0 = blockIdx.x * 32;
    const int y0  = blockIdx.y * 4;
    const int b   = blockIdx.z;
    const int tid = threadIdx.x;
    const int xg  = tid & 31;
    const int og  = tid >> 5;

    __shared__ float s_in[8][6][68];
    __shared__ float s_w[32][8][9];

    float acc[4][4][2];
    #pragma unroll
    for (int o = 0; o < 4; ++o)
        #pragma unroll
        for (int yy = 0; yy < 4; ++yy) { acc[o][yy][0] = 0.f; acc[o][yy][1] = 0.f; }

    for (int ic0 = 0; ic0 < 512; ic0 += 8) {
        for (int e = tid; e < 8 * 6 * 66; e += 256) {
            int ic = e / 396; int r = e - ic * 396;
            int yy = r / 66;  int xx = r - yy * 66;
            int gy = y0 + yy - 1;
            int gx = xx - 1;
            float v = 0.f;
            if (gy >= 0 && gy < 64 && gx >= 0 && gx < 64)
                v = in[(((b * 512 + ic0 + ic) * 64 + gy) << 6) + gx];
            s_in[ic][yy][xx] = v;
        }
        {
            int oc = tid >> 3, ic = tid & 7;
            const float* wp = w + ((size_t)(oc0 + oc) * 512 + ic0 + ic) * 9;
            #pragma unroll
            for (int k = 0; k < 9; ++k) s_w[oc][ic][k] = wp[k];
        }
        __syncthreads();
        for (int ic = 0; ic < 8; ++ic) {
            #pragma unroll
            for (int ky = 0; ky < 3; ++ky) {
                #pragma unroll
                for (int kx = 0; kx < 3; ++kx) {
                    const int k = ky * 3 + kx;
                    float w0 = s_w[og][ic][k];
                    float w1 = s_w[og + 8][ic][k];
                    float w2 = s_w[og + 16][ic][k];
                    float w3 = s_w[og + 24][ic][k];
                    #pragma unroll
                    for (int yy = 0; yy < 4; ++yy) {
                        float i0 = s_in[ic][yy + ky][xg + kx];
                        float i1 = s_in[ic][yy + ky][xg + 32 + kx];
                        acc[0][yy][0] = fmaf(w0, i0, acc[0][yy][0]);
                        acc[0][yy][1] = fmaf(w0, i1, acc[0][yy][1]);
                        acc[1][yy][0] = fmaf(w1, i0, acc[1][yy][0]);
                        acc[1][yy][1] = fmaf(w1, i1, acc[1][yy][1]);
                        acc[2][yy][0] = fmaf(w2, i0, acc[2][yy][0]);
                        acc[2][yy][1] = fmaf(w2, i1, acc[2][yy][1]);
                        acc[3][yy][0] = fmaf(w3, i0, acc[3][yy][0]);
                        acc[3][yy][1] = fmaf(w3, i1, acc[3][yy][1]);
                    }
                }
            }
        }
        __syncthreads();
    }

    #pragma unroll
    for (int o = 0; o < 4; ++o) {
        int oc = oc0 + og + 8 * o;
        float bv = bias[oc];
        #pragma unroll
        for (int yy = 0; yy < 4; ++yy) {
            int y = y0 + yy;
            float* op = out + (((b * 512 + oc) * 64 + y) << 6);
            float v0 = acc[o][yy][0] + bv; v0 = v0 > 0.f ? v0 : 0.f;
            float v1 = acc[o][yy][1] + bv; v1 = v1 > 0.f ? v1 : 0.f;
            op[xg] = v0; op[xg + 32] = v1;
        }
    }
}

__global__ __launch_bounds__(256) void heads(
    const float* __restrict__ h, const float* __restrict__ cls_w,
    const float* __restrict__ cls_b, const float* __restrict__ bbox_w,
    const float* __restrict__ bbox_b, const float* __restrict__ im_info,
    float* __restrict__ scores, float* __restrict__ boxes,
    uint32_t* __restrict__ hist)
{
    const int tid = threadIdx.x;
    const int b = blockIdx.x >> 4;
    const int s = ((blockIdx.x & 15) << 8) + tid;

    __shared__ float s_w[54][64];

    float acc[54];
    #pragma unroll
    for (int o = 0; o < 54; ++o) acc[o] = 0.f;

    for (int c0 = 0; c0 < 512; c0 += 64) {
        __syncthreads();
        for (int e = tid; e < 54 * 64; e += 256) {
            int oc = e >> 6, i = e & 63;
            float v = (oc < 18) ? cls_w[oc * 512 + c0 + i]
                                : bbox_w[(oc - 18) * 512 + c0 + i];
            s_w[oc][i] = v;
        }
        __syncthreads();
        for (int i = 0; i < 64; ++i) {
            float hv = h[((b * 512 + c0 + i) << 12) + s];
            #pragma unroll
            for (int o = 0; o < 54; ++o) acc[o] = fmaf(hv, s_w[o][i], acc[o]);
        }
    }
    #pragma unroll
    for (int o = 0; o < 18; ++o) acc[o] += cls_b[o];
    #pragma unroll
    for (int o = 0; o < 36; ++o) acc[18 + o] += bbox_b[o];

    const float info0 = im_info[b * 3 + 0];
    const float info1 = im_info[b * 3 + 1];
    const float info2 = im_info[b * 3 + 2];
    const float maxx = info1 - 1.0f, maxy = info0 - 1.0f;
    const float min_size = 16.0f * info2;
    const int y = s >> 6, x = s & 63;
    const float cxa = 16.f * (float)x + 8.f;
    const float cya = 16.f * (float)y + 8.f;
    const float WA[9] = {184.f, 368.f, 736.f, 128.f, 256.f, 512.f,  88.f, 176.f, 352.f};
    const float HA[9] = { 96.f, 192.f, 384.f, 128.f, 256.f, 512.f, 176.f, 352.f, 704.f};

    uint32_t* hb = hist + ((size_t)b << 16);
    const int base = b * 36864 + s * 9;
    #pragma unroll
    for (int a = 0; a < 9; ++a) {
        float c0v = acc[a], c1v = acc[9 + a];
        float mm = fmaxf(c0v, c1v);
        float e0 = expf(c0v - mm), e1 = expf(c1v - mm);
        float fg = e1 / (e0 + e1);
        float dx = acc[18 + 4 * a + 0];
        float dy = acc[18 + 4 * a + 1];
        float dw = acc[18 + 4 * a + 2];
        float dh = acc[18 + 4 * a + 3];
        float cx = dx * WA[a] + cxa;
        float cy = dy * HA[a] + cya;
        float pw = expf(dw) * WA[a];
        float ph = expf(dh) * HA[a];
        float x1 = fminf(fmaxf(cx - 0.5f * pw, 0.f), maxx);
        float y1 = fminf(fmaxf(cy - 0.5f * ph, 0.f), maxy);
        float x2 = fminf(fmaxf(cx + 0.5f * pw, 0.f), maxx);
        float y2 = fminf(fmaxf(cy + 0.5f * ph, 0.f), maxy);
        bool keep = ((x2 - x1 + 1.f) >= min_size) && ((y2 - y1 + 1.f) >= min_size);
        float sc = keep ? fg : NEG_INF_F;
        scores[base + a] = sc;
        atomicAdd(&hb[(~ordf(sc)) >> 16], 1u);
        float* bp = boxes + (size_t)(base + a) * 4;
        bp[0] = x1; bp[1] = y1; bp[2] = x2; bp[3] = y2;
    }
}

// ---------------------------------------------------------------------------
// select_k: per-batch fused top-2000 select (round-17 proven).
// ---------------------------------------------------------------------------
__global__ __launch_bounds__(1024) void select_k(
    const uint32_t* __restrict__ hist, const float* __restrict__ scores,
    const float* __restrict__ boxes, float* __restrict__ ts,
    float* __restrict__ tb)
{
    const int b = blockIdx.x;
    const int t = threadIdx.x;
    __shared__ uint64_t s[4096];       // candidate keys (32 KB)
    __shared__ uint32_t part[1024];
    __shared__ uint32_t thr;
    __shared__ uint32_t sel[2];        // [0]=definite count, [1]=boundary count

    const uint32_t* hb = hist + ((size_t)b << 16);

    uint32_t own = 0;
    #pragma unroll 4
    for (int k = 0; k < 64; ++k) own += hb[t * 64 + k];
    part[t] = own;
    for (int i = t; i < 4096; i += 1024) s[i] = ~0ull;
    if (t < 2) sel[t] = 0u;
    __syncthreads();
    for (int off = 1; off < 1024; off <<= 1) {
        uint32_t v = (t >= off) ? part[t - off] : 0u;
        __syncthreads();
        part[t] += v;
        __syncthreads();
    }
    uint32_t incl = part[t];
    uint32_t excl = incl - own;
    if (excl < 2000u && incl >= 2000u) {
        uint32_t c = excl;
        for (int k = 0; k < 64; ++k) {
            uint32_t hh = hb[t * 64 + k];
            if (c + hh >= 2000u) { thr = t * 64 + k; break; }
            c += hh;
        }
    }
    __syncthreads();
    const uint32_t T = thr;

    for (int i = t; i < 36864; i += 1024) {
        float sc = scores[b * 36864 + i];
        uint32_t kh = ~ordf(sc);
        uint32_t bin = kh >> 16;
        uint64_t key = ((uint64_t)kh << 32) | (uint32_t)i;
        if (bin < T) {
            uint32_t p = atomicAdd(&sel[0], 1u);
            s[p] = key;
        } else if (bin == T) {
            uint32_t p = atomicAdd(&sel[1], 1u);
            if (p < 2048u) s[4095 - p] = key;
        }
    }
    __syncthreads();

    for (int k = 2; k <= 4096; k <<= 1) {
        for (int j = k >> 1; j > 0; j >>= 1) {
            for (int t2 = t; t2 < 2048; t2 += 1024) {
                int i = ((t2 & ~(j - 1)) << 1) | (t2 & (j - 1));
                int ixj = i + j;
                bool up = ((i & k) == 0);
                uint64_t a = s[i], c = s[ixj];
                if ((a > c) == up) { s[i] = c; s[ixj] = a; }
            }
            __syncthreads();
        }
    }

    for (int r = t; r < 2000; r += 1024) {
        uint64_t k = s[r];
        int idx = (int)(uint32_t)k;
        ts[b * 2048 + r] = scores[b * 36864 + idx];
        const float* sp = boxes + ((size_t)b * 36864 + idx) * 4;
        float* dp = tb + ((size_t)b * 2048 + r) * 4;
        dp[0] = sp[0]; dp[1] = sp[1]; dp[2] = sp[2]; dp[3] = sp[3];
    }
}

// ---------------------------------------------------------------------------
// NMS: IoU bitmask build, UPPER TRIANGLE only (cb >= rb).
// ---------------------------------------------------------------------------
__global__ __launch_bounds__(64) void nms_mask(const float* __restrict__ tb,
                                               uint64_t* __restrict__ mask)
{
    const int b  = blockIdx.z;
    const int rb = blockIdx.y;
    const int cb = blockIdx.x;
    if (cb < rb) return;
    const int t  = threadIdx.x;
    __shared__ float cbox[64][4];
    const int col0 = cb * 64;
    {
        int c = col0 + t;
        if (c < 2000) {
            const float* p = tb + ((size_t)b * 2048 + c) * 4;
            cbox[t][0] = p[0]; cbox[t][1] = p[1]; cbox[t][2] = p[2]; cbox[t][3] = p[3];
        } else {
            cbox[t][0] = 0.f; cbox[t][1] = 0.f; cbox[t][2] = -1.f; cbox[t][3] = -1.f;
        }
    }
    __syncthreads();
    int row = rb * 64 + t;
    if (row >= 2000) return;
    const float* p = tb + ((size_t)b * 2048 + row) * 4;
    float x1 = p[0], y1 = p[1], x2 = p[2], y2 = p[3];
    float area = (x2 - x1 + 1.f) * (y2 - y1 + 1.f);
    uint64_t bits = 0;
    int ncol = 2000 - col0; if (ncol > 64) ncol = 64;
    for (int j = 0; j < ncol; ++j) {
        float xx1 = fmaxf(x1, cbox[j][0]);
        float yy1 = fmaxf(y1, cbox[j][1]);
        float xx2 = fminf(x2, cbox[j][2]);
        float yy2 = fminf(y2, cbox[j][3]);
        float iw = fmaxf(xx2 - xx1 + 1.f, 0.f);
        float ih = fmaxf(yy2 - yy1 + 1.f, 0.f);
        float inter = iw * ih;
        float areaj = (cbox[j][2] - cbox[j][0] + 1.f) * (cbox[j][3] - cbox[j][1] + 1.f);
        float iou = inter / (area + areaj - inter);
        if (iou > 0.7f) bits |= (1ull << j);
    }
    mask[((size_t)b * 2048 + row) * 32 + cb] = bits;
}

// ---------------------------------------------------------------------------
// Fused NMS scan + final sort + roi emit (round-12 proven).
// ---------------------------------------------------------------------------
__global__ __launch_bounds__(1024) void nms_final(
    const uint64_t* __restrict__ mask, const float* __restrict__ ts,
    const float* __restrict__ tb, float* __restrict__ out)
{
    const int b = blockIdx.x;
    const int tid = threadIdx.x;
    __shared__ uint64_t kw[32];        // keep bits, one u64 per 64 rows
    __shared__ uint64_t s[2048];

    if (tid < 64) {
        const int lane = tid;
        const uint64_t* mrow = mask + (size_t)b * 2048 * 32;
        const bool ml = (lane < 32);
        uint64_t remv = 0;
        uint32_t cur_lo = 0, cur_hi = 0;
        uint64_t kcur = 0;

        uint64_t bufA[16], bufB[16];

#define LOADG(buf, gidx) do { int base_ = (gidx) * 16;                        \
    _Pragma("unroll")                                                         \
    for (int k_ = 0; k_ < 16; ++k_) {                                         \
        int r_ = base_ + k_;                                                  \
        buf[k_] = (ml && r_ < 2000) ? mrow[(size_t)r_ * 32 + lane] : 0ull;    \
    } } while (0)

#define PROCG(buf, gidx) do { int base_ = (gidx) * 16;                        \
    _Pragma("unroll")                                                         \
    for (int k_ = 0; k_ < 16; ++k_) {                                         \
        int i_ = base_ + k_;                                                  \
        int w_ = i_ >> 6;                                                     \
        int bit_ = i_ & 63;                                                   \
        if (bit_ == 0) {                                                      \
            cur_lo = __builtin_amdgcn_readlane((uint32_t)remv, w_);           \
            cur_hi = __builtin_amdgcn_readlane((uint32_t)(remv >> 32), w_);   \
            kcur = 0;                                                         \
        }                                                                     \
        uint32_t sw_ = (bit_ < 32) ? cur_lo : cur_hi;                         \
        if (!((sw_ >> (bit_ & 31)) & 1u)) {                                   \
            kcur |= (1ull << bit_);                                           \
            if (ml) remv |= buf[k_];                                          \
            cur_lo |= __builtin_amdgcn_readlane((uint32_t)buf[k_], w_);       \
            cur_hi |= __builtin_amdgcn_readlane((uint32_t)(buf[k_] >> 32), w_);\
        }                                                                     \
        if (bit_ == 63 || i_ == 1999) { if (lane == 0) kw[w_] = kcur; }       \
    } } while (0)

        LOADG(bufA, 0);
        LOADG(bufB, 1);
        for (int gq = 0; gq < 125; gq += 2) {      // 125 groups of 16 = 2000
            PROCG(bufA, gq);
            LOADG(bufA, gq + 2);
            if (gq + 1 < 125) {
                PROCG(bufB, gq + 1);
                LOADG(bufB, gq + 3);
            }
        }
#undef LOADG
#undef PROCG
    }
    __syncthreads();                               // kw visible to all waves

    for (int i = tid; i < 2048; i += 1024) {
        uint64_t k;
        if (i < 2000) {
            bool kp = (kw[i >> 6] >> (i & 63)) & 1ull;
            float sc = kp ? ts[b * 2048 + i] : NEG_INF_F;
            k = ((uint64_t)(~ordf(sc)) << 32) | (uint32_t)i;
        } else {
            k = ~0ull;
        }
        s[i] = k;
    }
    __syncthreads();

    for (int k = 2; k <= 2048; k <<= 1) {
        for (int j = k >> 1; j > 0; j >>= 1) {
            for (int t = tid; t < 2048; t += 1024) {
                int ixj = t ^ j;
                if (ixj > t) {
                    bool up = ((t & k) == 0);
                    uint64_t a = s[t], c = s[ixj];
                    if ((a > c) == up) { s[t] = c; s[ixj] = a; }
                }
            }
            __syncthreads();
        }
    }
    for (int r = tid; r < 300; r += 1024) {
        int idx = (int)(uint32_t)s[r];
        const float* bp = tb + ((size_t)b * 2048 + idx) * 4;
        float* op = out + (size_t)(b * 300 + r) * 5;
        op[0] = (float)b;
        op[1] = bp[0]; op[2] = bp[1]; op[3] = bp[2]; op[4] = bp[3];
    }
}

// ---------------------------------------------------------------------------
extern "C" void kernel_launch(void* const* d_in, const int* in_sizes, int n_in,
                              void* d_out, int out_size, void* d_ws, size_t ws_size,
                              hipStream_t stream)
{
    const float* im_data = (const float*)d_in[0];
    const float* im_info = (const float*)d_in[1];
    const float* conv_w  = (const float*)d_in[2];
    const float* conv_b  = (const float*)d_in[3];
    const float* cls_w   = (const float*)d_in[4];
    const float* cls_b   = (const float*)d_in[5];
    const float* bbox_w  = (const float*)d_in[6];
    const float* bbox_b  = (const float*)d_in[7];
    float* out = (float*)d_out;

    char* ws = (char*)d_ws;
    float*    h      = (float*)(ws);                      // 67,108,864
    float*    scores = (float*)(ws + 67108864ull);        // 1,179,648
    float*    boxes  = (float*)(ws + 68288512ull);        // 4,718,592
    uint32_t* hist   = (uint32_t*)(ws + 73007104ull);     // 2,097,152
    float*    ts     = (float*)(ws + 75367424ull);        // 65,536
    float*    tb     = (float*)(ws + 75432960ull);        // 262,144
    uint64_t* mask   = (uint64_t*)(ws + 75695104ull);     // 4,194,304
    char*     bhw    = ws + 88409088ull;                  // 131,328   (dead-apad zone)

    char* apad = ws + 67108864ull;                        // 73,531,392 (conv phase only)
    char* bwp  = ws + 140640256ull;                       // 9,437,184
    const size_t NEED_FULL = 150077440ull;

    if (ws_size >= NEED_FULL) {
        prep_init<<<dim3(4384), 256, 0, stream>>>(conv_w, im_data, apad, bwp);
        conv_mfma<<<dim3(4, 32, 8), 256, 0, stream>>>(apad, bwp, conv_b, h);
        // apad dead from here; hist/bhw live in its footprint --
        // ALL of their initialization must come after conv_mfma (r13/r15).
        prep_hw<<<dim3(32), 256, 0, stream>>>(cls_w, bbox_w, cls_b, bbox_b,
                                              bhw, hist);
        heads_fused<<<dim3(16, 8), 256, 0, stream>>>(h, bhw, im_info,
                                                     scores, boxes, hist);
    } else {
        hipMemsetAsync(hist, 0, 2097152ull, stream);
        conv3_relu<<<dim3(16, 16, 8), 256, 0, stream>>>(im_data, conv_w, conv_b, h);
        heads<<<dim3(128), 256, 0, stream>>>(h, cls_w, cls_b, bbox_w, bbox_b, im_info,
                                             scores, boxes, hist);
    }

    select_k<<<dim3(8), 1024, 0, stream>>>(hist, scores, boxes, ts, tb);
    nms_mask<<<dim3(32, 32, 8), 64, 0, stream>>>(tb, mask);
    nms_final<<<dim3(8), 1024, 0, stream>>>(mask, ts, tb, out);
}

// Round 19
// 724.631 us; speedup vs baseline: 1.4194x; 1.0210x over previous
//
#include <hip/hip_runtime.h>
#include <stdint.h>

#define NEG_INF_F (-1e30f)

typedef _Float16 half8 __attribute__((ext_vector_type(8)));
typedef float f32x4 __attribute__((ext_vector_type(4)));
typedef uint32_t u32x4 __attribute__((ext_vector_type(4)));

__device__ __forceinline__ uint32_t ordf(float f) {
    uint32_t u = __float_as_uint(f);
    return u ^ ((u >> 31) ? 0xFFFFFFFFu : 0x80000000u);
}

#define GLL16(g, l) __builtin_amdgcn_global_load_lds( \
    (const __attribute__((address_space(1))) void*)(g), \
    (__attribute__((address_space(3))) void*)(l), 16, 0, 0)

// Apad: [split][b][yy 0..65][xx 0..67][icb 16][rot 4][8 fp16]  (pixel = 1024 B)
// Bw:   [split][kk 9][icb 16][oc 512][rot 4][8 fp16]; rot = (g + oc) & 3.
#define APLANE 36765696ull
#define BPLANE 4718592ull

// ---------------------------------------------------------------------------
// prep_init: merged halo-zero (blocks 0..1567) + conv weight prep
// (blocks 1568..3871) + input prep (blocks 3872..4383).
// ---------------------------------------------------------------------------
__global__ __launch_bounds__(256) void prep_init(const float* __restrict__ w,
                                                 const float* __restrict__ in,
                                                 char* __restrict__ apad,
                                                 char* __restrict__ bw)
{
    __shared__ float s_tile[64][65];

    if (blockIdx.x < 1568) {
        int t = blockIdx.x * 256 + threadIdx.x;     // 0 .. 401407
        int chunk = t & 63;
        int r  = t >> 6;                            // 0 .. 6271
        int p  = r % 392;
        int bs = r / 392;                           // b*2 + split
        int split = bs & 1;
        int b     = bs >> 1;
        int yy, xx;
        if (p < 68)       { yy = 0;  xx = p; }
        else if (p < 136) { yy = 65; xx = p - 68; }
        else {
            int q = p - 136;
            yy = 1 + (q >> 2);
            int s2 = q & 3;
            xx = (s2 == 0) ? 0 : 64 + s2;
        }
        *(f32x4*)(apad + (size_t)split * APLANE +
                  ((size_t)((b * 66 + yy) * 68 + xx) << 10) + chunk * 16) =
            (f32x4){0.f, 0.f, 0.f, 0.f};
    } else if (blockIdx.x < 3872) {
        int t = (blockIdx.x - 1568) * 256 + threadIdx.x;  // 0 .. 589823
        int split = t / 294912;
        int r  = t % 294912;
        int kk = r >> 15;
        int r2 = r & 32767;
        int icb = r2 >> 11;
        int r3  = r2 & 2047;
        int oc  = r3 >> 2;
        int rot = r3 & 3;
        int g   = (rot - oc) & 3;
        int ic0 = icb * 32 + g * 8;

        half8 hv;
        #pragma unroll
        for (int e = 0; e < 8; ++e) {
            float wf = w[(size_t)(oc * 512 + ic0 + e) * 9 + kk];
            if (split == 0) {
                hv[e] = (_Float16)wf;
            } else {
                _Float16 hi = (_Float16)wf;
                hv[e] = (_Float16)((wf - (float)hi) * 2048.0f);
            }
        }
        *(half8*)(bw + (size_t)split * BPLANE +
                  ((size_t)(kk * 16 + icb) * 2048 + r3) * 16) = hv;
    } else {
        const int idx = blockIdx.x - 3872;          // 0..511
        const int y = idx & 63;
        const int b = idx >> 6;
        const int t = threadIdx.x;

        for (int c = 0; c < 8; ++c) {
            __syncthreads();
            #pragma unroll
            for (int rep = 0; rep < 16; ++rep) {
                int ic_l = rep * 4 + (t >> 6);
                int x    = t & 63;
                s_tile[ic_l][x] =
                    in[(((size_t)(b * 512 + c * 64 + ic_l) * 64 + y) << 6) + x];
            }
            __syncthreads();
            #pragma unroll
            for (int q = 0; q < 4; ++q) {
                int s     = q * 256 + t;           // 0..1023
                int split = s >> 9;
                int rem   = s & 511;
                int x     = rem >> 3;
                int icb_l = (rem >> 2) & 1;
                int rot   = rem & 3;
                int xx    = x + 1;
                int g     = (rot - xx) & 3;
                int ic_l0 = icb_l * 32 + g * 8;
                half8 hv;
                #pragma unroll
                for (int e = 0; e < 8; ++e) {
                    float v = s_tile[ic_l0 + e][x];
                    if (split == 0) {
                        hv[e] = (_Float16)v;
                    } else {
                        _Float16 hi = (_Float16)v;
                        hv[e] = (_Float16)((v - (float)hi) * 2048.0f);
                    }
                }
                *(half8*)(apad + (size_t)split * APLANE +
                          ((size_t)((b * 66 + y + 1) * 68 + xx) << 10) +
                          ((c * 2 + icb_l) << 6) + (rot << 4)) = hv;
            }
        }
    }
}

// ---------------------------------------------------------------------------
// MFMA conv: implicit GEMM, fp16 x3 split precision. Round-8 structure with
// ONE change: sB is double-buffered (+8 KB LDS, still 2 blocks/CU), so the
// barrier between compute and writeB is gone -- 1 barrier per kk-step
// (2 only at icb boundaries where sA is overwritten). 288 -> 164 barriers.
// ---------------------------------------------------------------------------
__global__ __launch_bounds__(256, 2) void conv_mfma(
    const char* __restrict__ apad, const char* __restrict__ bw,
    const float* __restrict__ bias, float* __restrict__ out)
{
    __shared__ _Float16 sA[2][8704];
    __shared__ _Float16 sB[2][2][4096];   // [buf][split][slot*8]

    const int tid = threadIdx.x;
    const int l   = tid & 63;
    const int wid = tid >> 6;
    const int m   = wid & 1;
    const int n   = wid >> 1;
    const int g   = l >> 4;
    const int l15 = l & 15;
    const int oc0 = blockIdx.x * 128;
    const int y0  = blockIdx.y * 2;
    const int b   = blockIdx.z;

    f32x4 accm[4][4], accc[4][4];
    #pragma unroll
    for (int i = 0; i < 4; ++i)
        #pragma unroll
        for (int j = 0; j < 4; ++j) {
            accm[i][j] = (f32x4){0.f, 0.f, 0.f, 0.f};
            accc[i][j] = (f32x4){0.f, 0.f, 0.f, 0.f};
        }

    auto stageA = [&](int icb) {
        for (int c = wid; c < 17; c += 4) {
            int s  = c * 64 + l;
            int px = s >> 2;
            int r  = px / 68;
            int xx = px - r * 68;
            const char* src = apad +
                ((size_t)((b * 66 + y0 + r) * 68 + xx) << 10) +
                (icb << 6) + ((s & 3) << 4);
            GLL16(src,          &sA[0][c * 512]);
            GLL16(src + APLANE, &sA[1][c * 512]);
        }
    };

    u32x4 breg[4];
    auto loadB = [&](int kk, int icb) {
        const char* bb = bw + ((size_t)(kk * 16 + icb) * 2048 + oc0 * 4) * 16;
        breg[0] = *(const u32x4*)(bb + (size_t)tid * 16);
        breg[1] = *(const u32x4*)(bb + (size_t)(tid + 256) * 16);
        breg[2] = *(const u32x4*)(bb + BPLANE + (size_t)tid * 16);
        breg[3] = *(const u32x4*)(bb + BPLANE + (size_t)(tid + 256) * 16);
    };
    auto writeB = [&](int nb) {
        *(u32x4*)&sB[nb][0][(size_t)tid * 8]         = breg[0];
        *(u32x4*)&sB[nb][0][(size_t)(tid + 256) * 8] = breg[1];
        *(u32x4*)&sB[nb][1][(size_t)tid * 8]         = breg[2];
        *(u32x4*)&sB[nb][1][(size_t)(tid + 256) * 8] = breg[3];
    };

    stageA(0);
    loadB(0, 0);
    asm volatile("s_waitcnt vmcnt(0)" ::: "memory");
    writeB(0);
    __syncthreads();

    int kk = 0, icb = 0, buf = 0;
    for (int it = 0; it < 144; ++it) {
        int nkk = kk + 1, nicb = icb;
        if (nkk == 9) { nkk = 0; ++nicb; }
        const bool have_next = (it < 143);
        if (have_next) loadB(nkk, nicb);

        const int ky = kk / 3;
        const int kx = kk - 3 * ky;
        half8 bh[4], bl[4];
        #pragma unroll
        for (int jf = 0; jf < 4; ++jf) {
            int ocl  = n * 64 + 16 * jf + l15;
            int slot = (ocl << 2) | ((g + ocl) & 3);
            bh[jf] = *(const half8*)&sB[buf][0][slot * 8];
            bl[jf] = *(const half8*)&sB[buf][1][slot * 8];
        }
        const int r = m + ky;
        #pragma unroll
        for (int i = 0; i < 4; ++i) {
            int xx   = 16 * i + l15 + kx;
            int px   = r * 68 + xx;
            int slot = (px << 2) | ((g + px) & 3);
            half8 ah = *(const half8*)&sA[0][slot * 8];
            half8 al = *(const half8*)&sA[1][slot * 8];
            #pragma unroll
            for (int jf = 0; jf < 4; ++jf) {
                accm[i][jf] = __builtin_amdgcn_mfma_f32_16x16x32_f16(ah, bh[jf], accm[i][jf], 0, 0, 0);
                accc[i][jf] = __builtin_amdgcn_mfma_f32_16x16x32_f16(ah, bl[jf], accc[i][jf], 0, 0, 0);
                accc[i][jf] = __builtin_amdgcn_mfma_f32_16x16x32_f16(al, bh[jf], accc[i][jf], 0, 0, 0);
            }
        }

        if (have_next) {
            writeB(buf ^ 1);           // other buffer: no barrier needed first
            if (nkk == 0) {
                __syncthreads();       // all waves done reading sA
                stageA(nicb);          // overwrite sA for next icb
                asm volatile("s_waitcnt vmcnt(0)" ::: "memory");
            }
        }
        __syncthreads();               // publish writeB (+sA at boundaries)
        buf ^= 1; kk = nkk; icb = nicb;
    }

    const float inv2048 = 4.8828125e-4f;
    #pragma unroll
    for (int i = 0; i < 4; ++i) {
        #pragma unroll
        for (int jf = 0; jf < 4; ++jf) {
            int oc = oc0 + n * 64 + 16 * jf + l15;
            int x  = 16 * i + (l >> 4) * 4;
            float bv = bias[oc];
            f32x4 vm = accm[i][jf], vc = accc[i][jf];
            f32x4 o;
            #pragma unroll
            for (int j = 0; j < 4; ++j) {
                float v = vm[j] + vc[j] * inv2048 + bv;
                o[j] = v > 0.f ? v : 0.f;
            }
            *(f32x4*)(out + (((size_t)(b * 512 + oc) << 12) +
                             ((y0 + m) << 6) + x)) = o;
        }
    }
}

// ---------------------------------------------------------------------------
// Head-weight prep + hist zero. Runs AFTER conv_mfma (r13/r15 lessons).
// ---------------------------------------------------------------------------
__global__ __launch_bounds__(256) void prep_hw(
    const float* __restrict__ cls_w, const float* __restrict__ bbox_w,
    const float* __restrict__ cls_b, const float* __restrict__ bbox_b,
    char* __restrict__ bhw, uint32_t* __restrict__ hist)
{
    int t = blockIdx.x * 256 + threadIdx.x;   // 0..8191
    int plane = t >> 12;
    int r  = t & 4095;
    int ks = r >> 8;
    int g  = (r >> 6) & 3;
    int oc = r & 63;
    int ic0 = ks * 32 + g * 8;

    half8 hv;
    #pragma unroll
    for (int e = 0; e < 8; ++e) {
        int ic = ic0 + e;
        float wf = 0.f;
        if (oc < 18)      wf = cls_w[oc * 512 + ic];
        else if (oc < 54) wf = bbox_w[(oc - 18) * 512 + ic];
        if (plane == 0) {
            hv[e] = (_Float16)wf;
        } else {
            _Float16 hi = (_Float16)wf;
            hv[e] = (_Float16)((wf - (float)hi) * 2048.0f);
        }
    }
    *(half8*)(bhw + (size_t)plane * 65536 +
              (size_t)(((ks * 4 + g) * 64 + oc)) * 16) = hv;

    if (blockIdx.x == 0 && threadIdx.x < 64) {
        int o = threadIdx.x;
        float bv = 0.f;
        if (o < 18)      bv = cls_b[o];
        else if (o < 54) bv = bbox_b[o - 18];
        *(float*)(bhw + 131072 + o * 4) = bv;
    }

    // hist: 524288 u32 = 8192 threads x 64.
    uint32_t* hz = hist + (size_t)t * 64;
    #pragma unroll
    for (int k = 0; k < 16; ++k)
        *(u32x4*)(hz + 4 * k) = (u32x4){0u, 0u, 0u, 0u};
}

// ---------------------------------------------------------------------------
// Fused heads: 1x1-conv GEMM (fp16x3 MFMA) -> LDS tile -> softmax/box decode
// + histogram, one kernel (round-18 proven).
// ---------------------------------------------------------------------------
__global__ __launch_bounds__(256) void heads_fused(
    const float* __restrict__ h, const char* __restrict__ bhw,
    const float* __restrict__ im_info, float* __restrict__ scores,
    float* __restrict__ boxes, uint32_t* __restrict__ hist)
{
    __shared__ float sdec[4][64][65];

    const int tid = threadIdx.x;
    const int l   = tid & 63;
    const int w   = tid >> 6;
    const int g   = l >> 4;
    const int l15 = l & 15;
    const int b   = blockIdx.y;
    const int px0 = blockIdx.x * 256 + w * 64;

    f32x4 accm[4][4], accc[4][4];
    #pragma unroll
    for (int i = 0; i < 4; ++i)
        #pragma unroll
        for (int j = 0; j < 4; ++j) {
            accm[i][j] = (f32x4){0.f, 0.f, 0.f, 0.f};
            accc[i][j] = (f32x4){0.f, 0.f, 0.f, 0.f};
        }

    const float* hb = h + (((size_t)(b * 512 + g * 8)) << 12) + px0 + l15;
    const float* bias64 = (const float*)(bhw + 131072);

    #pragma unroll 2
    for (int ks = 0; ks < 16; ++ks) {
        half8 bh[4], bl[4];
        #pragma unroll
        for (int jf = 0; jf < 4; ++jf) {
            size_t slot = (size_t)(((ks * 4 + g) * 64 + 16 * jf + l15)) * 16;
            bh[jf] = *(const half8*)(bhw + slot);
            bl[jf] = *(const half8*)(bhw + 65536 + slot);
        }
        #pragma unroll
        for (int i = 0; i < 4; ++i) {
            float af[8];
            #pragma unroll
            for (int e = 0; e < 8; ++e)
                af[e] = hb[(((size_t)(ks * 32 + e)) << 12) + i * 16];
            half8 ah, al;
            #pragma unroll
            for (int e = 0; e < 8; ++e) {
                _Float16 hi = (_Float16)af[e];
                ah[e] = hi;
                al[e] = (_Float16)((af[e] - (float)hi) * 2048.0f);
            }
            #pragma unroll
            for (int jf = 0; jf < 4; ++jf) {
                accm[i][jf] = __builtin_amdgcn_mfma_f32_16x16x32_f16(ah, bh[jf], accm[i][jf], 0, 0, 0);
                accc[i][jf] = __builtin_amdgcn_mfma_f32_16x16x32_f16(ah, bl[jf], accc[i][jf], 0, 0, 0);
                accc[i][jf] = __builtin_amdgcn_mfma_f32_16x16x32_f16(al, bh[jf], accc[i][jf], 0, 0, 0);
            }
        }
    }

    const float inv2048 = 4.8828125e-4f;
    float bv[4];
    #pragma unroll
    for (int jf = 0; jf < 4; ++jf) bv[jf] = bias64[16 * jf + l15];

    #pragma unroll
    for (int i = 0; i < 4; ++i) {
        #pragma unroll
        for (int jf = 0; jf < 4; ++jf) {
            int oc = 16 * jf + l15;
            #pragma unroll
            for (int j = 0; j < 4; ++j) {
                int pl = i * 16 + g * 4 + j;
                sdec[w][pl][oc] =
                    accm[i][jf][j] + accc[i][jf][j] * inv2048 + bv[jf];
            }
        }
    }
    __syncthreads();

    const int w2  = tid >> 6;
    const int pl2 = tid & 63;
    const int s = blockIdx.x * 256 + tid;

    float acc[54];
    #pragma unroll
    for (int o = 0; o < 54; ++o) acc[o] = sdec[w2][pl2][o];

    const float info0 = im_info[b * 3 + 0];
    const float info1 = im_info[b * 3 + 1];
    const float info2 = im_info[b * 3 + 2];
    const float maxx = info1 - 1.0f, maxy = info0 - 1.0f;
    const float min_size = 16.0f * info2;
    const int y = s >> 6, x = s & 63;
    const float cxa = 16.f * (float)x + 8.f;
    const float cya = 16.f * (float)y + 8.f;
    const float WA[9] = {184.f, 368.f, 736.f, 128.f, 256.f, 512.f,  88.f, 176.f, 352.f};
    const float HA[9] = { 96.f, 192.f, 384.f, 128.f, 256.f, 512.f, 176.f, 352.f, 704.f};

    uint32_t* hbm = hist + ((size_t)b << 16);
    const int base = b * 36864 + s * 9;
    #pragma unroll
    for (int a = 0; a < 9; ++a) {
        float c0v = acc[a], c1v = acc[9 + a];
        float mm = fmaxf(c0v, c1v);
        float e0 = expf(c0v - mm), e1 = expf(c1v - mm);
        float fg = e1 / (e0 + e1);
        float dx = acc[18 + 4 * a + 0];
        float dy = acc[18 + 4 * a + 1];
        float dw = acc[18 + 4 * a + 2];
        float dh = acc[18 + 4 * a + 3];
        float cx = dx * WA[a] + cxa;
        float cy = dy * HA[a] + cya;
        float pw = expf(dw) * WA[a];
        float ph = expf(dh) * HA[a];
        float x1 = fminf(fmaxf(cx - 0.5f * pw, 0.f), maxx);
        float y1 = fminf(fmaxf(cy - 0.5f * ph, 0.f), maxy);
        float x2 = fminf(fmaxf(cx + 0.5f * pw, 0.f), maxx);
        float y2 = fminf(fmaxf(cy + 0.5f * ph, 0.f), maxy);
        bool keep = ((x2 - x1 + 1.f) >= min_size) && ((y2 - y1 + 1.f) >= min_size);
        float sc = keep ? fg : NEG_INF_F;
        scores[base + a] = sc;
        atomicAdd(&hbm[(~ordf(sc)) >> 16], 1u);
        float* bp = boxes + (size_t)(base + a) * 4;
        bp[0] = x1; bp[1] = y1; bp[2] = x2; bp[3] = y2;
    }
}

// ---------------------------------------------------------------------------
// Fallback f32 conv + fused heads (used only if ws too small for MFMA path).
// ---------------------------------------------------------------------------
__global__ __launch_bounds__(256) void conv3_relu(
    const float* __restrict__ in, const float* __restrict__ w,
    const float* __restrict__ bias, float* __restrict__ out)
{
    const int oc0 = blockIdx.x * 32;
    const int y0  = blockIdx.y * 4;
    const int b   = blockIdx.z;
    const int tid = threadIdx.x;
    const int xg  = tid & 31;
    const int og  = tid >> 5;

    __shared__ float s_in[8][6][68];
    __shared__ float s_w[32][8][9];

    float acc[4][4][2];
    #pragma unroll
    for (int o = 0; o < 4; ++o)
        #pragma unroll
        for (int yy = 0; yy < 4; ++yy) { acc[o][yy][0] = 0.f; acc[o][yy][1] = 0.f; }

    for (int ic0 = 0; ic0 < 512; ic0 += 8) {
        for (int e = tid; e < 8 * 6 * 66; e += 256) {
            int ic = e / 396; int r = e - ic * 396;
            int yy = r / 66;  int xx = r - yy * 66;
            int gy = y0 + yy - 1;
            int gx = xx - 1;
            float v = 0.f;
            if (gy >= 0 && gy < 64 && gx >= 0 && gx < 64)
                v = in[(((b * 512 + ic0 + ic) * 64 + gy) << 6) + gx];
            s_in[ic][yy][xx] = v;
        }
        {
            int oc = tid >> 3, ic = tid & 7;
            const float* wp = w + ((size_t)(oc0 + oc) * 512 + ic0 + ic) * 9;
            #pragma unroll
            for (int k = 0; k < 9; ++k) s_w[oc][ic][k] = wp[k];
        }
        __syncthreads();
        for (int ic = 0; ic < 8; ++ic) {
            #pragma unroll
            for (int ky = 0; ky < 3; ++ky) {
                #pragma unroll
                for (int kx = 0; kx < 3; ++kx) {
                    const int k = ky * 3 + kx;
                    float w0 = s_w[og][ic][k];
                    float w1 = s_w[og + 8][ic][k];
                    float w2 = s_w[og + 16][ic][k];
                    float w3 = s_w[og + 24][ic][k];
                    #pragma unroll
                    for (int yy = 0; yy < 4; ++yy) {
                        float i0 = s_in[ic][yy + ky][xg + kx];
                        float i1 = s_in[ic][yy + ky][xg + 32 + kx];
                        acc[0][yy][0] = fmaf(w0, i0, acc[0][yy][0]);
                        acc[0][yy][1] = fmaf(w0, i1, acc[0][yy][1]);
                        acc[1][yy][0] = fmaf(w1, i0, acc[1][yy][0]);
                        acc[1][yy][1] = fmaf(w1, i1, acc[1][yy][1]);
                        acc[2][yy][0] = fmaf(w2, i0, acc[2][yy][0]);
                        acc[2][yy][1] = fmaf(w2, i1, acc[2][yy][1]);
                        acc[3][yy][0] = fmaf(w3, i0, acc[3][yy][0]);
                        acc[3][yy][1] = fmaf(w3, i1, acc[3][yy][1]);
                    }
                }
            }
        }
        __syncthreads();
    }

    #pragma unroll
    for (int o = 0; o < 4; ++o) {
        int oc = oc0 + og + 8 * o;
        float bv = bias[oc];
        #pragma unroll
        for (int yy = 0; yy < 4; ++yy) {
            int y = y0 + yy;
            float* op = out + (((b * 512 + oc) * 64 + y) << 6);
            float v0 = acc[o][yy][0] + bv; v0 = v0 > 0.f ? v0 : 0.f;
            float v1 = acc[o][yy][1] + bv; v1 = v1 > 0.f ? v1 : 0.f;
            op[xg] = v0; op[xg + 32] = v1;
        }
    }
}

__global__ __launch_bounds__(256) void heads(
    const float* __restrict__ h, const float* __restrict__ cls_w,
    const float* __restrict__ cls_b, const float* __restrict__ bbox_w,
    const float* __restrict__ bbox_b, const float* __restrict__ im_info,
    float* __restrict__ scores, float* __restrict__ boxes,
    uint32_t* __restrict__ hist)
{
    const int tid = threadIdx.x;
    const int b = blockIdx.x >> 4;
    const int s = ((blockIdx.x & 15) << 8) + tid;

    __shared__ float s_w[54][64];

    float acc[54];
    #pragma unroll
    for (int o = 0; o < 54; ++o) acc[o] = 0.f;

    for (int c0 = 0; c0 < 512; c0 += 64) {
        __syncthreads();
        for (int e = tid; e < 54 * 64; e += 256) {
            int oc = e >> 6, i = e & 63;
            float v = (oc < 18) ? cls_w[oc * 512 + c0 + i]
                                : bbox_w[(oc - 18) * 512 + c0 + i];
            s_w[oc][i] = v;
        }
        __syncthreads();
        for (int i = 0; i < 64; ++i) {
            float hv = h[((b * 512 + c0 + i) << 12) + s];
            #pragma unroll
            for (int o = 0; o < 54; ++o) acc[o] = fmaf(hv, s_w[o][i], acc[o]);
        }
    }
    #pragma unroll
    for (int o = 0; o < 18; ++o) acc[o] += cls_b[o];
    #pragma unroll
    for (int o = 0; o < 36; ++o) acc[18 + o] += bbox_b[o];

    const float info0 = im_info[b * 3 + 0];
    const float info1 = im_info[b * 3 + 1];
    const float info2 = im_info[b * 3 + 2];
    const float maxx = info1 - 1.0f, maxy = info0 - 1.0f;
    const float min_size = 16.0f * info2;
    const int y = s >> 6, x = s & 63;
    const float cxa = 16.f * (float)x + 8.f;
    const float cya = 16.f * (float)y + 8.f;
    const float WA[9] = {184.f, 368.f, 736.f, 128.f, 256.f, 512.f,  88.f, 176.f, 352.f};
    const float HA[9] = { 96.f, 192.f, 384.f, 128.f, 256.f, 512.f, 176.f, 352.f, 704.f};

    uint32_t* hb = hist + ((size_t)b << 16);
    const int base = b * 36864 + s * 9;
    #pragma unroll
    for (int a = 0; a < 9; ++a) {
        float c0v = acc[a], c1v = acc[9 + a];
        float mm = fmaxf(c0v, c1v);
        float e0 = expf(c0v - mm), e1 = expf(c1v - mm);
        float fg = e1 / (e0 + e1);
        float dx = acc[18 + 4 * a + 0];
        float dy = acc[18 + 4 * a + 1];
        float dw = acc[18 + 4 * a + 2];
        float dh = acc[18 + 4 * a + 3];
        float cx = dx * WA[a] + cxa;
        float cy = dy * HA[a] + cya;
        float pw = expf(dw) * WA[a];
        float ph = expf(dh) * HA[a];
        float x1 = fminf(fmaxf(cx - 0.5f * pw, 0.f), maxx);
        float y1 = fminf(fmaxf(cy - 0.5f * ph, 0.f), maxy);
        float x2 = fminf(fmaxf(cx + 0.5f * pw, 0.f), maxx);
        float y2 = fminf(fmaxf(cy + 0.5f * ph, 0.f), maxy);
        bool keep = ((x2 - x1 + 1.f) >= min_size) && ((y2 - y1 + 1.f) >= min_size);
        float sc = keep ? fg : NEG_INF_F;
        scores[base + a] = sc;
        atomicAdd(&hb[(~ordf(sc)) >> 16], 1u);
        float* bp = boxes + (size_t)(base + a) * 4;
        bp[0] = x1; bp[1] = y1; bp[2] = x2; bp[3] = y2;
    }
}

// ---------------------------------------------------------------------------
// select_k: per-batch fused top-2000 select (round-17 proven).
// ---------------------------------------------------------------------------
__global__ __launch_bounds__(1024) void select_k(
    const uint32_t* __restrict__ hist, const float* __restrict__ scores,
    const float* __restrict__ boxes, float* __restrict__ ts,
    float* __restrict__ tb)
{
    const int b = blockIdx.x;
    const int t = threadIdx.x;
    __shared__ uint64_t s[4096];       // candidate keys (32 KB)
    __shared__ uint32_t part[1024];
    __shared__ uint32_t thr;
    __shared__ uint32_t sel[2];        // [0]=definite count, [1]=boundary count

    const uint32_t* hb = hist + ((size_t)b << 16);

    uint32_t own = 0;
    #pragma unroll 4
    for (int k = 0; k < 64; ++k) own += hb[t * 64 + k];
    part[t] = own;
    for (int i = t; i < 4096; i += 1024) s[i] = ~0ull;
    if (t < 2) sel[t] = 0u;
    __syncthreads();
    for (int off = 1; off < 1024; off <<= 1) {
        uint32_t v = (t >= off) ? part[t - off] : 0u;
        __syncthreads();
        part[t] += v;
        __syncthreads();
    }
    uint32_t incl = part[t];
    uint32_t excl = incl - own;
    if (excl < 2000u && incl >= 2000u) {
        uint32_t c = excl;
        for (int k = 0; k < 64; ++k) {
            uint32_t hh = hb[t * 64 + k];
            if (c + hh >= 2000u) { thr = t * 64 + k; break; }
            c += hh;
        }
    }
    __syncthreads();
    const uint32_t T = thr;

    for (int i = t; i < 36864; i += 1024) {
        float sc = scores[b * 36864 + i];
        uint32_t kh = ~ordf(sc);
        uint32_t bin = kh >> 16;
        uint64_t key = ((uint64_t)kh << 32) | (uint32_t)i;
        if (bin < T) {
            uint32_t p = atomicAdd(&sel[0], 1u);
            s[p] = key;
        } else if (bin == T) {
            uint32_t p = atomicAdd(&sel[1], 1u);
            if (p < 2048u) s[4095 - p] = key;
        }
    }
    __syncthreads();

    for (int k = 2; k <= 4096; k <<= 1) {
        for (int j = k >> 1; j > 0; j >>= 1) {
            for (int t2 = t; t2 < 2048; t2 += 1024) {
                int i = ((t2 & ~(j - 1)) << 1) | (t2 & (j - 1));
                int ixj = i + j;
                bool up = ((i & k) == 0);
                uint64_t a = s[i], c = s[ixj];
                if ((a > c) == up) { s[i] = c; s[ixj] = a; }
            }
            __syncthreads();
        }
    }

    for (int r = t; r < 2000; r += 1024) {
        uint64_t k = s[r];
        int idx = (int)(uint32_t)k;
        ts[b * 2048 + r] = scores[b * 36864 + idx];
        const float* sp = boxes + ((size_t)b * 36864 + idx) * 4;
        float* dp = tb + ((size_t)b * 2048 + r) * 4;
        dp[0] = sp[0]; dp[1] = sp[1]; dp[2] = sp[2]; dp[3] = sp[3];
    }
}

// ---------------------------------------------------------------------------
// NMS: IoU bitmask build, UPPER TRIANGLE only (cb >= rb).
// ---------------------------------------------------------------------------
__global__ __launch_bounds__(64) void nms_mask(const float* __restrict__ tb,
                                               uint64_t* __restrict__ mask)
{
    const int b  = blockIdx.z;
    const int rb = blockIdx.y;
    const int cb = blockIdx.x;
    if (cb < rb) return;
    const int t  = threadIdx.x;
    __shared__ float cbox[64][4];
    const int col0 = cb * 64;
    {
        int c = col0 + t;
        if (c < 2000) {
            const float* p = tb + ((size_t)b * 2048 + c) * 4;
            cbox[t][0] = p[0]; cbox[t][1] = p[1]; cbox[t][2] = p[2]; cbox[t][3] = p[3];
        } else {
            cbox[t][0] = 0.f; cbox[t][1] = 0.f; cbox[t][2] = -1.f; cbox[t][3] = -1.f;
        }
    }
    __syncthreads();
    int row = rb * 64 + t;
    if (row >= 2000) return;
    const float* p = tb + ((size_t)b * 2048 + row) * 4;
    float x1 = p[0], y1 = p[1], x2 = p[2], y2 = p[3];
    float area = (x2 - x1 + 1.f) * (y2 - y1 + 1.f);
    uint64_t bits = 0;
    int ncol = 2000 - col0; if (ncol > 64) ncol = 64;
    for (int j = 0; j < ncol; ++j) {
        float xx1 = fmaxf(x1, cbox[j][0]);
        float yy1 = fmaxf(y1, cbox[j][1]);
        float xx2 = fminf(x2, cbox[j][2]);
        float yy2 = fminf(y2, cbox[j][3]);
        float iw = fmaxf(xx2 - xx1 + 1.f, 0.f);
        float ih = fmaxf(yy2 - yy1 + 1.f, 0.f);
        float inter = iw * ih;
        float areaj = (cbox[j][2] - cbox[j][0] + 1.f) * (cbox[j][3] - cbox[j][1] + 1.f);
        float iou = inter / (area + areaj - inter);
        if (iou > 0.7f) bits |= (1ull << j);
    }
    mask[((size_t)b * 2048 + row) * 32 + cb] = bits;
}

// ---------------------------------------------------------------------------
// Fused NMS scan + final sort + roi emit (round-12 proven).
// ---------------------------------------------------------------------------
__global__ __launch_bounds__(1024) void nms_final(
    const uint64_t* __restrict__ mask, const float* __restrict__ ts,
    const float* __restrict__ tb, float* __restrict__ out)
{
    const int b = blockIdx.x;
    const int tid = threadIdx.x;
    __shared__ uint64_t kw[32];        // keep bits, one u64 per 64 rows
    __shared__ uint64_t s[2048];

    if (tid < 64) {
        const int lane = tid;
        const uint64_t* mrow = mask + (size_t)b * 2048 * 32;
        const bool ml = (lane < 32);
        uint64_t remv = 0;
        uint32_t cur_lo = 0, cur_hi = 0;
        uint64_t kcur = 0;

        uint64_t bufA[16], bufB[16];

#define LOADG(buf, gidx) do { int base_ = (gidx) * 16;                        \
    _Pragma("unroll")                                                         \
    for (int k_ = 0; k_ < 16; ++k_) {                                         \
        int r_ = base_ + k_;                                                  \
        buf[k_] = (ml && r_ < 2000) ? mrow[(size_t)r_ * 32 + lane] : 0ull;    \
    } } while (0)

#define PROCG(buf, gidx) do { int base_ = (gidx) * 16;                        \
    _Pragma("unroll")                                                         \
    for (int k_ = 0; k_ < 16; ++k_) {                                         \
        int i_ = base_ + k_;                                                  \
        int w_ = i_ >> 6;                                                     \
        int bit_ = i_ & 63;                                                   \
        if (bit_ == 0) {                                                      \
            cur_lo = __builtin_amdgcn_readlane((uint32_t)remv, w_);           \
            cur_hi = __builtin_amdgcn_readlane((uint32_t)(remv >> 32), w_);   \
            kcur = 0;                                                         \
        }                                                                     \
        uint32_t sw_ = (bit_ < 32) ? cur_lo : cur_hi;                         \
        if (!((sw_ >> (bit_ & 31)) & 1u)) {                                   \
            kcur |= (1ull << bit_);                                           \
            if (ml) remv |= buf[k_];                                          \
            cur_lo |= __builtin_amdgcn_readlane((uint32_t)buf[k_], w_);       \
            cur_hi |= __builtin_amdgcn_readlane((uint32_t)(buf[k_] >> 32), w_);\
        }                                                                     \
        if (bit_ == 63 || i_ == 1999) { if (lane == 0) kw[w_] = kcur; }       \
    } } while (0)

        LOADG(bufA, 0);
        LOADG(bufB, 1);
        for (int gq = 0; gq < 125; gq += 2) {      // 125 groups of 16 = 2000
            PROCG(bufA, gq);
            LOADG(bufA, gq + 2);
            if (gq + 1 < 125) {
                PROCG(bufB, gq + 1);
                LOADG(bufB, gq + 3);
            }
        }
#undef LOADG
#undef PROCG
    }
    __syncthreads();                               // kw visible to all waves

    for (int i = tid; i < 2048; i += 1024) {
        uint64_t k;
        if (i < 2000) {
            bool kp = (kw[i >> 6] >> (i & 63)) & 1ull;
            float sc = kp ? ts[b * 2048 + i] : NEG_INF_F;
            k = ((uint64_t)(~ordf(sc)) << 32) | (uint32_t)i;
        } else {
            k = ~0ull;
        }
        s[i] = k;
    }
    __syncthreads();

    for (int k = 2; k <= 2048; k <<= 1) {
        for (int j = k >> 1; j > 0; j >>= 1) {
            for (int t = tid; t < 2048; t += 1024) {
                int ixj = t ^ j;
                if (ixj > t) {
                    bool up = ((t & k) == 0);
                    uint64_t a = s[t], c = s[ixj];
                    if ((a > c) == up) { s[t] = c; s[ixj] = a; }
                }
            }
            __syncthreads();
        }
    }
    for (int r = tid; r < 300; r += 1024) {
        int idx = (int)(uint32_t)s[r];
        const float* bp = tb + ((size_t)b * 2048 + idx) * 4;
        float* op = out + (size_t)(b * 300 + r) * 5;
        op[0] = (float)b;
        op[1] = bp[0]; op[2] = bp[1]; op[3] = bp[2]; op[4] = bp[3];
    }
}

// ---------------------------------------------------------------------------
extern "C" void kernel_launch(void* const* d_in, const int* in_sizes, int n_in,
                              void* d_out, int out_size, void* d_ws, size_t ws_size,
                              hipStream_t stream)
{
    const float* im_data = (const float*)d_in[0];
    const float* im_info = (const float*)d_in[1];
    const float* conv_w  = (const float*)d_in[2];
    const float* conv_b  = (const float*)d_in[3];
    const float* cls_w   = (const float*)d_in[4];
    const float* cls_b   = (const float*)d_in[5];
    const float* bbox_w  = (const float*)d_in[6];
    const float* bbox_b  = (const float*)d_in[7];
    float* out = (float*)d_out;

    char* ws = (char*)d_ws;
    float*    h      = (float*)(ws);                      // 67,108,864
    float*    scores = (float*)(ws + 67108864ull);        // 1,179,648
    float*    boxes  = (float*)(ws + 68288512ull);        // 4,718,592
    uint32_t* hist   = (uint32_t*)(ws + 73007104ull);     // 2,097,152
    float*    ts     = (float*)(ws + 75367424ull);        // 65,536
    float*    tb     = (float*)(ws + 75432960ull);        // 262,144
    uint64_t* mask   = (uint64_t*)(ws + 75695104ull);     // 4,194,304
    char*     bhw    = ws + 88409088ull;                  // 131,328   (dead-apad zone)

    char* apad = ws + 67108864ull;                        // 73,531,392 (conv phase only)
    char* bwp  = ws + 140640256ull;                       // 9,437,184
    const size_t NEED_FULL = 150077440ull;

    if (ws_size >= NEED_FULL) {
        prep_init<<<dim3(4384), 256, 0, stream>>>(conv_w, im_data, apad, bwp);
        conv_mfma<<<dim3(4, 32, 8), 256, 0, stream>>>(apad, bwp, conv_b, h);
        // apad dead from here; hist/bhw live in its footprint --
        // ALL of their initialization must come after conv_mfma (r13/r15).
        prep_hw<<<dim3(32), 256, 0, stream>>>(cls_w, bbox_w, cls_b, bbox_b,
                                              bhw, hist);
        heads_fused<<<dim3(16, 8), 256, 0, stream>>>(h, bhw, im_info,
                                                     scores, boxes, hist);
    } else {
        hipMemsetAsync(hist, 0, 2097152ull, stream);
        conv3_relu<<<dim3(16, 16, 8), 256, 0, stream>>>(im_data, conv_w, conv_b, h);
        heads<<<dim3(128), 256, 0, stream>>>(h, cls_w, cls_b, bbox_w, bbox_b, im_info,
                                             scores, boxes, hist);
    }

    select_k<<<dim3(8), 1024, 0, stream>>>(hist, scores, boxes, ts, tb);
    nms_mask<<<dim3(32, 32, 8), 64, 0, stream>>>(tb, mask);
    nms_final<<<dim3(8), 1024, 0, stream>>>(mask, ts, tb, out);
}